// Round 1
// baseline (3046.415 us; speedup 1.0000x reference)
//
#include <hip/hip_runtime.h>
#include <math.h>

// Problem constants (fixed by setup_inputs): B=4, N=2048, C=128, H=6, K=8
#define NFIX 2048
#define HH 6
#define KNN 8
#define NSLOPE 0.2f
#define EPSF 1e-6f
#define LNEPSF 1e-5f

#define LOAD12(dst, ptr) { \
  float4 _r0 = *(const float4*)((ptr));   \
  float4 _r1 = *(const float4*)((ptr)+4); \
  float4 _r2 = *(const float4*)((ptr)+8); \
  dst[0]=_r0.x; dst[1]=_r0.y; dst[2]=_r0.z; dst[3]=_r0.w; \
  dst[4]=_r1.x; dst[5]=_r1.y; dst[6]=_r1.z; dst[7]=_r1.w; \
  dst[8]=_r2.x; dst[9]=_r2.y; dst[10]=_r2.z; dst[11]=_r2.w; }

// out[d] = NS*p + (1-NS)*where(dot>=0, p, p - dot/(dsq+eps)*d)
__device__ __forceinline__ void vnleaky3(const float* p, const float* dv, float* out) {
  float dot = p[0]*dv[0] + p[1]*dv[1] + p[2]*dv[2];
  float dsq = dv[0]*dv[0] + dv[1]*dv[1] + dv[2]*dv[2] + EPSF;
  float f = dot / dsq;
#pragma unroll
  for (int d = 0; d < 3; ++d) {
    float neg = p[d] - f * dv[d];
    out[d] = NSLOPE * p[d] + (1.f - NSLOPE) * ((dot >= 0.f) ? p[d] : neg);
  }
}

// ---------------- weight prep: transposes + M = W2[:, :128] @ Wo ----------------
// segment layout (floats): Wqt 49152 | Wkt 49152 | Wvt 49152 | W1t 32768 | U1t 32768 |
//                          W3t 32768 | U3t 32768 | W4t 32768 | U4t 32768 | W2bt 16384 | Mt 49152
__global__ void prep_weights(const float* __restrict__ Wq, const float* __restrict__ Wk,
                             const float* __restrict__ Wv, const float* __restrict__ Wo,
                             const float* __restrict__ W1, const float* __restrict__ U1,
                             const float* __restrict__ W2, const float* __restrict__ W3,
                             const float* __restrict__ U3, const float* __restrict__ W4,
                             const float* __restrict__ U4,
                             float* __restrict__ Wqt, float* __restrict__ Wkt,
                             float* __restrict__ Wvt, float* __restrict__ W1t,
                             float* __restrict__ U1t, float* __restrict__ W3t,
                             float* __restrict__ U3t, float* __restrict__ W4t,
                             float* __restrict__ U4t, float* __restrict__ W2bt,
                             float* __restrict__ Mt) {
  int idx = blockIdx.x * 256 + threadIdx.x;
  if (idx < 49152) { int c = idx / 384, o = idx % 384; Wqt[idx] = Wq[o*128 + c]; return; }
  idx -= 49152;
  if (idx < 49152) { int c = idx / 384, o = idx % 384; Wkt[idx] = Wk[o*128 + c]; return; }
  idx -= 49152;
  if (idx < 49152) { int c = idx / 384, o = idx % 384; Wvt[idx] = Wv[o*128 + c]; return; }
  idx -= 49152;
  if (idx < 32768) { int c = idx / 128, o = idx % 128; W1t[idx] = W1[o*256 + c]; return; }
  idx -= 32768;
  if (idx < 32768) { int c = idx / 128, o = idx % 128; U1t[idx] = U1[o*256 + c]; return; }
  idx -= 32768;
  if (idx < 32768) { int c = idx / 256, o = idx % 256; W3t[idx] = W3[o*128 + c]; return; }
  idx -= 32768;
  if (idx < 32768) { int c = idx / 256, o = idx % 256; U3t[idx] = U3[o*128 + c]; return; }
  idx -= 32768;
  if (idx < 32768) { int c = idx / 128, o = idx % 128; W4t[idx] = W4[o*256 + c]; return; }
  idx -= 32768;
  if (idx < 32768) { int c = idx / 128, o = idx % 128; U4t[idx] = U4[o*256 + c]; return; }
  idx -= 32768;
  if (idx < 16384) { int c2 = idx / 128, c = idx % 128; W2bt[idx] = W2[c*256 + 128 + c2]; return; }
  idx -= 16384;
  if (idx < 49152) {
    int o = idx / 128, c = idx % 128;
    float s = 0.f;
    for (int cp = 0; cp < 128; ++cp) s += W2[c*256 + cp] * Wo[cp*384 + o];
    Mt[idx] = s;   // Mt[o*128 + c] = (W2a @ Wo)[c][o]
  }
}

// ---------------- VN LayerNorm: per point (b,n), channels c=0..127 ----------------
__global__ __launch_bounds__(128) void ln_kernel(const float* __restrict__ in,
                                                 float* __restrict__ out,
                                                 const float* __restrict__ g,
                                                 const float* __restrict__ b) {
  int bn = blockIdx.x;
  int c = threadIdx.x;
  const float* row = in + (size_t)bn * 384;
  float x0 = row[c*3+0], x1 = row[c*3+1], x2 = row[c*3+2];
  float nv = sqrtf(x0*x0 + x1*x1 + x2*x2 + EPSF);
  float s1 = nv, s2 = nv*nv;
#pragma unroll
  for (int off = 32; off >= 1; off >>= 1) {
    s1 += __shfl_down(s1, off);
    s2 += __shfl_down(s2, off);
  }
  __shared__ float red[4];
  int lane = threadIdx.x & 63, w = threadIdx.x >> 6;
  if (lane == 0) { red[w*2] = s1; red[w*2+1] = s2; }
  __syncthreads();
  float tot1 = red[0] + red[2], tot2 = red[1] + red[3];
  float mu  = tot1 * (1.f/128.f);
  float var = tot2 * (1.f/128.f) - mu*mu;
  float rsig = rsqrtf(var + LNEPSF);
  float nnew = g[c] * ((nv - mu) * rsig) + b[c];
  float sc = nnew / nv;
  float* orow = out + (size_t)bn * 384;
  orow[c*3+0] = x0*sc; orow[c*3+1] = x1*sc; orow[c*3+2] = x2*sc;
}

// ---------------- QKV projection: out[bn][o*3+d] = sum_c W[o][c] * in[bn][c*3+d] ----------------
// block = 256 thr, 16 points/block. thread: po=t&7 (point pair), og=t>>3 (4 out-channels)
__global__ __launch_bounds__(256) void qkv_kernel(const float* __restrict__ in,
    const float* __restrict__ Wqt, const float* __restrict__ Wkt,
    const float* __restrict__ Wvt,
    float* __restrict__ q, float* __restrict__ k, float* __restrict__ v) {
  __shared__ float ins[16*388];   // pitch 388 breaks same-bank stride
  int bnb = blockIdx.x * 16;
  int t = threadIdx.x;
  for (int idx = t; idx < 16*96; idx += 256) {
    int pt = idx / 96, j4 = (idx % 96) * 4;
    *(float4*)&ins[pt*388 + j4] = *(const float4*)&in[((size_t)bnb + pt)*384 + j4];
  }
  __syncthreads();
  int po = t & 7;
  int og = t >> 3;
  for (int pass = 0; pass < 9; ++pass) {
    int which = pass / 3;
    int om_ = (pass % 3) * 128 + og * 4;  // out channel base within matrix
    const float* W = (which == 0) ? Wqt : (which == 1) ? Wkt : Wvt;
    float a[2][4][3];
#pragma unroll
    for (int pp = 0; pp < 2; ++pp)
#pragma unroll
      for (int uu = 0; uu < 4; ++uu)
#pragma unroll
        for (int d = 0; d < 3; ++d) a[pp][uu][d] = 0.f;
    for (int ci = 0; ci < 32; ++ci) {
      float wv[4][4];
#pragma unroll
      for (int cc = 0; cc < 4; ++cc) {
        float4 wt = *(const float4*)&W[(size_t)(4*ci+cc)*384 + om_];
        wv[cc][0]=wt.x; wv[cc][1]=wt.y; wv[cc][2]=wt.z; wv[cc][3]=wt.w;
      }
#pragma unroll
      for (int pp = 0; pp < 2; ++pp) {
        const float* ip = &ins[(2*po+pp)*388 + 12*ci];
        float vals[12];
        LOAD12(vals, ip);
#pragma unroll
        for (int cc = 0; cc < 4; ++cc)
#pragma unroll
          for (int uu = 0; uu < 4; ++uu)
#pragma unroll
            for (int d = 0; d < 3; ++d)
              a[pp][uu][d] += wv[cc][uu] * vals[cc*3+d];
      }
    }
    float* op = (which == 0) ? q : (which == 1) ? k : v;
#pragma unroll
    for (int pp = 0; pp < 2; ++pp) {
      size_t rb = ((size_t)bnb + 2*po + pp) * 1152;
#pragma unroll
      for (int uu = 0; uu < 4; ++uu)
#pragma unroll
        for (int d = 0; d < 3; ++d)
          op[rb + (size_t)(om_+uu)*3 + d] = a[pp][uu][d];
    }
  }
}

// ---------------- attention: flash-style online softmax, TQ=32, TK=32 ----------------
// block=256: ty=t>>4 -> q rows {ty, ty+16}; tx=t&15 -> k cols {tx, tx+16}, o cols tx*12..+11
#define APITCH 196
__global__ __launch_bounds__(256) void attn_kernel(const float* __restrict__ q,
    const float* __restrict__ k, const float* __restrict__ v,
    float* __restrict__ o) {
  __shared__ float qs[32*APITCH];
  __shared__ float kv[32*APITCH];   // shared between K (phase2) and V (phase3)
  __shared__ float ss[32*36];
  const int nqb = NFIX / 32;
  int qb = blockIdx.x % nqb;
  int bh = blockIdx.x / nqb;
  int h = bh % HH, b = bh / HH;
  int t = threadIdx.x;
  int ty = t >> 4, tx = t & 15;
  size_t base = ((size_t)b * NFIX) * 1152 + (size_t)h * 192;
  size_t qrow0 = base + (size_t)(qb * 32) * 1152;
  for (int idx = t; idx < 32*48; idx += 256) {
    int r = idx / 48, c4 = (idx % 48) * 4;
    float4 qv = *(const float4*)&q[qrow0 + (size_t)r*1152 + c4];
    qv.x *= 0.125f; qv.y *= 0.125f; qv.z *= 0.125f; qv.w *= 0.125f;
    *(float4*)&qs[r*APITCH + c4] = qv;
  }
  float acc0[12], acc1[12];
#pragma unroll
  for (int j = 0; j < 12; ++j) { acc0[j] = 0.f; acc1[j] = 0.f; }
  float m0 = -1e30f, m1 = -1e30f, l0 = 0.f, l1 = 0.f;
  __syncthreads();
  for (int kb = 0; kb < NFIX/32; ++kb) {
    size_t krow0 = base + (size_t)(kb * 32) * 1152;
    for (int idx = t; idx < 32*48; idx += 256) {
      int r = idx / 48, c4 = (idx % 48) * 4;
      *(float4*)&kv[r*APITCH + c4] = *(const float4*)&k[krow0 + (size_t)r*1152 + c4];
    }
    __syncthreads();
    // phase 2: S = Q K^T  (2q x 2k per thread)
    float d00=0.f, d01=0.f, d10=0.f, d11=0.f;
    const float* q0 = &qs[ty*APITCH];
    const float* q1 = &qs[(ty+16)*APITCH];
    const float* k0 = &kv[tx*APITCH];
    const float* k1 = &kv[(tx+16)*APITCH];
#pragma unroll 8
    for (int c = 0; c < 192; c += 4) {
      float4 a0 = *(const float4*)&q0[c];
      float4 a1 = *(const float4*)&q1[c];
      float4 b0 = *(const float4*)&k0[c];
      float4 b1 = *(const float4*)&k1[c];
      d00 += a0.x*b0.x + a0.y*b0.y + a0.z*b0.z + a0.w*b0.w;
      d01 += a0.x*b1.x + a0.y*b1.y + a0.z*b1.z + a0.w*b1.w;
      d10 += a1.x*b0.x + a1.y*b0.y + a1.z*b0.z + a1.w*b0.w;
      d11 += a1.x*b1.x + a1.y*b1.y + a1.z*b1.z + a1.w*b1.w;
    }
    ss[ty*36 + tx]        = d00;
    ss[ty*36 + tx + 16]   = d01;
    ss[(ty+16)*36 + tx]      = d10;
    ss[(ty+16)*36 + tx + 16] = d11;
    __syncthreads();
    // overwrite kv with V tile
    for (int idx = t; idx < 32*48; idx += 256) {
      int r = idx / 48, c4 = (idx % 48) * 4;
      *(float4*)&kv[r*APITCH + c4] = *(const float4*)&v[krow0 + (size_t)r*1152 + c4];
    }
    __syncthreads();
    // phase 3: online softmax + PV. All 16 tx-threads of a row compute identical m/l.
    const float* s0 = &ss[ty*36];
    const float* s1 = &ss[(ty+16)*36];
    float mx0 = m0, mx1 = m1;
#pragma unroll
    for (int kj = 0; kj < 32; ++kj) { mx0 = fmaxf(mx0, s0[kj]); mx1 = fmaxf(mx1, s1[kj]); }
    float al0 = __expf(m0 - mx0), al1 = __expf(m1 - mx1);
#pragma unroll
    for (int j = 0; j < 12; ++j) { acc0[j] *= al0; acc1[j] *= al1; }
    float ls0 = 0.f, ls1 = 0.f;
#pragma unroll 8
    for (int kj = 0; kj < 32; ++kj) {
      float p0 = __expf(s0[kj] - mx0);
      float p1 = __expf(s1[kj] - mx1);
      ls0 += p0; ls1 += p1;
      const float* vr = &kv[kj*APITCH + tx*12];
      float4 v0 = *(const float4*)vr;
      float4 v1 = *(const float4*)(vr+4);
      float4 v2 = *(const float4*)(vr+8);
      acc0[0] += p0*v0.x; acc0[1] += p0*v0.y; acc0[2]  += p0*v0.z; acc0[3]  += p0*v0.w;
      acc0[4] += p0*v1.x; acc0[5] += p0*v1.y; acc0[6]  += p0*v1.z; acc0[7]  += p0*v1.w;
      acc0[8] += p0*v2.x; acc0[9] += p0*v2.y; acc0[10] += p0*v2.z; acc0[11] += p0*v2.w;
      acc1[0] += p1*v0.x; acc1[1] += p1*v0.y; acc1[2]  += p1*v0.z; acc1[3]  += p1*v0.w;
      acc1[4] += p1*v1.x; acc1[5] += p1*v1.y; acc1[6]  += p1*v1.z; acc1[7]  += p1*v1.w;
      acc1[8] += p1*v2.x; acc1[9] += p1*v2.y; acc1[10] += p1*v2.z; acc1[11] += p1*v2.w;
    }
    l0 = al0*l0 + ls0; l1 = al1*l1 + ls1;
    m0 = mx0; m1 = mx1;
    __syncthreads();
  }
  float inv0 = 1.f / l0, inv1 = 1.f / l1;
  size_t ob0 = qrow0 + (size_t)ty*1152 + tx*12;
  size_t ob1 = qrow0 + (size_t)(ty+16)*1152 + tx*12;
#pragma unroll
  for (int j = 0; j < 12; ++j) { o[ob0 + j] = acc0[j]*inv0; o[ob1 + j] = acc1[j]*inv1; }
}

// ---------------- knn gather + conv1 (VNLinearLeakyReLU 256->128) + mean over K ----------------
__global__ __launch_bounds__(128) void conv1_kernel(const float* __restrict__ normx,
    const int* __restrict__ knn_index,
    const float* __restrict__ W1t, const float* __restrict__ U1t,
    float* __restrict__ knnmean) {
  __shared__ float xc[384];
  __shared__ float feats[KNN*384];
  __shared__ int sidx[KNN];
  int bn = blockIdx.x;
  int b = bn / NFIX, n = bn % NFIX;
  int t = threadIdx.x;
  if (t < KNN) sidx[t] = knn_index[(b*KNN + t)*NFIX + n];
  for (int idx = t; idx < 96; idx += 128)
    *(float4*)&xc[idx*4] = *(const float4*)&normx[(size_t)bn*384 + idx*4];
  __syncthreads();
  for (int idx = t; idx < KNN*96; idx += 128) {
    int kk = idx / 96, j4 = (idx % 96) * 4;
    *(float4*)&feats[kk*384 + j4] = *(const float4*)&normx[(size_t)sidx[kk]*384 + j4];
  }
  __syncthreads();
  int o = t;
  float p[KNN][3], dd[KNN][3];
#pragma unroll
  for (int kk = 0; kk < KNN; ++kk)
#pragma unroll
    for (int d = 0; d < 3; ++d) { p[kk][d] = 0.f; dd[kk][d] = 0.f; }
  for (int ci = 0; ci < 32; ++ci) {
    float w1[4], w1b[4], u1[4], u1b[4];
#pragma unroll
    for (int cc = 0; cc < 4; ++cc) {
      int c = 4*ci + cc;
      w1[cc]  = W1t[c*128 + o];
      w1b[cc] = W1t[(128+c)*128 + o];
      u1[cc]  = U1t[c*128 + o];
      u1b[cc] = U1t[(128+c)*128 + o];
    }
    float xv[12];
    LOAD12(xv, &xc[12*ci]);
#pragma unroll
    for (int kk = 0; kk < KNN; ++kk) {
      float fv[12];
      LOAD12(fv, &feats[kk*384 + 12*ci]);
#pragma unroll
      for (int cc = 0; cc < 4; ++cc)
#pragma unroll
        for (int d = 0; d < 3; ++d) {
          float xcv = xv[cc*3+d];
          float fa = fv[cc*3+d] - xcv;
          p[kk][d]  += w1[cc]*fa + w1b[cc]*xcv;
          dd[kk][d] += u1[cc]*fa + u1b[cc]*xcv;
        }
    }
  }
  float om[3] = {0.f, 0.f, 0.f};
#pragma unroll
  for (int kk = 0; kk < KNN; ++kk) {
    float res[3];
    vnleaky3(p[kk], dd[kk], res);
    om[0] += res[0]; om[1] += res[1]; om[2] += res[2];
  }
  size_t ob = (size_t)bn*384 + o*3;
  knnmean[ob+0] = om[0] * (1.f/KNN);
  knnmean[ob+1] = om[1] * (1.f/KNN);
  knnmean[ob+2] = om[2] * (1.f/KNN);
}

// ---------------- x_mid = x + M @ o_attn + W2b @ knnmean ----------------
// block=128: tc=t&31 -> c in {tc,tc+32,tc+64,tc+96}; tp=t>>5 -> pts {2tp, 2tp+1}; 8 pts/block
__global__ __launch_bounds__(128) void x1mid_kernel(const float* __restrict__ x,
    const float* __restrict__ oattn, const float* __restrict__ knnm,
    const float* __restrict__ Mt, const float* __restrict__ W2bt,
    float* __restrict__ out) {
  __shared__ float os[8*1156];
  __shared__ float ksm[8*388];
  int bnb = blockIdx.x * 8;
  int t = threadIdx.x;
  for (int idx = t; idx < 8*288; idx += 128) {
    int pt = idx / 288, j4 = (idx % 288) * 4;
    *(float4*)&os[pt*1156 + j4] = *(const float4*)&oattn[((size_t)bnb + pt)*1152 + j4];
  }
  for (int idx = t; idx < 8*96; idx += 128) {
    int pt = idx / 96, j4 = (idx % 96) * 4;
    *(float4*)&ksm[pt*388 + j4] = *(const float4*)&knnm[((size_t)bnb + pt)*384 + j4];
  }
  __syncthreads();
  int tc = t & 31;
  int tp = t >> 5;
  float acc[4][2][3];
#pragma unroll
  for (int u = 0; u < 4; ++u)
#pragma unroll
    for (int pp = 0; pp < 2; ++pp)
#pragma unroll
      for (int d = 0; d < 3; ++d)
        acc[u][pp][d] = x[((size_t)bnb + 2*tp + pp)*384 + (tc + 32*u)*3 + d];
  for (int oi = 0; oi < 96; ++oi) {
    float w[4][4];
#pragma unroll
    for (int oo = 0; oo < 4; ++oo)
#pragma unroll
      for (int u = 0; u < 4; ++u)
        w[oo][u] = Mt[(size_t)(4*oi+oo)*128 + tc + 32*u];
#pragma unroll
    for (int pp = 0; pp < 2; ++pp) {
      float vals[12];
      LOAD12(vals, &os[(2*tp+pp)*1156 + 12*oi]);
#pragma unroll
      for (int oo = 0; oo < 4; ++oo)
#pragma unroll
        for (int u = 0; u < 4; ++u)
#pragma unroll
          for (int d = 0; d < 3; ++d)
            acc[u][pp][d] += w[oo][u] * vals[oo*3+d];
    }
  }
  for (int ci = 0; ci < 32; ++ci) {
    float w[4][4];
#pragma unroll
    for (int cc = 0; cc < 4; ++cc)
#pragma unroll
      for (int u = 0; u < 4; ++u)
        w[cc][u] = W2bt[(size_t)(4*ci+cc)*128 + tc + 32*u];
#pragma unroll
    for (int pp = 0; pp < 2; ++pp) {
      float vals[12];
      LOAD12(vals, &ksm[(2*tp+pp)*388 + 12*ci]);
#pragma unroll
      for (int cc = 0; cc < 4; ++cc)
#pragma unroll
        for (int u = 0; u < 4; ++u)
#pragma unroll
          for (int d = 0; d < 3; ++d)
            acc[u][pp][d] += w[cc][u] * vals[cc*3+d];
    }
  }
#pragma unroll
  for (int u = 0; u < 4; ++u)
#pragma unroll
    for (int pp = 0; pp < 2; ++pp)
#pragma unroll
      for (int d = 0; d < 3; ++d)
        out[((size_t)bnb + 2*tp + pp)*384 + (tc + 32*u)*3 + d] = acc[u][pp][d];
}

// ---------------- conv3: VNLinearLeakyReLU 128 -> 256 ----------------
__global__ __launch_bounds__(256) void conv3_kernel(const float* __restrict__ in,
    const float* __restrict__ W3t, const float* __restrict__ U3t,
    float* __restrict__ h3) {
  __shared__ float ins[4*384];
  int bnb = blockIdx.x * 4;
  int t = threadIdx.x;  // o2 in [0,256)
  for (int idx = t; idx < 4*96; idx += 256)
    *(float4*)&ins[idx*4] = *(const float4*)&in[(size_t)bnb*384 + idx*4];
  __syncthreads();
  float p[4][3], dd[4][3];
#pragma unroll
  for (int pt = 0; pt < 4; ++pt)
#pragma unroll
    for (int d = 0; d < 3; ++d) { p[pt][d] = 0.f; dd[pt][d] = 0.f; }
  for (int ci = 0; ci < 32; ++ci) {
    float w3[4], u3[4];
#pragma unroll
    for (int cc = 0; cc < 4; ++cc) {
      int c = 4*ci + cc;
      w3[cc] = W3t[c*256 + t];
      u3[cc] = U3t[c*256 + t];
    }
#pragma unroll
    for (int pt = 0; pt < 4; ++pt) {
      float vals[12];
      LOAD12(vals, &ins[pt*384 + 12*ci]);
#pragma unroll
      for (int cc = 0; cc < 4; ++cc)
#pragma unroll
        for (int d = 0; d < 3; ++d) {
          float xv = vals[cc*3+d];
          p[pt][d]  += w3[cc]*xv;
          dd[pt][d] += u3[cc]*xv;
        }
    }
  }
#pragma unroll
  for (int pt = 0; pt < 4; ++pt) {
    float res[3];
    vnleaky3(p[pt], dd[pt], res);
    size_t ob = ((size_t)bnb + pt)*768 + t*3;
    h3[ob+0] = res[0]; h3[ob+1] = res[1]; h3[ob+2] = res[2];
  }
}

// ---------------- conv4: VNLinearLeakyReLU 256 -> 128, + residual into out ----------------
__global__ __launch_bounds__(128) void conv4_kernel(const float* __restrict__ h3,
    const float* __restrict__ W4t, const float* __restrict__ U4t,
    float* __restrict__ out) {
  __shared__ float ins[4*768];
  int bnb = blockIdx.x * 4;
  int t = threadIdx.x;  // o in [0,128)
  for (int idx = t; idx < 4*192; idx += 128)
    *(float4*)&ins[idx*4] = *(const float4*)&h3[(size_t)bnb*768 + idx*4];
  __syncthreads();
  float p[4][3], dd[4][3];
#pragma unroll
  for (int pt = 0; pt < 4; ++pt)
#pragma unroll
    for (int d = 0; d < 3; ++d) { p[pt][d] = 0.f; dd[pt][d] = 0.f; }
  for (int ci = 0; ci < 64; ++ci) {
    float w4[4], u4[4];
#pragma unroll
    for (int cc = 0; cc < 4; ++cc) {
      int c2 = 4*ci + cc;
      w4[cc] = W4t[c2*128 + t];
      u4[cc] = U4t[c2*128 + t];
    }
#pragma unroll
    for (int pt = 0; pt < 4; ++pt) {
      float vals[12];
      LOAD12(vals, &ins[pt*768 + 12*ci]);
#pragma unroll
      for (int cc = 0; cc < 4; ++cc)
#pragma unroll
        for (int d = 0; d < 3; ++d) {
          float xv = vals[cc*3+d];
          p[pt][d]  += w4[cc]*xv;
          dd[pt][d] += u4[cc]*xv;
        }
    }
  }
#pragma unroll
  for (int pt = 0; pt < 4; ++pt) {
    float res[3];
    vnleaky3(p[pt], dd[pt], res);
    float* orow = out + ((size_t)bnb + pt)*384 + t*3;
    orow[0] += res[0]; orow[1] += res[1]; orow[2] += res[2];
  }
}

extern "C" void kernel_launch(void* const* d_in, const int* in_sizes, int n_in,
                              void* d_out, int out_size, void* d_ws, size_t ws_size,
                              hipStream_t stream) {
  const float* x   = (const float*)d_in[0];
  const int* knn   = (const int*)d_in[1];
  const float* g1  = (const float*)d_in[2];
  const float* b1  = (const float*)d_in[3];
  const float* g2  = (const float*)d_in[4];
  const float* b2  = (const float*)d_in[5];
  const float* Wq  = (const float*)d_in[6];
  const float* Wk  = (const float*)d_in[7];
  const float* Wv  = (const float*)d_in[8];
  const float* Wo  = (const float*)d_in[9];
  const float* W1  = (const float*)d_in[10];
  const float* U1  = (const float*)d_in[11];
  const float* W2  = (const float*)d_in[12];
  const float* W3  = (const float*)d_in[13];
  const float* U3  = (const float*)d_in[14];
  const float* W4  = (const float*)d_in[15];
  const float* U4  = (const float*)d_in[16];
  float* out = (float*)d_out;
  (void)n_in; (void)out_size; (void)ws_size;

  const size_t BN = (size_t)in_sizes[0] / 384;   // 8192

  float* ws    = (float*)d_ws;
  float* normx = ws;                       // BN*384
  float* qbuf  = normx + BN*384;           // BN*1152
  float* kbuf  = qbuf  + BN*1152;
  float* vbuf  = kbuf  + BN*1152;
  float* obuf  = vbuf  + BN*1152;
  float* knnm  = obuf  + BN*1152;          // BN*384
  float* wsp   = knnm  + BN*384;
  float* Wqt  = wsp;
  float* Wkt  = Wqt + 49152;
  float* Wvt  = Wkt + 49152;
  float* W1t  = Wvt + 49152;
  float* U1t  = W1t + 32768;
  float* W3t  = U1t + 32768;
  float* U3t  = W3t + 32768;
  float* W4t  = U3t + 32768;
  float* U4t  = W4t + 32768;
  float* W2bt = U4t + 32768;
  float* Mt   = W2bt + 16384;
  float* nx2 = qbuf;   // alias: q dead after attention
  float* h3  = kbuf;   // alias: k dead after attention

  prep_weights<<<1600, 256, 0, stream>>>(Wq, Wk, Wv, Wo, W1, U1, W2, W3, U3, W4, U4,
                                         Wqt, Wkt, Wvt, W1t, U1t, W3t, U3t, W4t, U4t,
                                         W2bt, Mt);
  ln_kernel<<<(int)BN, 128, 0, stream>>>(x, normx, g1, b1);
  qkv_kernel<<<(int)(BN/16), 256, 0, stream>>>(normx, Wqt, Wkt, Wvt, qbuf, kbuf, vbuf);
  attn_kernel<<<(int)((BN/32)*HH), 256, 0, stream>>>(qbuf, kbuf, vbuf, obuf);
  conv1_kernel<<<(int)BN, 128, 0, stream>>>(normx, knn, W1t, U1t, knnm);
  x1mid_kernel<<<(int)(BN/8), 128, 0, stream>>>(x, obuf, knnm, Mt, W2bt, out);
  ln_kernel<<<(int)BN, 128, 0, stream>>>(out, nx2, g2, b2);
  conv3_kernel<<<(int)(BN/4), 256, 0, stream>>>(nx2, W3t, U3t, h3);
  conv4_kernel<<<(int)(BN/4), 128, 0, stream>>>(h3, W4t, U4t, out);
}

// Round 2
// 1449.678 us; speedup vs baseline: 2.1014x; 2.1014x over previous
//
#include <hip/hip_runtime.h>
#include <math.h>

// Problem constants (fixed by setup_inputs): B=4, N=2048, C=128, H=6, K=8
#define NFIX 2048
#define HH 6
#define KNN 8
#define NSLOPE 0.2f
#define EPSF 1e-6f
#define LNEPSF 1e-5f
// 0.125 (softmax scale) * log2(e), folded into bf16 Q so S-MFMA output is exp2-ready
#define QSCALE 0.18033688011112042f

typedef unsigned short ushort_t;
typedef unsigned int uint_t;
typedef __attribute__((ext_vector_type(8))) short bf16x8;
typedef __attribute__((ext_vector_type(4))) short bf16x4;
typedef __attribute__((ext_vector_type(16))) float f32x16;
typedef __attribute__((ext_vector_type(4))) float f32x4;

__device__ __forceinline__ ushort_t f2bf(float f) {
  union { float f; unsigned u; } v; v.f = f;
  unsigned r = v.u + 0x7fff + ((v.u >> 16) & 1);   // RNE
  return (ushort_t)(r >> 16);
}

#define LOAD12(dst, ptr) { \
  float4 _r0 = *(const float4*)((ptr));   \
  float4 _r1 = *(const float4*)((ptr)+4); \
  float4 _r2 = *(const float4*)((ptr)+8); \
  dst[0]=_r0.x; dst[1]=_r0.y; dst[2]=_r0.z; dst[3]=_r0.w; \
  dst[4]=_r1.x; dst[5]=_r1.y; dst[6]=_r1.z; dst[7]=_r1.w; \
  dst[8]=_r2.x; dst[9]=_r2.y; dst[10]=_r2.z; dst[11]=_r2.w; }

__device__ __forceinline__ void vnleaky3(const float* p, const float* dv, float* out) {
  float dot = p[0]*dv[0] + p[1]*dv[1] + p[2]*dv[2];
  float dsq = dv[0]*dv[0] + dv[1]*dv[1] + dv[2]*dv[2] + EPSF;
  float f = dot / dsq;
#pragma unroll
  for (int d = 0; d < 3; ++d) {
    float neg = p[d] - f * dv[d];
    out[d] = NSLOPE * p[d] + (1.f - NSLOPE) * ((dot >= 0.f) ? p[d] : neg);
  }
}

// ---------------- weight prep: transposes + M = W2[:, :128] @ Wo ----------------
__global__ void prep_weights(const float* __restrict__ Wq, const float* __restrict__ Wk,
                             const float* __restrict__ Wv, const float* __restrict__ Wo,
                             const float* __restrict__ W1, const float* __restrict__ U1,
                             const float* __restrict__ W2, const float* __restrict__ W3,
                             const float* __restrict__ U3, const float* __restrict__ W4,
                             const float* __restrict__ U4,
                             float* __restrict__ Wqt, float* __restrict__ Wkt,
                             float* __restrict__ Wvt, float* __restrict__ W1t,
                             float* __restrict__ U1t, float* __restrict__ W3t,
                             float* __restrict__ U3t, float* __restrict__ W4t,
                             float* __restrict__ U4t, float* __restrict__ W2bt,
                             float* __restrict__ Mt) {
  int idx = blockIdx.x * 256 + threadIdx.x;
  if (idx < 49152) { int c = idx / 384, o = idx % 384; Wqt[idx] = Wq[o*128 + c]; return; }
  idx -= 49152;
  if (idx < 49152) { int c = idx / 384, o = idx % 384; Wkt[idx] = Wk[o*128 + c]; return; }
  idx -= 49152;
  if (idx < 49152) { int c = idx / 384, o = idx % 384; Wvt[idx] = Wv[o*128 + c]; return; }
  idx -= 49152;
  if (idx < 32768) { int c = idx / 128, o = idx % 128; W1t[idx] = W1[o*256 + c]; return; }
  idx -= 32768;
  if (idx < 32768) { int c = idx / 128, o = idx % 128; U1t[idx] = U1[o*256 + c]; return; }
  idx -= 32768;
  if (idx < 32768) { int c = idx / 256, o = idx % 256; W3t[idx] = W3[o*128 + c]; return; }
  idx -= 32768;
  if (idx < 32768) { int c = idx / 256, o = idx % 256; U3t[idx] = U3[o*128 + c]; return; }
  idx -= 32768;
  if (idx < 32768) { int c = idx / 128, o = idx % 128; W4t[idx] = W4[o*256 + c]; return; }
  idx -= 32768;
  if (idx < 32768) { int c = idx / 128, o = idx % 128; U4t[idx] = U4[o*256 + c]; return; }
  idx -= 32768;
  if (idx < 16384) { int c2 = idx / 128, c = idx % 128; W2bt[idx] = W2[c*256 + 128 + c2]; return; }
  idx -= 16384;
  if (idx < 49152) {
    int o = idx / 128, c = idx % 128;
    float s = 0.f;
    for (int cp = 0; cp < 128; ++cp) s += W2[c*256 + cp] * Wo[cp*384 + o];
    Mt[idx] = s;
  }
}

// ---------------- VN LayerNorm ----------------
__global__ __launch_bounds__(128) void ln_kernel(const float* __restrict__ in,
                                                 float* __restrict__ out,
                                                 const float* __restrict__ g,
                                                 const float* __restrict__ b) {
  int bn = blockIdx.x;
  int c = threadIdx.x;
  const float* row = in + (size_t)bn * 384;
  float x0 = row[c*3+0], x1 = row[c*3+1], x2 = row[c*3+2];
  float nv = sqrtf(x0*x0 + x1*x1 + x2*x2 + EPSF);
  float s1 = nv, s2 = nv*nv;
#pragma unroll
  for (int off = 32; off >= 1; off >>= 1) {
    s1 += __shfl_down(s1, off);
    s2 += __shfl_down(s2, off);
  }
  __shared__ float red[4];
  int lane = threadIdx.x & 63, w = threadIdx.x >> 6;
  if (lane == 0) { red[w*2] = s1; red[w*2+1] = s2; }
  __syncthreads();
  float tot1 = red[0] + red[2], tot2 = red[1] + red[3];
  float mu  = tot1 * (1.f/128.f);
  float var = tot2 * (1.f/128.f) - mu*mu;
  float rsig = rsqrtf(var + LNEPSF);
  float nnew = g[c] * ((nv - mu) * rsig) + b[c];
  float sc = nnew / nv;
  float* orow = out + (size_t)bn * 384;
  orow[c*3+0] = x0*sc; orow[c*3+1] = x1*sc; orow[c*3+2] = x2*sc;
}

// ---------------- QKV projection -> bf16 (q pre-scaled by QSCALE) ----------------
__global__ __launch_bounds__(256) void qkv_kernel(const float* __restrict__ in,
    const float* __restrict__ Wqt, const float* __restrict__ Wkt,
    const float* __restrict__ Wvt,
    ushort_t* __restrict__ q, ushort_t* __restrict__ k, ushort_t* __restrict__ v) {
  __shared__ float ins[16*388];
  int bnb = blockIdx.x * 16;
  int t = threadIdx.x;
  for (int idx = t; idx < 16*96; idx += 256) {
    int pt = idx / 96, j4 = (idx % 96) * 4;
    *(float4*)&ins[pt*388 + j4] = *(const float4*)&in[((size_t)bnb + pt)*384 + j4];
  }
  __syncthreads();
  int po = t & 7;
  int og = t >> 3;
  for (int pass = 0; pass < 9; ++pass) {
    int which = pass / 3;
    int om_ = (pass % 3) * 128 + og * 4;
    const float* W = (which == 0) ? Wqt : (which == 1) ? Wkt : Wvt;
    float a[2][4][3];
#pragma unroll
    for (int pp = 0; pp < 2; ++pp)
#pragma unroll
      for (int uu = 0; uu < 4; ++uu)
#pragma unroll
        for (int d = 0; d < 3; ++d) a[pp][uu][d] = 0.f;
    for (int ci = 0; ci < 32; ++ci) {
      float wv[4][4];
#pragma unroll
      for (int cc = 0; cc < 4; ++cc) {
        float4 wt = *(const float4*)&W[(size_t)(4*ci+cc)*384 + om_];
        wv[cc][0]=wt.x; wv[cc][1]=wt.y; wv[cc][2]=wt.z; wv[cc][3]=wt.w;
      }
#pragma unroll
      for (int pp = 0; pp < 2; ++pp) {
        const float* ip = &ins[(2*po+pp)*388 + 12*ci];
        float vals[12];
        LOAD12(vals, ip);
#pragma unroll
        for (int cc = 0; cc < 4; ++cc)
#pragma unroll
          for (int uu = 0; uu < 4; ++uu)
#pragma unroll
            for (int d = 0; d < 3; ++d)
              a[pp][uu][d] += wv[cc][uu] * vals[cc*3+d];
      }
    }
    ushort_t* op = (which == 0) ? q : (which == 1) ? k : v;
    float scl = (which == 0) ? QSCALE : 1.0f;
#pragma unroll
    for (int pp = 0; pp < 2; ++pp) {
      size_t rb = ((size_t)bnb + 2*po + pp) * 1152 + (size_t)om_*3;
      ushort_t tmp[12];
#pragma unroll
      for (int uu = 0; uu < 4; ++uu)
#pragma unroll
        for (int d = 0; d < 3; ++d)
          tmp[uu*3+d] = f2bf(a[pp][uu][d] * scl);
      uint_t* wp = (uint_t*)&op[rb];
#pragma unroll
      for (int j = 0; j < 6; ++j)
        wp[j] = (uint_t)tmp[2*j] | ((uint_t)tmp[2*j+1] << 16);
    }
  }
}

// ---------------- V transpose: v[bn][1152] -> vT[(bh*192+ch)*2048 + pt] ----------------
__global__ __launch_bounds__(256) void vtrans_kernel(const ushort_t* __restrict__ v,
                                                     ushort_t* __restrict__ vT) {
  int T = blockIdx.x * 256 + threadIdx.x;   // BN*1152/8 chunks
  int pt0 = (T & 255) * 8;
  int row = T >> 8;                          // row = bh*192 + ch, 4608 rows
  int bh = row / 192, ch = row % 192;
  int b = bh / HH, h = bh % HH;
  ushort_t tmp[8];
#pragma unroll
  for (int i = 0; i < 8; ++i)
    tmp[i] = v[(size_t)(b*NFIX + pt0 + i)*1152 + h*192 + ch];
  uint4 o;
  o.x = (uint_t)tmp[0] | ((uint_t)tmp[1] << 16);
  o.y = (uint_t)tmp[2] | ((uint_t)tmp[3] << 16);
  o.z = (uint_t)tmp[4] | ((uint_t)tmp[5] << 16);
  o.w = (uint_t)tmp[6] | ((uint_t)tmp[7] << 16);
  *(uint4*)&vT[(size_t)row*2048 + pt0] = o;
}

// ---------------- attention: MFMA flash (no-max softmax), 1 wave / 32 q rows ----------------
// S^T = K*Q^T (32x32x16 bf16 MFMA): C col=lane&31=q, row=(r&3)+8*(r>>2)+4*hl = k-point
// P round-trips LDS (pitch 68) to become A-operand of O += P*V (V pre-transposed).
__global__ __launch_bounds__(64) void attn_kernel(const ushort_t* __restrict__ q,
    const ushort_t* __restrict__ k, const ushort_t* __restrict__ vT,
    float* __restrict__ o) {
  __shared__ ushort_t plds[32*68];
  __shared__ float alds[32];
  int w = blockIdx.x;
  int qt = w & 63, bh = w >> 6;
  int b = bh / HH, h = bh % HH;
  int lane = threadIdx.x;
  int ql = lane & 31, hl = lane >> 5;
  const ushort_t* qp = q + (size_t)(b*NFIX + qt*32 + ql)*1152 + h*192 + hl*8;
  bf16x8 qf[12];
#pragma unroll
  for (int cs = 0; cs < 12; ++cs) qf[cs] = *(const bf16x8*)(qp + cs*16);
  f32x16 acc[6];
#pragma unroll
  for (int nt = 0; nt < 6; ++nt)
#pragma unroll
    for (int r = 0; r < 16; ++r) acc[nt][r] = 0.f;
  float lsum = 0.f;
  const ushort_t* kbp = k + (size_t)(b*NFIX + ql)*1152 + h*192 + hl*8;
  const ushort_t* vbp = vT + ((size_t)bh*192 + ql)*2048 + hl*8;
  for (int kb = 0; kb < NFIX/64; ++kb) {
    f32x16 sc[2];
#pragma unroll
    for (int r = 0; r < 16; ++r) { sc[0][r] = 0.f; sc[1][r] = 0.f; }
    const ushort_t* k0 = kbp + (size_t)(kb*64)*1152;
    const ushort_t* k1 = k0 + 32*1152;
#pragma unroll
    for (int cs = 0; cs < 12; ++cs) {
      bf16x8 a0 = *(const bf16x8*)(k0 + cs*16);
      bf16x8 a1 = *(const bf16x8*)(k1 + cs*16);
      sc[0] = __builtin_amdgcn_mfma_f32_32x32x16_bf16(a0, qf[cs], sc[0], 0, 0, 0);
      sc[1] = __builtin_amdgcn_mfma_f32_32x32x16_bf16(a1, qf[cs], sc[1], 0, 0, 0);
    }
    // exp2 (scale already folded into Q), pack to bf16, write P[q][k] to LDS
#pragma unroll
    for (int mt = 0; mt < 2; ++mt) {
#pragma unroll
      for (int g2 = 0; g2 < 4; ++g2) {
        bf16x4 pw;
#pragma unroll
        for (int rr = 0; rr < 4; ++rr) {
          float p = __builtin_amdgcn_exp2f(sc[mt][g2*4 + rr]);
          lsum += p;
          pw[rr] = (short)f2bf(p);
        }
        *(bf16x4*)&plds[ql*68 + mt*32 + g2*8 + hl*4] = pw;
      }
    }
    asm volatile("s_waitcnt lgkmcnt(0)" ::: "memory");
    // O += P*V
#pragma unroll
    for (int s = 0; s < 4; ++s) {
      const ushort_t* pr = &plds[ql*68 + s*16 + hl*8];
      bf16x4 lo = *(const bf16x4*)pr;
      bf16x4 hi = *(const bf16x4*)(pr + 4);
      bf16x8 pa = __builtin_shufflevector(lo, hi, 0, 1, 2, 3, 4, 5, 6, 7);
      const ushort_t* vp = vbp + kb*64 + s*16;
#pragma unroll
      for (int nt = 0; nt < 6; ++nt) {
        bf16x8 vf = *(const bf16x8*)(vp + (size_t)nt*32*2048);
        acc[nt] = __builtin_amdgcn_mfma_f32_32x32x16_bf16(pa, vf, acc[nt], 0, 0, 0);
      }
    }
  }
  lsum += __shfl_xor(lsum, 32);
  if (lane < 32) alds[ql] = 1.0f / lsum;
  asm volatile("s_waitcnt lgkmcnt(0)" ::: "memory");
  float lv[4][4];
#pragma unroll
  for (int g2 = 0; g2 < 4; ++g2) {
    f32x4 t = *(const f32x4*)&alds[8*g2 + 4*hl];
#pragma unroll
    for (int rr = 0; rr < 4; ++rr) lv[g2][rr] = t[rr];
  }
  float* op = o + (size_t)(b*NFIX + qt*32)*1152 + h*192 + ql;
#pragma unroll
  for (int nt = 0; nt < 6; ++nt)
#pragma unroll
    for (int r = 0; r < 16; ++r) {
      int qrow = (r&3) + 8*(r>>2) + 4*hl;
      op[(size_t)qrow*1152 + nt*32] = acc[nt][r] * lv[r>>2][r&3];
    }
}

// ---------------- knn gather + conv1 + mean over K ----------------
__global__ __launch_bounds__(128) void conv1_kernel(const float* __restrict__ normx,
    const int* __restrict__ knn_index,
    const float* __restrict__ W1t, const float* __restrict__ U1t,
    float* __restrict__ knnmean) {
  __shared__ float xc[384];
  __shared__ float feats[KNN*384];
  __shared__ int sidx[KNN];
  int bn = blockIdx.x;
  int b = bn / NFIX, n = bn % NFIX;
  int t = threadIdx.x;
  if (t < KNN) sidx[t] = knn_index[(b*KNN + t)*NFIX + n];
  for (int idx = t; idx < 96; idx += 128)
    *(float4*)&xc[idx*4] = *(const float4*)&normx[(size_t)bn*384 + idx*4];
  __syncthreads();
  for (int idx = t; idx < KNN*96; idx += 128) {
    int kk = idx / 96, j4 = (idx % 96) * 4;
    *(float4*)&feats[kk*384 + j4] = *(const float4*)&normx[(size_t)sidx[kk]*384 + j4];
  }
  __syncthreads();
  int o = t;
  float p[KNN][3], dd[KNN][3];
#pragma unroll
  for (int kk = 0; kk < KNN; ++kk)
#pragma unroll
    for (int d = 0; d < 3; ++d) { p[kk][d] = 0.f; dd[kk][d] = 0.f; }
  for (int ci = 0; ci < 32; ++ci) {
    float w1[4], w1b[4], u1[4], u1b[4];
#pragma unroll
    for (int cc = 0; cc < 4; ++cc) {
      int c = 4*ci + cc;
      w1[cc]  = W1t[c*128 + o];
      w1b[cc] = W1t[(128+c)*128 + o];
      u1[cc]  = U1t[c*128 + o];
      u1b[cc] = U1t[(128+c)*128 + o];
    }
    float xv[12];
    LOAD12(xv, &xc[12*ci]);
#pragma unroll
    for (int kk = 0; kk < KNN; ++kk) {
      float fv[12];
      LOAD12(fv, &feats[kk*384 + 12*ci]);
#pragma unroll
      for (int cc = 0; cc < 4; ++cc)
#pragma unroll
        for (int d = 0; d < 3; ++d) {
          float xcv = xv[cc*3+d];
          float fa = fv[cc*3+d] - xcv;
          p[kk][d]  += w1[cc]*fa + w1b[cc]*xcv;
          dd[kk][d] += u1[cc]*fa + u1b[cc]*xcv;
        }
    }
  }
  float om[3] = {0.f, 0.f, 0.f};
#pragma unroll
  for (int kk = 0; kk < KNN; ++kk) {
    float res[3];
    vnleaky3(p[kk], dd[kk], res);
    om[0] += res[0]; om[1] += res[1]; om[2] += res[2];
  }
  size_t ob = (size_t)bn*384 + o*3;
  knnmean[ob+0] = om[0] * (1.f/KNN);
  knnmean[ob+1] = om[1] * (1.f/KNN);
  knnmean[ob+2] = om[2] * (1.f/KNN);
}

// ---------------- x_mid = x + M @ o_attn + W2b @ knnmean ----------------
__global__ __launch_bounds__(128) void x1mid_kernel(const float* __restrict__ x,
    const float* __restrict__ oattn, const float* __restrict__ knnm,
    const float* __restrict__ Mt, const float* __restrict__ W2bt,
    float* __restrict__ out) {
  __shared__ float os[8*1156];
  __shared__ float ksm[8*388];
  int bnb = blockIdx.x * 8;
  int t = threadIdx.x;
  for (int idx = t; idx < 8*288; idx += 128) {
    int pt = idx / 288, j4 = (idx % 288) * 4;
    *(float4*)&os[pt*1156 + j4] = *(const float4*)&oattn[((size_t)bnb + pt)*1152 + j4];
  }
  for (int idx = t; idx < 8*96; idx += 128) {
    int pt = idx / 96, j4 = (idx % 96) * 4;
    *(float4*)&ksm[pt*388 + j4] = *(const float4*)&knnm[((size_t)bnb + pt)*384 + j4];
  }
  __syncthreads();
  int tc = t & 31;
  int tp = t >> 5;
  float acc[4][2][3];
#pragma unroll
  for (int u = 0; u < 4; ++u)
#pragma unroll
    for (int pp = 0; pp < 2; ++pp)
#pragma unroll
      for (int d = 0; d < 3; ++d)
        acc[u][pp][d] = x[((size_t)bnb + 2*tp + pp)*384 + (tc + 32*u)*3 + d];
  for (int oi = 0; oi < 96; ++oi) {
    float w[4][4];
#pragma unroll
    for (int oo = 0; oo < 4; ++oo)
#pragma unroll
      for (int u = 0; u < 4; ++u)
        w[oo][u] = Mt[(size_t)(4*oi+oo)*128 + tc + 32*u];
#pragma unroll
    for (int pp = 0; pp < 2; ++pp) {
      float vals[12];
      LOAD12(vals, &os[(2*tp+pp)*1156 + 12*oi]);
#pragma unroll
      for (int oo = 0; oo < 4; ++oo)
#pragma unroll
        for (int u = 0; u < 4; ++u)
#pragma unroll
          for (int d = 0; d < 3; ++d)
            acc[u][pp][d] += w[oo][u] * vals[oo*3+d];
    }
  }
  for (int ci = 0; ci < 32; ++ci) {
    float w[4][4];
#pragma unroll
    for (int cc = 0; cc < 4; ++cc)
#pragma unroll
      for (int u = 0; u < 4; ++u)
        w[cc][u] = W2bt[(size_t)(4*ci+cc)*128 + tc + 32*u];
#pragma unroll
    for (int pp = 0; pp < 2; ++pp) {
      float vals[12];
      LOAD12(vals, &ksm[(2*tp+pp)*388 + 12*ci]);
#pragma unroll
      for (int cc = 0; cc < 4; ++cc)
#pragma unroll
        for (int u = 0; u < 4; ++u)
#pragma unroll
          for (int d = 0; d < 3; ++d)
            acc[u][pp][d] += w[cc][u] * vals[cc*3+d];
    }
  }
#pragma unroll
  for (int u = 0; u < 4; ++u)
#pragma unroll
    for (int pp = 0; pp < 2; ++pp)
#pragma unroll
      for (int d = 0; d < 3; ++d)
        out[((size_t)bnb + 2*tp + pp)*384 + (tc + 32*u)*3 + d] = acc[u][pp][d];
}

// ---------------- conv3: VNLinearLeakyReLU 128 -> 256 ----------------
__global__ __launch_bounds__(256) void conv3_kernel(const float* __restrict__ in,
    const float* __restrict__ W3t, const float* __restrict__ U3t,
    float* __restrict__ h3) {
  __shared__ float ins[4*384];
  int bnb = blockIdx.x * 4;
  int t = threadIdx.x;
  for (int idx = t; idx < 4*96; idx += 256)
    *(float4*)&ins[idx*4] = *(const float4*)&in[(size_t)bnb*384 + idx*4];
  __syncthreads();
  float p[4][3], dd[4][3];
#pragma unroll
  for (int pt = 0; pt < 4; ++pt)
#pragma unroll
    for (int d = 0; d < 3; ++d) { p[pt][d] = 0.f; dd[pt][d] = 0.f; }
  for (int ci = 0; ci < 32; ++ci) {
    float w3[4], u3[4];
#pragma unroll
    for (int cc = 0; cc < 4; ++cc) {
      int c = 4*ci + cc;
      w3[cc] = W3t[c*256 + t];
      u3[cc] = U3t[c*256 + t];
    }
#pragma unroll
    for (int pt = 0; pt < 4; ++pt) {
      float vals[12];
      LOAD12(vals, &ins[pt*384 + 12*ci]);
#pragma unroll
      for (int cc = 0; cc < 4; ++cc)
#pragma unroll
        for (int d = 0; d < 3; ++d) {
          float xv = vals[cc*3+d];
          p[pt][d]  += w3[cc]*xv;
          dd[pt][d] += u3[cc]*xv;
        }
    }
  }
#pragma unroll
  for (int pt = 0; pt < 4; ++pt) {
    float res[3];
    vnleaky3(p[pt], dd[pt], res);
    size_t ob = ((size_t)bnb + pt)*768 + t*3;
    h3[ob+0] = res[0]; h3[ob+1] = res[1]; h3[ob+2] = res[2];
  }
}

// ---------------- conv4: VNLinearLeakyReLU 256 -> 128, + residual ----------------
__global__ __launch_bounds__(128) void conv4_kernel(const float* __restrict__ h3,
    const float* __restrict__ W4t, const float* __restrict__ U4t,
    float* __restrict__ out) {
  __shared__ float ins[4*768];
  int bnb = blockIdx.x * 4;
  int t = threadIdx.x;
  for (int idx = t; idx < 4*192; idx += 128)
    *(float4*)&ins[idx*4] = *(const float4*)&h3[(size_t)bnb*768 + idx*4];
  __syncthreads();
  float p[4][3], dd[4][3];
#pragma unroll
  for (int pt = 0; pt < 4; ++pt)
#pragma unroll
    for (int d = 0; d < 3; ++d) { p[pt][d] = 0.f; dd[pt][d] = 0.f; }
  for (int ci = 0; ci < 64; ++ci) {
    float w4[4], u4[4];
#pragma unroll
    for (int cc = 0; cc < 4; ++cc) {
      int c2 = 4*ci + cc;
      w4[cc] = W4t[c2*128 + t];
      u4[cc] = U4t[c2*128 + t];
    }
#pragma unroll
    for (int pt = 0; pt < 4; ++pt) {
      float vals[12];
      LOAD12(vals, &ins[pt*768 + 12*ci]);
#pragma unroll
      for (int cc = 0; cc < 4; ++cc)
#pragma unroll
        for (int d = 0; d < 3; ++d) {
          float xv = vals[cc*3+d];
          p[pt][d]  += w4[cc]*xv;
          dd[pt][d] += u4[cc]*xv;
        }
    }
  }
#pragma unroll
  for (int pt = 0; pt < 4; ++pt) {
    float res[3];
    vnleaky3(p[pt], dd[pt], res);
    float* orow = out + ((size_t)bnb + pt)*384 + t*3;
    orow[0] += res[0]; orow[1] += res[1]; orow[2] += res[2];
  }
}

extern "C" void kernel_launch(void* const* d_in, const int* in_sizes, int n_in,
                              void* d_out, int out_size, void* d_ws, size_t ws_size,
                              hipStream_t stream) {
  const float* x   = (const float*)d_in[0];
  const int* knn   = (const int*)d_in[1];
  const float* g1  = (const float*)d_in[2];
  const float* b1  = (const float*)d_in[3];
  const float* g2  = (const float*)d_in[4];
  const float* b2  = (const float*)d_in[5];
  const float* Wq  = (const float*)d_in[6];
  const float* Wk  = (const float*)d_in[7];
  const float* Wv  = (const float*)d_in[8];
  const float* Wo  = (const float*)d_in[9];
  const float* W1  = (const float*)d_in[10];
  const float* U1  = (const float*)d_in[11];
  const float* W2  = (const float*)d_in[12];
  const float* W3  = (const float*)d_in[13];
  const float* U3  = (const float*)d_in[14];
  const float* W4  = (const float*)d_in[15];
  const float* U4  = (const float*)d_in[16];
  float* out = (float*)d_out;
  (void)n_in; (void)out_size; (void)ws_size;

  const size_t BN = (size_t)in_sizes[0] / 384;   // 8192

  float* ws    = (float*)d_ws;
  float* normx = ws;                        // BN*384 f32
  float* obuf  = normx + BN*384;            // BN*1152 f32
  float* knnm  = obuf + BN*1152;            // BN*384 f32
  ushort_t* qb = (ushort_t*)(knnm + BN*384);  // BN*1152 bf16
  ushort_t* kb = qb + BN*1152;
  ushort_t* vb = kb + BN*1152;
  ushort_t* vT = vb + BN*1152;
  float* wsp   = (float*)(vT + BN*1152);
  float* Wqt  = wsp;
  float* Wkt  = Wqt + 49152;
  float* Wvt  = Wkt + 49152;
  float* W1t  = Wvt + 49152;
  float* U1t  = W1t + 32768;
  float* W3t  = U1t + 32768;
  float* U3t  = W3t + 32768;
  float* W4t  = U3t + 32768;
  float* U4t  = W4t + 32768;
  float* W2bt = U4t + 32768;
  float* Mt   = W2bt + 16384;
  float* nx2 = (float*)qb;   // q dead after attention (BN*384 f32 fits in BN*1152 bf16)
  float* h3  = (float*)kb;   // k/v dead after attention (BN*768 f32 fits in k+v bf16)

  prep_weights<<<1600, 256, 0, stream>>>(Wq, Wk, Wv, Wo, W1, U1, W2, W3, U3, W4, U4,
                                         Wqt, Wkt, Wvt, W1t, U1t, W3t, U3t, W4t, U4t,
                                         W2bt, Mt);
  ln_kernel<<<(int)BN, 128, 0, stream>>>(x, normx, g1, b1);
  qkv_kernel<<<(int)(BN/16), 256, 0, stream>>>(normx, Wqt, Wkt, Wvt, qb, kb, vb);
  vtrans_kernel<<<(int)(BN*1152/8/256), 256, 0, stream>>>(vb, vT);
  attn_kernel<<<(int)((NFIX/32)*4*HH), 64, 0, stream>>>(qb, kb, vT, obuf);
  conv1_kernel<<<(int)BN, 128, 0, stream>>>(normx, knn, W1t, U1t, knnm);
  x1mid_kernel<<<(int)(BN/8), 128, 0, stream>>>(x, obuf, knnm, Mt, W2bt, out);
  ln_kernel<<<(int)BN, 128, 0, stream>>>(out, nx2, g2, b2);
  conv3_kernel<<<(int)(BN/4), 256, 0, stream>>>(nx2, W3t, U3t, h3);
  conv4_kernel<<<(int)(BN/4), 128, 0, stream>>>(h3, W4t, U4t, out);
}

// Round 3
// 1020.308 us; speedup vs baseline: 2.9858x; 1.4208x over previous
//
#include <hip/hip_runtime.h>
#include <math.h>

// Problem constants (fixed by setup_inputs): B=4, N=2048, C=128, H=6, K=8
#define NFIX 2048
#define HH 6
#define KNN 8
#define NSLOPE 0.2f
#define EPSF 1e-6f
#define LNEPSF 1e-5f
// 0.125 (softmax scale) * log2(e), folded into bf16 Q so S-MFMA output is exp2-ready
#define QSCALE 0.18033688011112042f

typedef unsigned short ushort_t;
typedef unsigned int uint_t;
typedef __attribute__((ext_vector_type(8))) short bf16x8;
typedef __attribute__((ext_vector_type(4))) short bf16x4;
typedef __attribute__((ext_vector_type(16))) float f32x16;
typedef __attribute__((ext_vector_type(4))) float f32x4;

__device__ __forceinline__ ushort_t f2bf(float f) {
  union { float f; unsigned u; } v; v.f = f;
  unsigned r = v.u + 0x7fff + ((v.u >> 16) & 1);   // RNE
  return (ushort_t)(r >> 16);
}

#define LOAD12(dst, ptr) { \
  float4 _r0 = *(const float4*)((ptr));   \
  float4 _r1 = *(const float4*)((ptr)+4); \
  float4 _r2 = *(const float4*)((ptr)+8); \
  dst[0]=_r0.x; dst[1]=_r0.y; dst[2]=_r0.z; dst[3]=_r0.w; \
  dst[4]=_r1.x; dst[5]=_r1.y; dst[6]=_r1.z; dst[7]=_r1.w; \
  dst[8]=_r2.x; dst[9]=_r2.y; dst[10]=_r2.z; dst[11]=_r2.w; }

__device__ __forceinline__ void vnleaky3(const float* p, const float* dv, float* out) {
  float dot = p[0]*dv[0] + p[1]*dv[1] + p[2]*dv[2];
  float dsq = dv[0]*dv[0] + dv[1]*dv[1] + dv[2]*dv[2] + EPSF;
  float f = dot / dsq;
#pragma unroll
  for (int d = 0; d < 3; ++d) {
    float neg = p[d] - f * dv[d];
    out[d] = NSLOPE * p[d] + (1.f - NSLOPE) * ((dot >= 0.f) ? p[d] : neg);
  }
}

// ---------------- weight prep ----------------
// segments: Wqt 49152 | Wkt 49152 | Wvt 49152 | CWt 65536 | W3t 32768 | U3t 32768 |
//           W4t 32768 | U4t 32768 | W2bt 16384 | Mt 49152    (total 409600 = 1600*256)
__global__ void prep_weights(const float* __restrict__ Wq, const float* __restrict__ Wk,
                             const float* __restrict__ Wv, const float* __restrict__ Wo,
                             const float* __restrict__ W1, const float* __restrict__ U1,
                             const float* __restrict__ W2, const float* __restrict__ W3,
                             const float* __restrict__ U3, const float* __restrict__ W4,
                             const float* __restrict__ U4,
                             float* __restrict__ Wqt, float* __restrict__ Wkt,
                             float* __restrict__ Wvt, float* __restrict__ CWt,
                             float* __restrict__ W3t, float* __restrict__ U3t,
                             float* __restrict__ W4t, float* __restrict__ U4t,
                             float* __restrict__ W2bt, float* __restrict__ Mt) {
  int idx = blockIdx.x * 256 + threadIdx.x;
  if (idx < 49152) { int c = idx / 384, o = idx % 384; Wqt[idx] = Wq[o*128 + c]; return; }
  idx -= 49152;
  if (idx < 49152) { int c = idx / 384, o = idx % 384; Wkt[idx] = Wk[o*128 + c]; return; }
  idx -= 49152;
  if (idx < 49152) { int c = idx / 384, o = idx % 384; Wvt[idx] = Wv[o*128 + c]; return; }
  idx -= 49152;
  if (idx < 65536) {
    int c = idx / 512, j = idx % 512;
    float val;
    if (j < 128)      val = W1[j*256 + c];                              // W1a
    else if (j < 256) val = U1[(j-128)*256 + c];                        // U1a
    else if (j < 384) { int o = j-256; val = W1[o*256 + 128 + c] - W1[o*256 + c]; }
    else              { int o = j-384; val = U1[o*256 + 128 + c] - U1[o*256 + c]; }
    CWt[idx] = val; return;
  }
  idx -= 65536;
  if (idx < 32768) { int c = idx / 256, o = idx % 256; W3t[idx] = W3[o*128 + c]; return; }
  idx -= 32768;
  if (idx < 32768) { int c = idx / 256, o = idx % 256; U3t[idx] = U3[o*128 + c]; return; }
  idx -= 32768;
  if (idx < 32768) { int c = idx / 128, o = idx % 128; W4t[idx] = W4[o*256 + c]; return; }
  idx -= 32768;
  if (idx < 32768) { int c = idx / 128, o = idx % 128; U4t[idx] = U4[o*256 + c]; return; }
  idx -= 32768;
  if (idx < 16384) { int c2 = idx / 128, c = idx % 128; W2bt[idx] = W2[c*256 + 128 + c2]; return; }
  idx -= 16384;
  if (idx < 49152) {
    int o = idx / 128, c = idx % 128;
    float s = 0.f;
    for (int cp = 0; cp < 128; ++cp) s += W2[c*256 + cp] * Wo[cp*384 + o];
    Mt[idx] = s;
  }
}

// ---------------- VN LayerNorm ----------------
__global__ __launch_bounds__(128) void ln_kernel(const float* __restrict__ in,
                                                 float* __restrict__ out,
                                                 const float* __restrict__ g,
                                                 const float* __restrict__ b) {
  int bn = blockIdx.x;
  int c = threadIdx.x;
  const float* row = in + (size_t)bn * 384;
  float x0 = row[c*3+0], x1 = row[c*3+1], x2 = row[c*3+2];
  float nv = sqrtf(x0*x0 + x1*x1 + x2*x2 + EPSF);
  float s1 = nv, s2 = nv*nv;
#pragma unroll
  for (int off = 32; off >= 1; off >>= 1) {
    s1 += __shfl_down(s1, off);
    s2 += __shfl_down(s2, off);
  }
  __shared__ float red[4];
  int lane = threadIdx.x & 63, w = threadIdx.x >> 6;
  if (lane == 0) { red[w*2] = s1; red[w*2+1] = s2; }
  __syncthreads();
  float tot1 = red[0] + red[2], tot2 = red[1] + red[3];
  float mu  = tot1 * (1.f/128.f);
  float var = tot2 * (1.f/128.f) - mu*mu;
  float rsig = rsqrtf(var + LNEPSF);
  float nnew = g[c] * ((nv - mu) * rsig) + b[c];
  float sc = nnew / nv;
  float* orow = out + (size_t)bn * 384;
  orow[c*3+0] = x0*sc; orow[c*3+1] = x1*sc; orow[c*3+2] = x2*sc;
}

// ---------------- conv1 GEMM: [Y|Z] and [YB|ZB] = CW @ normx ----------------
// block = 256 thr, 16 points. 4 passes of 128 out-channels; pass0->YZ[0:384),
// pass1->YZ[384:768), pass2->NB[0:384), pass3->NB[384:768).
__global__ __launch_bounds__(256) void conv1_gemm(const float* __restrict__ in,
    const float* __restrict__ CWt,
    float* __restrict__ YZ, float* __restrict__ NB) {
  __shared__ float ins[16*388];
  int bnb = blockIdx.x * 16;
  int t = threadIdx.x;
  for (int idx = t; idx < 16*96; idx += 256) {
    int pt = idx / 96, j4 = (idx % 96) * 4;
    *(float4*)&ins[pt*388 + j4] = *(const float4*)&in[((size_t)bnb + pt)*384 + j4];
  }
  __syncthreads();
  int po = t & 7;
  int og = t >> 3;
  for (int pass = 0; pass < 4; ++pass) {
    int j0 = pass * 128 + og * 4;
    float a[2][4][3];
#pragma unroll
    for (int pp = 0; pp < 2; ++pp)
#pragma unroll
      for (int uu = 0; uu < 4; ++uu)
#pragma unroll
        for (int d = 0; d < 3; ++d) a[pp][uu][d] = 0.f;
    for (int ci = 0; ci < 32; ++ci) {
      float wv[4][4];
#pragma unroll
      for (int cc = 0; cc < 4; ++cc) {
        float4 wt = *(const float4*)&CWt[(size_t)(4*ci+cc)*512 + j0];
        wv[cc][0]=wt.x; wv[cc][1]=wt.y; wv[cc][2]=wt.z; wv[cc][3]=wt.w;
      }
#pragma unroll
      for (int pp = 0; pp < 2; ++pp) {
        float vals[12];
        LOAD12(vals, &ins[(2*po+pp)*388 + 12*ci]);
#pragma unroll
        for (int cc = 0; cc < 4; ++cc)
#pragma unroll
          for (int uu = 0; uu < 4; ++uu)
#pragma unroll
            for (int d = 0; d < 3; ++d)
              a[pp][uu][d] += wv[cc][uu] * vals[cc*3+d];
      }
    }
    float* dst = (pass < 2) ? YZ : NB;
    int off = (pass & 1) * 384 + og * 12;
#pragma unroll
    for (int pp = 0; pp < 2; ++pp) {
      size_t rb = ((size_t)bnb + 2*po + pp) * 768 + off;
#pragma unroll
      for (int uu = 0; uu < 4; ++uu)
#pragma unroll
        for (int d = 0; d < 3; ++d)
          dst[rb + uu*3 + d] = a[pp][uu][d];
    }
  }
}

// ---------------- conv1 post: gather + add + vnleaky + mean over K ----------------
__global__ __launch_bounds__(128) void conv1_post(const float* __restrict__ YZ,
    const float* __restrict__ NB, const int* __restrict__ knn_index,
    float* __restrict__ knnm) {
  int bn = blockIdx.x;
  int b = bn / NFIX, n = bn % NFIX;
  int t = threadIdx.x;
  __shared__ int sidx[KNN];
  if (t < KNN) sidx[t] = knn_index[(b*KNN + t)*NFIX + n];
  __syncthreads();
  const float* nbp = NB + (size_t)bn*768 + t*3;
  float yb[3], zb[3];
#pragma unroll
  for (int d = 0; d < 3; ++d) { yb[d] = nbp[d]; zb[d] = nbp[384 + d]; }
  float om[3] = {0.f, 0.f, 0.f};
#pragma unroll
  for (int kk = 0; kk < KNN; ++kk) {
    const float* r = YZ + (size_t)sidx[kk]*768 + t*3;
    float p[3], dd[3];
#pragma unroll
    for (int d = 0; d < 3; ++d) { p[d] = r[d] + yb[d]; dd[d] = r[384 + d] + zb[d]; }
    float res[3];
    vnleaky3(p, dd, res);
    om[0] += res[0]; om[1] += res[1]; om[2] += res[2];
  }
  size_t ob = (size_t)bn*384 + t*3;
  knnm[ob+0] = om[0] * (1.f/KNN);
  knnm[ob+1] = om[1] * (1.f/KNN);
  knnm[ob+2] = om[2] * (1.f/KNN);
}

// ---------------- QKV projection -> bf16 (q pre-scaled by QSCALE) ----------------
__global__ __launch_bounds__(256) void qkv_kernel(const float* __restrict__ in,
    const float* __restrict__ Wqt, const float* __restrict__ Wkt,
    const float* __restrict__ Wvt,
    ushort_t* __restrict__ q, ushort_t* __restrict__ k, ushort_t* __restrict__ v) {
  __shared__ float ins[16*388];
  int bnb = blockIdx.x * 16;
  int t = threadIdx.x;
  for (int idx = t; idx < 16*96; idx += 256) {
    int pt = idx / 96, j4 = (idx % 96) * 4;
    *(float4*)&ins[pt*388 + j4] = *(const float4*)&in[((size_t)bnb + pt)*384 + j4];
  }
  __syncthreads();
  int po = t & 7;
  int og = t >> 3;
  for (int pass = 0; pass < 9; ++pass) {
    int which = pass / 3;
    int om_ = (pass % 3) * 128 + og * 4;
    const float* W = (which == 0) ? Wqt : (which == 1) ? Wkt : Wvt;
    float a[2][4][3];
#pragma unroll
    for (int pp = 0; pp < 2; ++pp)
#pragma unroll
      for (int uu = 0; uu < 4; ++uu)
#pragma unroll
        for (int d = 0; d < 3; ++d) a[pp][uu][d] = 0.f;
    for (int ci = 0; ci < 32; ++ci) {
      float wv[4][4];
#pragma unroll
      for (int cc = 0; cc < 4; ++cc) {
        float4 wt = *(const float4*)&W[(size_t)(4*ci+cc)*384 + om_];
        wv[cc][0]=wt.x; wv[cc][1]=wt.y; wv[cc][2]=wt.z; wv[cc][3]=wt.w;
      }
#pragma unroll
      for (int pp = 0; pp < 2; ++pp) {
        const float* ip = &ins[(2*po+pp)*388 + 12*ci];
        float vals[12];
        LOAD12(vals, ip);
#pragma unroll
        for (int cc = 0; cc < 4; ++cc)
#pragma unroll
          for (int uu = 0; uu < 4; ++uu)
#pragma unroll
            for (int d = 0; d < 3; ++d)
              a[pp][uu][d] += wv[cc][uu] * vals[cc*3+d];
      }
    }
    ushort_t* op = (which == 0) ? q : (which == 1) ? k : v;
    float scl = (which == 0) ? QSCALE : 1.0f;
#pragma unroll
    for (int pp = 0; pp < 2; ++pp) {
      size_t rb = ((size_t)bnb + 2*po + pp) * 1152 + (size_t)om_*3;
      ushort_t tmp[12];
#pragma unroll
      for (int uu = 0; uu < 4; ++uu)
#pragma unroll
        for (int d = 0; d < 3; ++d)
          tmp[uu*3+d] = f2bf(a[pp][uu][d] * scl);
      uint_t* wp = (uint_t*)&op[rb];
#pragma unroll
      for (int j = 0; j < 6; ++j)
        wp[j] = (uint_t)tmp[2*j] | ((uint_t)tmp[2*j+1] << 16);
    }
  }
}

// ---------------- V transpose ----------------
__global__ __launch_bounds__(256) void vtrans_kernel(const ushort_t* __restrict__ v,
                                                     ushort_t* __restrict__ vT) {
  int T = blockIdx.x * 256 + threadIdx.x;
  int pt0 = (T & 255) * 8;
  int row = T >> 8;
  int bh = row / 192, ch = row % 192;
  int b = bh / HH, h = bh % HH;
  ushort_t tmp[8];
#pragma unroll
  for (int i = 0; i < 8; ++i)
    tmp[i] = v[(size_t)(b*NFIX + pt0 + i)*1152 + h*192 + ch];
  uint4 o;
  o.x = (uint_t)tmp[0] | ((uint_t)tmp[1] << 16);
  o.y = (uint_t)tmp[2] | ((uint_t)tmp[3] << 16);
  o.z = (uint_t)tmp[4] | ((uint_t)tmp[5] << 16);
  o.w = (uint_t)tmp[6] | ((uint_t)tmp[7] << 16);
  *(uint4*)&vT[(size_t)row*2048 + pt0] = o;
}

// ---------------- attention: MFMA flash (no-max softmax), 1 wave / 32 q rows ----------------
__global__ __launch_bounds__(64) void attn_kernel(const ushort_t* __restrict__ q,
    const ushort_t* __restrict__ k, const ushort_t* __restrict__ vT,
    float* __restrict__ o) {
  __shared__ ushort_t plds[32*68];
  __shared__ float alds[32];
  int w = blockIdx.x;
  int qt = w & 63, bh = w >> 6;
  int b = bh / HH, h = bh % HH;
  int lane = threadIdx.x;
  int ql = lane & 31, hl = lane >> 5;
  const ushort_t* qp = q + (size_t)(b*NFIX + qt*32 + ql)*1152 + h*192 + hl*8;
  bf16x8 qf[12];
#pragma unroll
  for (int cs = 0; cs < 12; ++cs) qf[cs] = *(const bf16x8*)(qp + cs*16);
  f32x16 acc[6];
#pragma unroll
  for (int nt = 0; nt < 6; ++nt)
#pragma unroll
    for (int r = 0; r < 16; ++r) acc[nt][r] = 0.f;
  float lsum = 0.f;
  const ushort_t* kbp = k + (size_t)(b*NFIX + ql)*1152 + h*192 + hl*8;
  const ushort_t* vbp = vT + ((size_t)bh*192 + ql)*2048 + hl*8;
  for (int kb = 0; kb < NFIX/64; ++kb) {
    f32x16 sc[2];
#pragma unroll
    for (int r = 0; r < 16; ++r) { sc[0][r] = 0.f; sc[1][r] = 0.f; }
    const ushort_t* k0 = kbp + (size_t)(kb*64)*1152;
    const ushort_t* k1 = k0 + 32*1152;
#pragma unroll
    for (int cs = 0; cs < 12; ++cs) {
      bf16x8 a0 = *(const bf16x8*)(k0 + cs*16);
      bf16x8 a1 = *(const bf16x8*)(k1 + cs*16);
      sc[0] = __builtin_amdgcn_mfma_f32_32x32x16_bf16(a0, qf[cs], sc[0], 0, 0, 0);
      sc[1] = __builtin_amdgcn_mfma_f32_32x32x16_bf16(a1, qf[cs], sc[1], 0, 0, 0);
    }
#pragma unroll
    for (int mt = 0; mt < 2; ++mt) {
#pragma unroll
      for (int g2 = 0; g2 < 4; ++g2) {
        bf16x4 pw;
#pragma unroll
        for (int rr = 0; rr < 4; ++rr) {
          float p = __builtin_amdgcn_exp2f(sc[mt][g2*4 + rr]);
          lsum += p;
          pw[rr] = (short)f2bf(p);
        }
        *(bf16x4*)&plds[ql*68 + mt*32 + g2*8 + hl*4] = pw;
      }
    }
    asm volatile("s_waitcnt lgkmcnt(0)" ::: "memory");
#pragma unroll
    for (int s = 0; s < 4; ++s) {
      const ushort_t* pr = &plds[ql*68 + s*16 + hl*8];
      bf16x4 lo = *(const bf16x4*)pr;
      bf16x4 hi = *(const bf16x4*)(pr + 4);
      bf16x8 pa = __builtin_shufflevector(lo, hi, 0, 1, 2, 3, 4, 5, 6, 7);
      const ushort_t* vp = vbp + kb*64 + s*16;
#pragma unroll
      for (int nt = 0; nt < 6; ++nt) {
        bf16x8 vf = *(const bf16x8*)(vp + (size_t)nt*32*2048);
        acc[nt] = __builtin_amdgcn_mfma_f32_32x32x16_bf16(pa, vf, acc[nt], 0, 0, 0);
      }
    }
  }
  lsum += __shfl_xor(lsum, 32);
  if (lane < 32) alds[ql] = 1.0f / lsum;
  asm volatile("s_waitcnt lgkmcnt(0)" ::: "memory");
  float lv[4][4];
#pragma unroll
  for (int g2 = 0; g2 < 4; ++g2) {
    f32x4 tv = *(const f32x4*)&alds[8*g2 + 4*hl];
#pragma unroll
    for (int rr = 0; rr < 4; ++rr) lv[g2][rr] = tv[rr];
  }
  float* op = o + (size_t)(b*NFIX + qt*32)*1152 + h*192 + ql;
#pragma unroll
  for (int nt = 0; nt < 6; ++nt)
#pragma unroll
    for (int r = 0; r < 16; ++r) {
      int qrow = (r&3) + 8*(r>>2) + 4*hl;
      op[(size_t)qrow*1152 + nt*32] = acc[nt][r] * lv[r>>2][r&3];
    }
}

// ---------------- x_mid = x + M @ o_attn + W2b @ knnmean ----------------
__global__ __launch_bounds__(128) void x1mid_kernel(const float* __restrict__ x,
    const float* __restrict__ oattn, const float* __restrict__ knnm,
    const float* __restrict__ Mt, const float* __restrict__ W2bt,
    float* __restrict__ out) {
  __shared__ float os[8*1156];
  __shared__ float ksm[8*388];
  int bnb = blockIdx.x * 8;
  int t = threadIdx.x;
  for (int idx = t; idx < 8*288; idx += 128) {
    int pt = idx / 288, j4 = (idx % 288) * 4;
    *(float4*)&os[pt*1156 + j4] = *(const float4*)&oattn[((size_t)bnb + pt)*1152 + j4];
  }
  for (int idx = t; idx < 8*96; idx += 128) {
    int pt = idx / 96, j4 = (idx % 96) * 4;
    *(float4*)&ksm[pt*388 + j4] = *(const float4*)&knnm[((size_t)bnb + pt)*384 + j4];
  }
  __syncthreads();
  int tc = t & 31;
  int tp = t >> 5;
  float acc[4][2][3];
#pragma unroll
  for (int u = 0; u < 4; ++u)
#pragma unroll
    for (int pp = 0; pp < 2; ++pp)
#pragma unroll
      for (int d = 0; d < 3; ++d)
        acc[u][pp][d] = x[((size_t)bnb + 2*tp + pp)*384 + (tc + 32*u)*3 + d];
  for (int oi = 0; oi < 96; ++oi) {
    float w[4][4];
#pragma unroll
    for (int oo = 0; oo < 4; ++oo)
#pragma unroll
      for (int u = 0; u < 4; ++u)
        w[oo][u] = Mt[(size_t)(4*oi+oo)*128 + tc + 32*u];
#pragma unroll
    for (int pp = 0; pp < 2; ++pp) {
      float vals[12];
      LOAD12(vals, &os[(2*tp+pp)*1156 + 12*oi]);
#pragma unroll
      for (int oo = 0; oo < 4; ++oo)
#pragma unroll
        for (int u = 0; u < 4; ++u)
#pragma unroll
          for (int d = 0; d < 3; ++d)
            acc[u][pp][d] += w[oo][u] * vals[oo*3+d];
    }
  }
  for (int ci = 0; ci < 32; ++ci) {
    float w[4][4];
#pragma unroll
    for (int cc = 0; cc < 4; ++cc)
#pragma unroll
      for (int u = 0; u < 4; ++u)
        w[cc][u] = W2bt[(size_t)(4*ci+cc)*128 + tc + 32*u];
#pragma unroll
    for (int pp = 0; pp < 2; ++pp) {
      float vals[12];
      LOAD12(vals, &ksm[(2*tp+pp)*388 + 12*ci]);
#pragma unroll
      for (int cc = 0; cc < 4; ++cc)
#pragma unroll
        for (int u = 0; u < 4; ++u)
#pragma unroll
          for (int d = 0; d < 3; ++d)
            acc[u][pp][d] += w[cc][u] * vals[cc*3+d];
    }
  }
#pragma unroll
  for (int u = 0; u < 4; ++u)
#pragma unroll
    for (int pp = 0; pp < 2; ++pp)
#pragma unroll
      for (int d = 0; d < 3; ++d)
        out[((size_t)bnb + 2*tp + pp)*384 + (tc + 32*u)*3 + d] = acc[u][pp][d];
}

// ---------------- conv3: VNLinearLeakyReLU 128 -> 256 ----------------
__global__ __launch_bounds__(256) void conv3_kernel(const float* __restrict__ in,
    const float* __restrict__ W3t, const float* __restrict__ U3t,
    float* __restrict__ h3) {
  __shared__ float ins[4*384];
  int bnb = blockIdx.x * 4;
  int t = threadIdx.x;
  for (int idx = t; idx < 4*96; idx += 256)
    *(float4*)&ins[idx*4] = *(const float4*)&in[(size_t)bnb*384 + idx*4];
  __syncthreads();
  float p[4][3], dd[4][3];
#pragma unroll
  for (int pt = 0; pt < 4; ++pt)
#pragma unroll
    for (int d = 0; d < 3; ++d) { p[pt][d] = 0.f; dd[pt][d] = 0.f; }
  for (int ci = 0; ci < 32; ++ci) {
    float w3[4], u3[4];
#pragma unroll
    for (int cc = 0; cc < 4; ++cc) {
      int c = 4*ci + cc;
      w3[cc] = W3t[c*256 + t];
      u3[cc] = U3t[c*256 + t];
    }
#pragma unroll
    for (int pt = 0; pt < 4; ++pt) {
      float vals[12];
      LOAD12(vals, &ins[pt*384 + 12*ci]);
#pragma unroll
      for (int cc = 0; cc < 4; ++cc)
#pragma unroll
        for (int d = 0; d < 3; ++d) {
          float xv = vals[cc*3+d];
          p[pt][d]  += w3[cc]*xv;
          dd[pt][d] += u3[cc]*xv;
        }
    }
  }
#pragma unroll
  for (int pt = 0; pt < 4; ++pt) {
    float res[3];
    vnleaky3(p[pt], dd[pt], res);
    size_t ob = ((size_t)bnb + pt)*768 + t*3;
    h3[ob+0] = res[0]; h3[ob+1] = res[1]; h3[ob+2] = res[2];
  }
}

// ---------------- conv4: VNLinearLeakyReLU 256 -> 128, + residual ----------------
__global__ __launch_bounds__(128) void conv4_kernel(const float* __restrict__ h3,
    const float* __restrict__ W4t, const float* __restrict__ U4t,
    float* __restrict__ out) {
  __shared__ float ins[4*768];
  int bnb = blockIdx.x * 4;
  int t = threadIdx.x;
  for (int idx = t; idx < 4*192; idx += 128)
    *(float4*)&ins[idx*4] = *(const float4*)&h3[(size_t)bnb*768 + idx*4];
  __syncthreads();
  float p[4][3], dd[4][3];
#pragma unroll
  for (int pt = 0; pt < 4; ++pt)
#pragma unroll
    for (int d = 0; d < 3; ++d) { p[pt][d] = 0.f; dd[pt][d] = 0.f; }
  for (int ci = 0; ci < 64; ++ci) {
    float w4[4], u4[4];
#pragma unroll
    for (int cc = 0; cc < 4; ++cc) {
      int c2 = 4*ci + cc;
      w4[cc] = W4t[c2*128 + t];
      u4[cc] = U4t[c2*128 + t];
    }
#pragma unroll
    for (int pt = 0; pt < 4; ++pt) {
      float vals[12];
      LOAD12(vals, &ins[pt*768 + 12*ci]);
#pragma unroll
      for (int cc = 0; cc < 4; ++cc)
#pragma unroll
        for (int d = 0; d < 3; ++d) {
          float xv = vals[cc*3+d];
          p[pt][d]  += w4[cc]*xv;
          dd[pt][d] += u4[cc]*xv;
        }
    }
  }
#pragma unroll
  for (int pt = 0; pt < 4; ++pt) {
    float res[3];
    vnleaky3(p[pt], dd[pt], res);
    float* orow = out + ((size_t)bnb + pt)*384 + t*3;
    orow[0] += res[0]; orow[1] += res[1]; orow[2] += res[2];
  }
}

extern "C" void kernel_launch(void* const* d_in, const int* in_sizes, int n_in,
                              void* d_out, int out_size, void* d_ws, size_t ws_size,
                              hipStream_t stream) {
  const float* x   = (const float*)d_in[0];
  const int* knn   = (const int*)d_in[1];
  const float* g1  = (const float*)d_in[2];
  const float* b1  = (const float*)d_in[3];
  const float* g2  = (const float*)d_in[4];
  const float* b2  = (const float*)d_in[5];
  const float* Wq  = (const float*)d_in[6];
  const float* Wk  = (const float*)d_in[7];
  const float* Wv  = (const float*)d_in[8];
  const float* Wo  = (const float*)d_in[9];
  const float* W1  = (const float*)d_in[10];
  const float* U1  = (const float*)d_in[11];
  const float* W2  = (const float*)d_in[12];
  const float* W3  = (const float*)d_in[13];
  const float* U3  = (const float*)d_in[14];
  const float* W4  = (const float*)d_in[15];
  const float* U4  = (const float*)d_in[16];
  float* out = (float*)d_out;
  (void)n_in; (void)out_size; (void)ws_size;

  const size_t BN = (size_t)in_sizes[0] / 384;   // 8192

  float* ws    = (float*)d_ws;
  float* normx = ws;                          // BN*384 f32
  float* obuf  = normx + BN*384;              // BN*1152 f32
  float* knnm  = obuf + BN*1152;              // BN*384 f32
  ushort_t* qb = (ushort_t*)(knnm + BN*384);  // BN*1152 bf16
  ushort_t* kb = qb + BN*1152;
  ushort_t* vb = kb + BN*1152;
  ushort_t* vT = vb + BN*1152;
  float* wsp   = (float*)(vT + BN*1152);
  float* Wqt  = wsp;
  float* Wkt  = Wqt + 49152;
  float* Wvt  = Wkt + 49152;
  float* CWt  = Wvt + 49152;
  float* W3t  = CWt + 65536;
  float* U3t  = W3t + 32768;
  float* W4t  = U3t + 32768;
  float* U4t  = W4t + 32768;
  float* W2bt = U4t + 32768;
  float* Mt   = W2bt + 16384;
  // YZ/NB (BN*768 f32 each) alias the q/k/v bf16 region: conv1 runs BEFORE qkv.
  float* YZ = (float*)qb;              // BN*768 f32 = BN*3072 B, fits in qb+kb (BN*4608 B)
  float* NB = YZ + BN*768;             // next BN*3072 B, fits before end of vT region
  float* nx2 = (float*)qb;   // q dead after attention
  float* h3  = (float*)kb;   // k/v dead after attention

  prep_weights<<<1600, 256, 0, stream>>>(Wq, Wk, Wv, Wo, W1, U1, W2, W3, U3, W4, U4,
                                         Wqt, Wkt, Wvt, CWt, W3t, U3t, W4t, U4t,
                                         W2bt, Mt);
  ln_kernel<<<(int)BN, 128, 0, stream>>>(x, normx, g1, b1);
  conv1_gemm<<<(int)(BN/16), 256, 0, stream>>>(normx, CWt, YZ, NB);
  conv1_post<<<(int)BN, 128, 0, stream>>>(YZ, NB, knn, knnm);
  qkv_kernel<<<(int)(BN/16), 256, 0, stream>>>(normx, Wqt, Wkt, Wvt, qb, kb, vb);
  vtrans_kernel<<<(int)(BN*1152/8/256), 256, 0, stream>>>(vb, vT);
  attn_kernel<<<(int)((NFIX/32)*4*HH), 64, 0, stream>>>(qb, kb, vT, obuf);
  x1mid_kernel<<<(int)(BN/8), 128, 0, stream>>>(x, obuf, knnm, Mt, W2bt, out);
  ln_kernel<<<(int)BN, 128, 0, stream>>>(out, nx2, g2, b2);
  conv3_kernel<<<(int)(BN/4), 256, 0, stream>>>(nx2, W3t, U3t, h3);
  conv4_kernel<<<(int)(BN/4), 128, 0, stream>>>(h3, W4t, U4t, out);
}

// Round 4
// 1011.313 us; speedup vs baseline: 3.0123x; 1.0089x over previous
//
#include <hip/hip_runtime.h>
#include <math.h>

// Problem constants (fixed by setup_inputs): B=4, N=2048, C=128, H=6, K=8
#define NFIX 2048
#define HH 6
#define KNN 8
#define NSLOPE 0.2f
#define EPSF 1e-6f
#define LNEPSF 1e-5f
// 0.125 (softmax scale) * log2(e), folded into bf16 Q so S-MFMA output is exp2-ready
#define QSCALE 0.18033688011112042f

typedef unsigned short ushort_t;
typedef unsigned int uint_t;
typedef __attribute__((ext_vector_type(8))) short bf16x8;
typedef __attribute__((ext_vector_type(4))) short bf16x4;
typedef __attribute__((ext_vector_type(16))) float f32x16;
typedef __attribute__((ext_vector_type(4))) float f32x4;

__device__ __forceinline__ ushort_t f2bf(float f) {
  union { float f; unsigned u; } v; v.f = f;
  unsigned r = v.u + 0x7fff + ((v.u >> 16) & 1);   // RNE
  return (ushort_t)(r >> 16);
}

#define LOAD12(dst, ptr) { \
  float4 _r0 = *(const float4*)((ptr));   \
  float4 _r1 = *(const float4*)((ptr)+4); \
  float4 _r2 = *(const float4*)((ptr)+8); \
  dst[0]=_r0.x; dst[1]=_r0.y; dst[2]=_r0.z; dst[3]=_r0.w; \
  dst[4]=_r1.x; dst[5]=_r1.y; dst[6]=_r1.z; dst[7]=_r1.w; \
  dst[8]=_r2.x; dst[9]=_r2.y; dst[10]=_r2.z; dst[11]=_r2.w; }

__device__ __forceinline__ void vnleaky3(const float* p, const float* dv, float* out) {
  float dot = p[0]*dv[0] + p[1]*dv[1] + p[2]*dv[2];
  float dsq = dv[0]*dv[0] + dv[1]*dv[1] + dv[2]*dv[2] + EPSF;
  float f = dot / dsq;
#pragma unroll
  for (int d = 0; d < 3; ++d) {
    float neg = p[d] - f * dv[d];
    out[d] = NSLOPE * p[d] + (1.f - NSLOPE) * ((dot >= 0.f) ? p[d] : neg);
  }
}

// ---------------- weight prep ----------------
// segments: Wqt 49152 | Wkt 49152 | Wvt 49152 | CWt 65536 | W3t 32768 | U3t 32768 |
//           W4t 32768 | U4t 32768 | W2bt 16384 | Mt 49152    (total 409600 = 1600*256)
__global__ void prep_weights(const float* __restrict__ Wq, const float* __restrict__ Wk,
                             const float* __restrict__ Wv, const float* __restrict__ Wo,
                             const float* __restrict__ W1, const float* __restrict__ U1,
                             const float* __restrict__ W2, const float* __restrict__ W3,
                             const float* __restrict__ U3, const float* __restrict__ W4,
                             const float* __restrict__ U4,
                             float* __restrict__ Wqt, float* __restrict__ Wkt,
                             float* __restrict__ Wvt, float* __restrict__ CWt,
                             float* __restrict__ W3t, float* __restrict__ U3t,
                             float* __restrict__ W4t, float* __restrict__ U4t,
                             float* __restrict__ W2bt, float* __restrict__ Mt) {
  int idx = blockIdx.x * 256 + threadIdx.x;
  if (idx < 49152) { int c = idx / 384, o = idx % 384; Wqt[idx] = Wq[o*128 + c]; return; }
  idx -= 49152;
  if (idx < 49152) { int c = idx / 384, o = idx % 384; Wkt[idx] = Wk[o*128 + c]; return; }
  idx -= 49152;
  if (idx < 49152) { int c = idx / 384, o = idx % 384; Wvt[idx] = Wv[o*128 + c]; return; }
  idx -= 49152;
  if (idx < 65536) {
    int c = idx / 512, j = idx % 512;
    float val;
    if (j < 128)      val = W1[j*256 + c];                              // W1a
    else if (j < 256) val = U1[(j-128)*256 + c];                        // U1a
    else if (j < 384) { int o = j-256; val = W1[o*256 + 128 + c] - W1[o*256 + c]; }
    else              { int o = j-384; val = U1[o*256 + 128 + c] - U1[o*256 + c]; }
    CWt[idx] = val; return;
  }
  idx -= 65536;
  if (idx < 32768) { int c = idx / 256, o = idx % 256; W3t[idx] = W3[o*128 + c]; return; }
  idx -= 32768;
  if (idx < 32768) { int c = idx / 256, o = idx % 256; U3t[idx] = U3[o*128 + c]; return; }
  idx -= 32768;
  if (idx < 32768) { int c = idx / 128, o = idx % 128; W4t[idx] = W4[o*256 + c]; return; }
  idx -= 32768;
  if (idx < 32768) { int c = idx / 128, o = idx % 128; U4t[idx] = U4[o*256 + c]; return; }
  idx -= 32768;
  if (idx < 16384) { int c2 = idx / 128, c = idx % 128; W2bt[idx] = W2[c*256 + 128 + c2]; return; }
  idx -= 16384;
  if (idx < 49152) {
    int o = idx / 128, c = idx % 128;
    float s = 0.f;
    for (int cp = 0; cp < 128; ++cp) s += W2[c*256 + cp] * Wo[cp*384 + o];
    Mt[idx] = s;
  }
}

// ---------------- VN LayerNorm ----------------
__global__ __launch_bounds__(128) void ln_kernel(const float* __restrict__ in,
                                                 float* __restrict__ out,
                                                 const float* __restrict__ g,
                                                 const float* __restrict__ b) {
  int bn = blockIdx.x;
  int c = threadIdx.x;
  const float* row = in + (size_t)bn * 384;
  float x0 = row[c*3+0], x1 = row[c*3+1], x2 = row[c*3+2];
  float nv = sqrtf(x0*x0 + x1*x1 + x2*x2 + EPSF);
  float s1 = nv, s2 = nv*nv;
#pragma unroll
  for (int off = 32; off >= 1; off >>= 1) {
    s1 += __shfl_down(s1, off);
    s2 += __shfl_down(s2, off);
  }
  __shared__ float red[4];
  int lane = threadIdx.x & 63, w = threadIdx.x >> 6;
  if (lane == 0) { red[w*2] = s1; red[w*2+1] = s2; }
  __syncthreads();
  float tot1 = red[0] + red[2], tot2 = red[1] + red[3];
  float mu  = tot1 * (1.f/128.f);
  float var = tot2 * (1.f/128.f) - mu*mu;
  float rsig = rsqrtf(var + LNEPSF);
  float nnew = g[c] * ((nv - mu) * rsig) + b[c];
  float sc = nnew / nv;
  float* orow = out + (size_t)bn * 384;
  orow[c*3+0] = x0*sc; orow[c*3+1] = x1*sc; orow[c*3+2] = x2*sc;
}

// ---------------- conv1 GEMM: [Y|Z] and [YB|ZB] = CW @ normx ----------------
__global__ __launch_bounds__(256) void conv1_gemm(const float* __restrict__ in,
    const float* __restrict__ CWt,
    float* __restrict__ YZ, float* __restrict__ NB) {
  __shared__ float ins[16*388];
  int bnb = blockIdx.x * 16;
  int t = threadIdx.x;
  for (int idx = t; idx < 16*96; idx += 256) {
    int pt = idx / 96, j4 = (idx % 96) * 4;
    *(float4*)&ins[pt*388 + j4] = *(const float4*)&in[((size_t)bnb + pt)*384 + j4];
  }
  __syncthreads();
  int po = t & 7;
  int og = t >> 3;
  for (int pass = 0; pass < 4; ++pass) {
    int j0 = pass * 128 + og * 4;
    float a[2][4][3];
#pragma unroll
    for (int pp = 0; pp < 2; ++pp)
#pragma unroll
      for (int uu = 0; uu < 4; ++uu)
#pragma unroll
        for (int d = 0; d < 3; ++d) a[pp][uu][d] = 0.f;
    for (int ci = 0; ci < 32; ++ci) {
      float wv[4][4];
#pragma unroll
      for (int cc = 0; cc < 4; ++cc) {
        float4 wt = *(const float4*)&CWt[(size_t)(4*ci+cc)*512 + j0];
        wv[cc][0]=wt.x; wv[cc][1]=wt.y; wv[cc][2]=wt.z; wv[cc][3]=wt.w;
      }
#pragma unroll
      for (int pp = 0; pp < 2; ++pp) {
        float vals[12];
        LOAD12(vals, &ins[(2*po+pp)*388 + 12*ci]);
#pragma unroll
        for (int cc = 0; cc < 4; ++cc)
#pragma unroll
          for (int uu = 0; uu < 4; ++uu)
#pragma unroll
            for (int d = 0; d < 3; ++d)
              a[pp][uu][d] += wv[cc][uu] * vals[cc*3+d];
      }
    }
    float* dst = (pass < 2) ? YZ : NB;
    int off = (pass & 1) * 384 + og * 12;
#pragma unroll
    for (int pp = 0; pp < 2; ++pp) {
      size_t rb = ((size_t)bnb + 2*po + pp) * 768 + off;
#pragma unroll
      for (int uu = 0; uu < 4; ++uu)
#pragma unroll
        for (int d = 0; d < 3; ++d)
          dst[rb + uu*3 + d] = a[pp][uu][d];
    }
  }
}

// ---------------- conv1 post: gather + add + vnleaky + mean over K ----------------
__global__ __launch_bounds__(128) void conv1_post(const float* __restrict__ YZ,
    const float* __restrict__ NB, const int* __restrict__ knn_index,
    float* __restrict__ knnm) {
  int bn = blockIdx.x;
  int b = bn / NFIX, n = bn % NFIX;
  int t = threadIdx.x;
  __shared__ int sidx[KNN];
  if (t < KNN) sidx[t] = knn_index[(b*KNN + t)*NFIX + n];
  __syncthreads();
  const float* nbp = NB + (size_t)bn*768 + t*3;
  float yb[3], zb[3];
#pragma unroll
  for (int d = 0; d < 3; ++d) { yb[d] = nbp[d]; zb[d] = nbp[384 + d]; }
  float om[3] = {0.f, 0.f, 0.f};
#pragma unroll
  for (int kk = 0; kk < KNN; ++kk) {
    const float* r = YZ + (size_t)sidx[kk]*768 + t*3;
    float p[3], dd[3];
#pragma unroll
    for (int d = 0; d < 3; ++d) { p[d] = r[d] + yb[d]; dd[d] = r[384 + d] + zb[d]; }
    float res[3];
    vnleaky3(p, dd, res);
    om[0] += res[0]; om[1] += res[1]; om[2] += res[2];
  }
  size_t ob = (size_t)bn*384 + t*3;
  knnm[ob+0] = om[0] * (1.f/KNN);
  knnm[ob+1] = om[1] * (1.f/KNN);
  knnm[ob+2] = om[2] * (1.f/KNN);
}

// ---------------- QKV projection -> bf16 (q pre-scaled by QSCALE) ----------------
__global__ __launch_bounds__(256) void qkv_kernel(const float* __restrict__ in,
    const float* __restrict__ Wqt, const float* __restrict__ Wkt,
    const float* __restrict__ Wvt,
    ushort_t* __restrict__ q, ushort_t* __restrict__ k, ushort_t* __restrict__ v) {
  __shared__ float ins[16*388];
  int bnb = blockIdx.x * 16;
  int t = threadIdx.x;
  for (int idx = t; idx < 16*96; idx += 256) {
    int pt = idx / 96, j4 = (idx % 96) * 4;
    *(float4*)&ins[pt*388 + j4] = *(const float4*)&in[((size_t)bnb + pt)*384 + j4];
  }
  __syncthreads();
  int po = t & 7;
  int og = t >> 3;
  for (int pass = 0; pass < 9; ++pass) {
    int which = pass / 3;
    int om_ = (pass % 3) * 128 + og * 4;
    const float* W = (which == 0) ? Wqt : (which == 1) ? Wkt : Wvt;
    float a[2][4][3];
#pragma unroll
    for (int pp = 0; pp < 2; ++pp)
#pragma unroll
      for (int uu = 0; uu < 4; ++uu)
#pragma unroll
        for (int d = 0; d < 3; ++d) a[pp][uu][d] = 0.f;
    for (int ci = 0; ci < 32; ++ci) {
      float wv[4][4];
#pragma unroll
      for (int cc = 0; cc < 4; ++cc) {
        float4 wt = *(const float4*)&W[(size_t)(4*ci+cc)*384 + om_];
        wv[cc][0]=wt.x; wv[cc][1]=wt.y; wv[cc][2]=wt.z; wv[cc][3]=wt.w;
      }
#pragma unroll
      for (int pp = 0; pp < 2; ++pp) {
        const float* ip = &ins[(2*po+pp)*388 + 12*ci];
        float vals[12];
        LOAD12(vals, ip);
#pragma unroll
        for (int cc = 0; cc < 4; ++cc)
#pragma unroll
          for (int uu = 0; uu < 4; ++uu)
#pragma unroll
            for (int d = 0; d < 3; ++d)
              a[pp][uu][d] += wv[cc][uu] * vals[cc*3+d];
      }
    }
    ushort_t* op = (which == 0) ? q : (which == 1) ? k : v;
    float scl = (which == 0) ? QSCALE : 1.0f;
#pragma unroll
    for (int pp = 0; pp < 2; ++pp) {
      size_t rb = ((size_t)bnb + 2*po + pp) * 1152 + (size_t)om_*3;
      ushort_t tmp[12];
#pragma unroll
      for (int uu = 0; uu < 4; ++uu)
#pragma unroll
        for (int d = 0; d < 3; ++d)
          tmp[uu*3+d] = f2bf(a[pp][uu][d] * scl);
      uint_t* wp = (uint_t*)&op[rb];
#pragma unroll
      for (int j = 0; j < 6; ++j)
        wp[j] = (uint_t)tmp[2*j] | ((uint_t)tmp[2*j+1] << 16);
    }
  }
}

// ---------------- V transpose ----------------
__global__ __launch_bounds__(256) void vtrans_kernel(const ushort_t* __restrict__ v,
                                                     ushort_t* __restrict__ vT) {
  int T = blockIdx.x * 256 + threadIdx.x;
  int pt0 = (T & 255) * 8;
  int row = T >> 8;
  int bh = row / 192, ch = row % 192;
  int b = bh / HH, h = bh % HH;
  ushort_t tmp[8];
#pragma unroll
  for (int i = 0; i < 8; ++i)
    tmp[i] = v[(size_t)(b*NFIX + pt0 + i)*1152 + h*192 + ch];
  uint4 o;
  o.x = (uint_t)tmp[0] | ((uint_t)tmp[1] << 16);
  o.y = (uint_t)tmp[2] | ((uint_t)tmp[3] << 16);
  o.z = (uint_t)tmp[4] | ((uint_t)tmp[5] << 16);
  o.w = (uint_t)tmp[6] | ((uint_t)tmp[7] << 16);
  *(uint4*)&vT[(size_t)row*2048 + pt0] = o;
}

// ---------------- attention: MFMA flash, split-K (2 halves), 1 wave / 32 q rows ----------------
// grid = 64 qtiles * 24 bh * 2 splits. Each wave computes its half's softmax-normalized
// partial O (by its own lsum) + stores lsum; attn_combine merges.
__global__ __launch_bounds__(64, 3) void attn_kernel(const ushort_t* __restrict__ q,
    const ushort_t* __restrict__ k, const ushort_t* __restrict__ vT,
    float* __restrict__ o0, float* __restrict__ o1, float* __restrict__ lpart) {
  __shared__ ushort_t plds[32*68];
  __shared__ float alds[32];
  int w = blockIdx.x;
  int qt = w % 64;
  int bh = (w / 64) % 24;
  int split = w / (64*24);
  int b = bh / HH, h = bh % HH;
  int lane = threadIdx.x;
  int ql = lane & 31, hl = lane >> 5;
  const ushort_t* qp = q + (size_t)(b*NFIX + qt*32 + ql)*1152 + h*192 + hl*8;
  bf16x8 qf[12];
#pragma unroll
  for (int cs = 0; cs < 12; ++cs) qf[cs] = *(const bf16x8*)(qp + cs*16);
  f32x16 acc[6];
#pragma unroll
  for (int nt = 0; nt < 6; ++nt)
#pragma unroll
    for (int r = 0; r < 16; ++r) acc[nt][r] = 0.f;
  float lsum = 0.f;
  const ushort_t* kbp = k + (size_t)(b*NFIX + ql)*1152 + h*192 + hl*8;
  const ushort_t* vbp = vT + ((size_t)bh*192 + ql)*2048 + hl*8;
  for (int kb = split*16; kb < split*16 + 16; ++kb) {
    f32x16 sc[2];
#pragma unroll
    for (int r = 0; r < 16; ++r) { sc[0][r] = 0.f; sc[1][r] = 0.f; }
    const ushort_t* k0 = kbp + (size_t)(kb*64)*1152;
    const ushort_t* k1 = k0 + 32*1152;
#pragma unroll
    for (int cs = 0; cs < 12; ++cs) {
      bf16x8 a0 = *(const bf16x8*)(k0 + cs*16);
      bf16x8 a1 = *(const bf16x8*)(k1 + cs*16);
      sc[0] = __builtin_amdgcn_mfma_f32_32x32x16_bf16(a0, qf[cs], sc[0], 0, 0, 0);
      sc[1] = __builtin_amdgcn_mfma_f32_32x32x16_bf16(a1, qf[cs], sc[1], 0, 0, 0);
    }
#pragma unroll
    for (int mt = 0; mt < 2; ++mt) {
#pragma unroll
      for (int g2 = 0; g2 < 4; ++g2) {
        bf16x4 pw;
#pragma unroll
        for (int rr = 0; rr < 4; ++rr) {
          float p = __builtin_amdgcn_exp2f(sc[mt][g2*4 + rr]);
          lsum += p;
          pw[rr] = (short)f2bf(p);
        }
        *(bf16x4*)&plds[ql*68 + mt*32 + g2*8 + hl*4] = pw;
      }
    }
    asm volatile("s_waitcnt lgkmcnt(0)" ::: "memory");
#pragma unroll
    for (int s = 0; s < 4; ++s) {
      const ushort_t* pr = &plds[ql*68 + s*16 + hl*8];
      bf16x4 lo = *(const bf16x4*)pr;
      bf16x4 hi = *(const bf16x4*)(pr + 4);
      bf16x8 pa = __builtin_shufflevector(lo, hi, 0, 1, 2, 3, 4, 5, 6, 7);
      const ushort_t* vp = vbp + kb*64 + s*16;
#pragma unroll
      for (int nt = 0; nt < 6; ++nt) {
        bf16x8 vf = *(const bf16x8*)(vp + (size_t)nt*32*2048);
        acc[nt] = __builtin_amdgcn_mfma_f32_32x32x16_bf16(pa, vf, acc[nt], 0, 0, 0);
      }
    }
  }
  lsum += __shfl_xor(lsum, 32);
  if (lane < 32) {
    alds[ql] = 1.0f / lsum;
    lpart[(size_t)split*24*NFIX + (size_t)bh*NFIX + qt*32 + ql] = lsum;
  }
  asm volatile("s_waitcnt lgkmcnt(0)" ::: "memory");
  float lv[4][4];
#pragma unroll
  for (int g2 = 0; g2 < 4; ++g2) {
    f32x4 tv = *(const f32x4*)&alds[8*g2 + 4*hl];
#pragma unroll
    for (int rr = 0; rr < 4; ++rr) lv[g2][rr] = tv[rr];
  }
  float* ob = split ? o1 : o0;
  float* op = ob + (size_t)(b*NFIX + qt*32)*1152 + h*192 + ql;
#pragma unroll
  for (int nt = 0; nt < 6; ++nt)
#pragma unroll
    for (int r = 0; r < 16; ++r) {
      int qrow = (r&3) + 8*(r>>2) + 4*hl;
      op[(size_t)qrow*1152 + nt*32] = acc[nt][r] * lv[r>>2][r&3];
    }
}

// ---------------- combine split-K partials: o0 = (o0*l0 + o1*l1)/(l0+l1) in-place ----------------
__global__ __launch_bounds__(256) void attn_combine(float* __restrict__ o0,
    const float* __restrict__ o1, const float* __restrict__ lpart) {
  size_t i = ((size_t)blockIdx.x * 256 + threadIdx.x) * 4;
  int bn = (int)(i / 1152);
  int ch = (int)(i % 1152);
  int b = bn >> 11, n = bn & 2047;
  int h = ch / 192;
  size_t lidx = (size_t)(b*HH + h)*NFIX + n;
  float l0 = lpart[lidx], l1 = lpart[(size_t)24*NFIX + lidx];
  float rd = 1.f / (l0 + l1);
  float w0 = l0 * rd, w1 = l1 * rd;
  float4 a = *(float4*)&o0[i];
  float4 c = *(const float4*)&o1[i];
  a.x = a.x*w0 + c.x*w1;
  a.y = a.y*w0 + c.y*w1;
  a.z = a.z*w0 + c.z*w1;
  a.w = a.w*w0 + c.w*w1;
  *(float4*)&o0[i] = a;
}

// ---------------- x_mid = x + M @ o_attn + W2b @ knnmean ----------------
__global__ __launch_bounds__(128) void x1mid_kernel(const float* __restrict__ x,
    const float* __restrict__ oattn, const float* __restrict__ knnm,
    const float* __restrict__ Mt, const float* __restrict__ W2bt,
    float* __restrict__ out) {
  __shared__ float os[8*1156];
  __shared__ float ksm[8*388];
  int bnb = blockIdx.x * 8;
  int t = threadIdx.x;
  for (int idx = t; idx < 8*288; idx += 128) {
    int pt = idx / 288, j4 = (idx % 288) * 4;
    *(float4*)&os[pt*1156 + j4] = *(const float4*)&oattn[((size_t)bnb + pt)*1152 + j4];
  }
  for (int idx = t; idx < 8*96; idx += 128) {
    int pt = idx / 96, j4 = (idx % 96) * 4;
    *(float4*)&ksm[pt*388 + j4] = *(const float4*)&knnm[((size_t)bnb + pt)*384 + j4];
  }
  __syncthreads();
  int tc = t & 31;
  int tp = t >> 5;
  float acc[4][2][3];
#pragma unroll
  for (int u = 0; u < 4; ++u)
#pragma unroll
    for (int pp = 0; pp < 2; ++pp)
#pragma unroll
      for (int d = 0; d < 3; ++d)
        acc[u][pp][d] = x[((size_t)bnb + 2*tp + pp)*384 + (tc + 32*u)*3 + d];
  for (int oi = 0; oi < 96; ++oi) {
    float w[4][4];
#pragma unroll
    for (int oo = 0; oo < 4; ++oo)
#pragma unroll
      for (int u = 0; u < 4; ++u)
        w[oo][u] = Mt[(size_t)(4*oi+oo)*128 + tc + 32*u];
#pragma unroll
    for (int pp = 0; pp < 2; ++pp) {
      float vals[12];
      LOAD12(vals, &os[(2*tp+pp)*1156 + 12*oi]);
#pragma unroll
      for (int oo = 0; oo < 4; ++oo)
#pragma unroll
        for (int u = 0; u < 4; ++u)
#pragma unroll
          for (int d = 0; d < 3; ++d)
            acc[u][pp][d] += w[oo][u] * vals[oo*3+d];
    }
  }
  for (int ci = 0; ci < 32; ++ci) {
    float w[4][4];
#pragma unroll
    for (int cc = 0; cc < 4; ++cc)
#pragma unroll
      for (int u = 0; u < 4; ++u)
        w[cc][u] = W2bt[(size_t)(4*ci+cc)*128 + tc + 32*u];
#pragma unroll
    for (int pp = 0; pp < 2; ++pp) {
      float vals[12];
      LOAD12(vals, &ksm[(2*tp+pp)*388 + 12*ci]);
#pragma unroll
      for (int cc = 0; cc < 4; ++cc)
#pragma unroll
        for (int u = 0; u < 4; ++u)
#pragma unroll
          for (int d = 0; d < 3; ++d)
            acc[u][pp][d] += w[cc][u] * vals[cc*3+d];
    }
  }
#pragma unroll
  for (int u = 0; u < 4; ++u)
#pragma unroll
    for (int pp = 0; pp < 2; ++pp)
#pragma unroll
      for (int d = 0; d < 3; ++d)
        out[((size_t)bnb + 2*tp + pp)*384 + (tc + 32*u)*3 + d] = acc[u][pp][d];
}

// ---------------- conv3: VNLinearLeakyReLU 128 -> 256 ----------------
__global__ __launch_bounds__(256) void conv3_kernel(const float* __restrict__ in,
    const float* __restrict__ W3t, const float* __restrict__ U3t,
    float* __restrict__ h3) {
  __shared__ float ins[4*384];
  int bnb = blockIdx.x * 4;
  int t = threadIdx.x;
  for (int idx = t; idx < 4*96; idx += 256)
    *(float4*)&ins[idx*4] = *(const float4*)&in[(size_t)bnb*384 + idx*4];
  __syncthreads();
  float p[4][3], dd[4][3];
#pragma unroll
  for (int pt = 0; pt < 4; ++pt)
#pragma unroll
    for (int d = 0; d < 3; ++d) { p[pt][d] = 0.f; dd[pt][d] = 0.f; }
  for (int ci = 0; ci < 32; ++ci) {
    float w3[4], u3[4];
#pragma unroll
    for (int cc = 0; cc < 4; ++cc) {
      int c = 4*ci + cc;
      w3[cc] = W3t[c*256 + t];
      u3[cc] = U3t[c*256 + t];
    }
#pragma unroll
    for (int pt = 0; pt < 4; ++pt) {
      float vals[12];
      LOAD12(vals, &ins[pt*384 + 12*ci]);
#pragma unroll
      for (int cc = 0; cc < 4; ++cc)
#pragma unroll
        for (int d = 0; d < 3; ++d) {
          float xv = vals[cc*3+d];
          p[pt][d]  += w3[cc]*xv;
          dd[pt][d] += u3[cc]*xv;
        }
    }
  }
#pragma unroll
  for (int pt = 0; pt < 4; ++pt) {
    float res[3];
    vnleaky3(p[pt], dd[pt], res);
    size_t ob = ((size_t)bnb + pt)*768 + t*3;
    h3[ob+0] = res[0]; h3[ob+1] = res[1]; h3[ob+2] = res[2];
  }
}

// ---------------- conv4: VNLinearLeakyReLU 256 -> 128, + residual ----------------
__global__ __launch_bounds__(128) void conv4_kernel(const float* __restrict__ h3,
    const float* __restrict__ W4t, const float* __restrict__ U4t,
    float* __restrict__ out) {
  __shared__ float ins[4*768];
  int bnb = blockIdx.x * 4;
  int t = threadIdx.x;
  for (int idx = t; idx < 4*192; idx += 128)
    *(float4*)&ins[idx*4] = *(const float4*)&h3[(size_t)bnb*768 + idx*4];
  __syncthreads();
  float p[4][3], dd[4][3];
#pragma unroll
  for (int pt = 0; pt < 4; ++pt)
#pragma unroll
    for (int d = 0; d < 3; ++d) { p[pt][d] = 0.f; dd[pt][d] = 0.f; }
  for (int ci = 0; ci < 64; ++ci) {
    float w4[4], u4[4];
#pragma unroll
    for (int cc = 0; cc < 4; ++cc) {
      int c2 = 4*ci + cc;
      w4[cc] = W4t[c2*128 + t];
      u4[cc] = U4t[c2*128 + t];
    }
#pragma unroll
    for (int pt = 0; pt < 4; ++pt) {
      float vals[12];
      LOAD12(vals, &ins[pt*768 + 12*ci]);
#pragma unroll
      for (int cc = 0; cc < 4; ++cc)
#pragma unroll
        for (int d = 0; d < 3; ++d) {
          float xv = vals[cc*3+d];
          p[pt][d]  += w4[cc]*xv;
          dd[pt][d] += u4[cc]*xv;
        }
    }
  }
#pragma unroll
  for (int pt = 0; pt < 4; ++pt) {
    float res[3];
    vnleaky3(p[pt], dd[pt], res);
    float* orow = out + ((size_t)bnb + pt)*384 + t*3;
    orow[0] += res[0]; orow[1] += res[1]; orow[2] += res[2];
  }
}

extern "C" void kernel_launch(void* const* d_in, const int* in_sizes, int n_in,
                              void* d_out, int out_size, void* d_ws, size_t ws_size,
                              hipStream_t stream) {
  const float* x   = (const float*)d_in[0];
  const int* knn   = (const int*)d_in[1];
  const float* g1  = (const float*)d_in[2];
  const float* b1  = (const float*)d_in[3];
  const float* g2  = (const float*)d_in[4];
  const float* b2  = (const float*)d_in[5];
  const float* Wq  = (const float*)d_in[6];
  const float* Wk  = (const float*)d_in[7];
  const float* Wv  = (const float*)d_in[8];
  const float* Wo  = (const float*)d_in[9];
  const float* W1  = (const float*)d_in[10];
  const float* U1  = (const float*)d_in[11];
  const float* W2  = (const float*)d_in[12];
  const float* W3  = (const float*)d_in[13];
  const float* U3  = (const float*)d_in[14];
  const float* W4  = (const float*)d_in[15];
  const float* U4  = (const float*)d_in[16];
  float* out = (float*)d_out;
  (void)n_in; (void)out_size; (void)ws_size;

  const size_t BN = (size_t)in_sizes[0] / 384;   // 8192

  float* ws    = (float*)d_ws;
  float* normx = ws;                          // BN*384 f32
  float* obuf  = normx + BN*384;              // BN*1152 f32  (split-0 partial, combined in-place)
  float* knnm  = obuf + BN*1152;              // BN*384 f32
  ushort_t* qb = (ushort_t*)(knnm + BN*384);  // BN*1152 bf16
  ushort_t* kb = qb + BN*1152;
  ushort_t* vb = kb + BN*1152;
  ushort_t* vT = vb + BN*1152;
  float* wsp   = (float*)(vT + BN*1152);
  float* Wqt  = wsp;
  float* Wkt  = Wqt + 49152;
  float* Wvt  = Wkt + 49152;
  float* CWt  = Wvt + 49152;
  float* W3t  = CWt + 65536;
  float* U3t  = W3t + 32768;
  float* W4t  = U3t + 32768;
  float* U4t  = W4t + 32768;
  float* W2bt = U4t + 32768;
  float* Mt   = W2bt + 16384;
  float* opart1 = Mt + 49152;          // BN*1152 f32 (split-1 partial)
  float* lpart  = opart1 + BN*1152;    // 2*24*2048 f32
  // YZ/NB (BN*768 f32 each) alias the q/k/v bf16 region: conv1 runs BEFORE qkv.
  float* YZ = (float*)qb;
  float* NB = YZ + BN*768;
  float* nx2 = (float*)qb;   // q dead after attention
  float* h3  = (float*)kb;   // k/v dead after attention

  prep_weights<<<1600, 256, 0, stream>>>(Wq, Wk, Wv, Wo, W1, U1, W2, W3, U3, W4, U4,
                                         Wqt, Wkt, Wvt, CWt, W3t, U3t, W4t, U4t,
                                         W2bt, Mt);
  ln_kernel<<<(int)BN, 128, 0, stream>>>(x, normx, g1, b1);
  conv1_gemm<<<(int)(BN/16), 256, 0, stream>>>(normx, CWt, YZ, NB);
  conv1_post<<<(int)BN, 128, 0, stream>>>(YZ, NB, knn, knnm);
  qkv_kernel<<<(int)(BN/16), 256, 0, stream>>>(normx, Wqt, Wkt, Wvt, qb, kb, vb);
  vtrans_kernel<<<(int)(BN*1152/8/256), 256, 0, stream>>>(vb, vT);
  attn_kernel<<<64*24*2, 64, 0, stream>>>(qb, kb, vT, obuf, opart1, lpart);
  attn_combine<<<(int)(BN*1152/4/256), 256, 0, stream>>>(obuf, opart1, lpart);
  x1mid_kernel<<<(int)(BN/8), 128, 0, stream>>>(x, obuf, knnm, Mt, W2bt, out);
  ln_kernel<<<(int)BN, 128, 0, stream>>>(out, nx2, g2, b2);
  conv3_kernel<<<(int)(BN/4), 256, 0, stream>>>(nx2, W3t, U3t, h3);
  conv4_kernel<<<(int)(BN/4), 128, 0, stream>>>(h3, W4t, U4t, out);
}

// Round 5
// 803.381 us; speedup vs baseline: 3.7920x; 1.2588x over previous
//
#include <hip/hip_runtime.h>
#include <math.h>

// Problem constants (fixed by setup_inputs): B=4, N=2048, C=128, H=6, K=8
#define NFIX 2048
#define HH 6
#define KNN 8
#define NSLOPE 0.2f
#define EPSF 1e-6f
#define LNEPSF 1e-5f
// 0.125 (softmax scale) * log2(e), folded into bf16 Q so S-MFMA output is exp2-ready
#define QSCALE 0.18033688011112042f

typedef unsigned short ushort_t;
typedef unsigned int uint_t;
typedef __attribute__((ext_vector_type(8))) short bf16x8;
typedef __attribute__((ext_vector_type(4))) short bf16x4;
typedef __attribute__((ext_vector_type(16))) float f32x16;
typedef __attribute__((ext_vector_type(4))) float f32x4;

__device__ __forceinline__ ushort_t f2bf(float f) {
  union { float f; unsigned u; } v; v.f = f;
  unsigned r = v.u + 0x7fff + ((v.u >> 16) & 1);   // RNE
  return (ushort_t)(r >> 16);
}
__device__ __forceinline__ float bf2f(ushort_t u) {
  union { uint_t u; float f; } v; v.u = ((uint_t)u) << 16; return v.f;
}

#define LOAD12(dst, ptr) { \
  float4 _r0 = *(const float4*)((ptr));   \
  float4 _r1 = *(const float4*)((ptr)+4); \
  float4 _r2 = *(const float4*)((ptr)+8); \
  dst[0]=_r0.x; dst[1]=_r0.y; dst[2]=_r0.z; dst[3]=_r0.w; \
  dst[4]=_r1.x; dst[5]=_r1.y; dst[6]=_r1.z; dst[7]=_r1.w; \
  dst[8]=_r2.x; dst[9]=_r2.y; dst[10]=_r2.z; dst[11]=_r2.w; }

__device__ __forceinline__ void vnleaky3(const float* p, const float* dv, float* out) {
  float dot = p[0]*dv[0] + p[1]*dv[1] + p[2]*dv[2];
  float dsq = dv[0]*dv[0] + dv[1]*dv[1] + dv[2]*dv[2] + EPSF;
  float f = dot / dsq;
#pragma unroll
  for (int d = 0; d < 3; ++d) {
    float neg = p[d] - f * dv[d];
    out[d] = NSLOPE * p[d] + (1.f - NSLOPE) * ((dot >= 0.f) ? p[d] : neg);
  }
}

// ---------------- weight prep ----------------
__global__ void prep_weights(const float* __restrict__ Wq, const float* __restrict__ Wk,
                             const float* __restrict__ Wv, const float* __restrict__ Wo,
                             const float* __restrict__ W1, const float* __restrict__ U1,
                             const float* __restrict__ W2, const float* __restrict__ W3,
                             const float* __restrict__ U3, const float* __restrict__ W4,
                             const float* __restrict__ U4,
                             float* __restrict__ Wqt, float* __restrict__ Wkt,
                             float* __restrict__ Wvt, float* __restrict__ CWt,
                             float* __restrict__ W3t, float* __restrict__ U3t,
                             float* __restrict__ W4t, float* __restrict__ U4t,
                             float* __restrict__ W2bt, float* __restrict__ Mt) {
  int idx = blockIdx.x * 256 + threadIdx.x;
  if (idx < 49152) { int c = idx / 384, o = idx % 384; Wqt[idx] = Wq[o*128 + c]; return; }
  idx -= 49152;
  if (idx < 49152) { int c = idx / 384, o = idx % 384; Wkt[idx] = Wk[o*128 + c]; return; }
  idx -= 49152;
  if (idx < 49152) { int c = idx / 384, o = idx % 384; Wvt[idx] = Wv[o*128 + c]; return; }
  idx -= 49152;
  if (idx < 65536) {
    int c = idx / 512, j = idx % 512;
    float val;
    if (j < 128)      val = W1[j*256 + c];                              // W1a
    else if (j < 256) val = U1[(j-128)*256 + c];                        // U1a
    else if (j < 384) { int o = j-256; val = W1[o*256 + 128 + c] - W1[o*256 + c]; }
    else              { int o = j-384; val = U1[o*256 + 128 + c] - U1[o*256 + c]; }
    CWt[idx] = val; return;
  }
  idx -= 65536;
  if (idx < 32768) { int c = idx / 256, o = idx % 256; W3t[idx] = W3[o*128 + c]; return; }
  idx -= 32768;
  if (idx < 32768) { int c = idx / 256, o = idx % 256; U3t[idx] = U3[o*128 + c]; return; }
  idx -= 32768;
  if (idx < 32768) { int c = idx / 128, o = idx % 128; W4t[idx] = W4[o*256 + c]; return; }
  idx -= 32768;
  if (idx < 32768) { int c = idx / 128, o = idx % 128; U4t[idx] = U4[o*256 + c]; return; }
  idx -= 32768;
  if (idx < 16384) { int c2 = idx / 128, c = idx % 128; W2bt[idx] = W2[c*256 + 128 + c2]; return; }
  idx -= 16384;
  if (idx < 49152) {
    int o = idx / 128, c = idx % 128;
    float s = 0.f;
    for (int cp = 0; cp < 128; ++cp) s += W2[c*256 + cp] * Wo[cp*384 + o];
    Mt[idx] = s;
  }
}

// ---------------- VN LayerNorm ----------------
__global__ __launch_bounds__(128) void ln_kernel(const float* __restrict__ in,
                                                 float* __restrict__ out,
                                                 const float* __restrict__ g,
                                                 const float* __restrict__ b) {
  int bn = blockIdx.x;
  int c = threadIdx.x;
  const float* row = in + (size_t)bn * 384;
  float x0 = row[c*3+0], x1 = row[c*3+1], x2 = row[c*3+2];
  float nv = sqrtf(x0*x0 + x1*x1 + x2*x2 + EPSF);
  float s1 = nv, s2 = nv*nv;
#pragma unroll
  for (int off = 32; off >= 1; off >>= 1) {
    s1 += __shfl_down(s1, off);
    s2 += __shfl_down(s2, off);
  }
  __shared__ float red[4];
  int lane = threadIdx.x & 63, w = threadIdx.x >> 6;
  if (lane == 0) { red[w*2] = s1; red[w*2+1] = s2; }
  __syncthreads();
  float tot1 = red[0] + red[2], tot2 = red[1] + red[3];
  float mu  = tot1 * (1.f/128.f);
  float var = tot2 * (1.f/128.f) - mu*mu;
  float rsig = rsqrtf(var + LNEPSF);
  float nnew = g[c] * ((nv - mu) * rsig) + b[c];
  float sc = nnew / nv;
  float* orow = out + (size_t)bn * 384;
  orow[c*3+0] = x0*sc; orow[c*3+1] = x1*sc; orow[c*3+2] = x2*sc;
}

// ---------------- conv1 GEMM: [Y|Z] and [YB|ZB] = CW @ normx ----------------
__global__ __launch_bounds__(256) void conv1_gemm(const float* __restrict__ in,
    const float* __restrict__ CWt,
    float* __restrict__ YZ, float* __restrict__ NB) {
  __shared__ float ins[16*388];
  int bnb = blockIdx.x * 16;
  int t = threadIdx.x;
  for (int idx = t; idx < 16*96; idx += 256) {
    int pt = idx / 96, j4 = (idx % 96) * 4;
    *(float4*)&ins[pt*388 + j4] = *(const float4*)&in[((size_t)bnb + pt)*384 + j4];
  }
  __syncthreads();
  int po = t & 7;
  int og = t >> 3;
  for (int pass = 0; pass < 4; ++pass) {
    int j0 = pass * 128 + og * 4;
    float a[2][4][3];
#pragma unroll
    for (int pp = 0; pp < 2; ++pp)
#pragma unroll
      for (int uu = 0; uu < 4; ++uu)
#pragma unroll
        for (int d = 0; d < 3; ++d) a[pp][uu][d] = 0.f;
    for (int ci = 0; ci < 32; ++ci) {
      float wv[4][4];
#pragma unroll
      for (int cc = 0; cc < 4; ++cc) {
        float4 wt = *(const float4*)&CWt[(size_t)(4*ci+cc)*512 + j0];
        wv[cc][0]=wt.x; wv[cc][1]=wt.y; wv[cc][2]=wt.z; wv[cc][3]=wt.w;
      }
#pragma unroll
      for (int pp = 0; pp < 2; ++pp) {
        float vals[12];
        LOAD12(vals, &ins[(2*po+pp)*388 + 12*ci]);
#pragma unroll
        for (int cc = 0; cc < 4; ++cc)
#pragma unroll
          for (int uu = 0; uu < 4; ++uu)
#pragma unroll
            for (int d = 0; d < 3; ++d)
              a[pp][uu][d] += wv[cc][uu] * vals[cc*3+d];
      }
    }
    float* dst = (pass < 2) ? YZ : NB;
    int off = (pass & 1) * 384 + og * 12;
#pragma unroll
    for (int pp = 0; pp < 2; ++pp) {
      size_t rb = ((size_t)bnb + 2*po + pp) * 768 + off;
#pragma unroll
      for (int uu = 0; uu < 4; ++uu)
#pragma unroll
        for (int d = 0; d < 3; ++d)
          dst[rb + uu*3 + d] = a[pp][uu][d];
    }
  }
}

// ---------------- conv1 post: gather + add + vnleaky + mean over K ----------------
__global__ __launch_bounds__(128) void conv1_post(const float* __restrict__ YZ,
    const float* __restrict__ NB, const int* __restrict__ knn_index,
    float* __restrict__ knnm) {
  int bn = blockIdx.x;
  int b = bn / NFIX, n = bn % NFIX;
  int t = threadIdx.x;
  __shared__ int sidx[KNN];
  if (t < KNN) sidx[t] = knn_index[(b*KNN + t)*NFIX + n];
  __syncthreads();
  const float* nbp = NB + (size_t)bn*768 + t*3;
  float yb[3], zb[3];
#pragma unroll
  for (int d = 0; d < 3; ++d) { yb[d] = nbp[d]; zb[d] = nbp[384 + d]; }
  float om[3] = {0.f, 0.f, 0.f};
#pragma unroll
  for (int kk = 0; kk < KNN; ++kk) {
    const float* r = YZ + (size_t)sidx[kk]*768 + t*3;
    float p[3], dd[3];
#pragma unroll
    for (int d = 0; d < 3; ++d) { p[d] = r[d] + yb[d]; dd[d] = r[384 + d] + zb[d]; }
    float res[3];
    vnleaky3(p, dd, res);
    om[0] += res[0]; om[1] += res[1]; om[2] += res[2];
  }
  size_t ob = (size_t)bn*384 + t*3;
  knnm[ob+0] = om[0] * (1.f/KNN);
  knnm[ob+1] = om[1] * (1.f/KNN);
  knnm[ob+2] = om[2] * (1.f/KNN);
}

// ---------------- QKV projection -> bf16 (q pre-scaled by QSCALE) ----------------
__global__ __launch_bounds__(256) void qkv_kernel(const float* __restrict__ in,
    const float* __restrict__ Wqt, const float* __restrict__ Wkt,
    const float* __restrict__ Wvt,
    ushort_t* __restrict__ q, ushort_t* __restrict__ k, ushort_t* __restrict__ v) {
  __shared__ float ins[16*388];
  int bnb = blockIdx.x * 16;
  int t = threadIdx.x;
  for (int idx = t; idx < 16*96; idx += 256) {
    int pt = idx / 96, j4 = (idx % 96) * 4;
    *(float4*)&ins[pt*388 + j4] = *(const float4*)&in[((size_t)bnb + pt)*384 + j4];
  }
  __syncthreads();
  int po = t & 7;
  int og = t >> 3;
  for (int pass = 0; pass < 9; ++pass) {
    int which = pass / 3;
    int om_ = (pass % 3) * 128 + og * 4;
    const float* W = (which == 0) ? Wqt : (which == 1) ? Wkt : Wvt;
    float a[2][4][3];
#pragma unroll
    for (int pp = 0; pp < 2; ++pp)
#pragma unroll
      for (int uu = 0; uu < 4; ++uu)
#pragma unroll
        for (int d = 0; d < 3; ++d) a[pp][uu][d] = 0.f;
    for (int ci = 0; ci < 32; ++ci) {
      float wv[4][4];
#pragma unroll
      for (int cc = 0; cc < 4; ++cc) {
        float4 wt = *(const float4*)&W[(size_t)(4*ci+cc)*384 + om_];
        wv[cc][0]=wt.x; wv[cc][1]=wt.y; wv[cc][2]=wt.z; wv[cc][3]=wt.w;
      }
#pragma unroll
      for (int pp = 0; pp < 2; ++pp) {
        const float* ip = &ins[(2*po+pp)*388 + 12*ci];
        float vals[12];
        LOAD12(vals, ip);
#pragma unroll
        for (int cc = 0; cc < 4; ++cc)
#pragma unroll
          for (int uu = 0; uu < 4; ++uu)
#pragma unroll
            for (int d = 0; d < 3; ++d)
              a[pp][uu][d] += wv[cc][uu] * vals[cc*3+d];
      }
    }
    ushort_t* op = (which == 0) ? q : (which == 1) ? k : v;
    float scl = (which == 0) ? QSCALE : 1.0f;
#pragma unroll
    for (int pp = 0; pp < 2; ++pp) {
      size_t rb = ((size_t)bnb + 2*po + pp) * 1152 + (size_t)om_*3;
      ushort_t tmp[12];
#pragma unroll
      for (int uu = 0; uu < 4; ++uu)
#pragma unroll
        for (int d = 0; d < 3; ++d)
          tmp[uu*3+d] = f2bf(a[pp][uu][d] * scl);
      uint_t* wp = (uint_t*)&op[rb];
#pragma unroll
      for (int j = 0; j < 6; ++j)
        wp[j] = (uint_t)tmp[2*j] | ((uint_t)tmp[2*j+1] << 16);
    }
  }
}

// ---------------- V transpose ----------------
__global__ __launch_bounds__(256) void vtrans_kernel(const ushort_t* __restrict__ v,
                                                     ushort_t* __restrict__ vT) {
  int T = blockIdx.x * 256 + threadIdx.x;
  int pt0 = (T & 255) * 8;
  int row = T >> 8;
  int bh = row / 192, ch = row % 192;
  int b = bh / HH, h = bh % HH;
  ushort_t tmp[8];
#pragma unroll
  for (int i = 0; i < 8; ++i)
    tmp[i] = v[(size_t)(b*NFIX + pt0 + i)*1152 + h*192 + ch];
  uint4 o;
  o.x = (uint_t)tmp[0] | ((uint_t)tmp[1] << 16);
  o.y = (uint_t)tmp[2] | ((uint_t)tmp[3] << 16);
  o.z = (uint_t)tmp[4] | ((uint_t)tmp[5] << 16);
  o.w = (uint_t)tmp[6] | ((uint_t)tmp[7] << 16);
  *(uint4*)&vT[(size_t)row*2048 + pt0] = o;
}

// ---------------- attention: LDS-staged MFMA flash, 4 waves (128 q) / block, split-K=4 ----------------
// grid = 16 qtiles(128) * 24 bh * 4 splits = 1536. Per 32-point K-tile: block stages
// K (32x192) + V (192x32, from vT) into LDS with coalesced loads; lanes read fragments
// via ds_read_b64 pairs (pitch 196/36 ushorts -> 2 lanes/bank = free).
__global__ __launch_bounds__(256, 2) void attn_kernel(const ushort_t* __restrict__ q,
    const ushort_t* __restrict__ k, const ushort_t* __restrict__ vT,
    ushort_t* __restrict__ opart, float* __restrict__ lpart) {
  __shared__ ushort_t kt[32*196];      // [kp][ch]
  __shared__ ushort_t vt[192*36];      // [ch][kp]
  __shared__ ushort_t plds[4][32*36];  // per-wave P [q][kp]
  __shared__ float alds[4][32];
  int blk = blockIdx.x;
  int qt = blk % 16;
  int bh = (blk / 16) % 24;
  int split = blk / (16*24);
  int b = bh / HH, h = bh % HH;
  int t = threadIdx.x;
  int w = t >> 6, lane = t & 63, ql = lane & 31, hl = lane >> 5;
  int qrow0 = qt*128 + w*32;
  // Q fragments (B-operand): lane ql = q col, hl*8 k-chunk, 12 ch-steps
  const ushort_t* qp = q + (size_t)(b*NFIX + qrow0 + ql)*1152 + h*192 + hl*8;
  bf16x8 qf[12];
#pragma unroll
  for (int cs = 0; cs < 12; ++cs) qf[cs] = *(const bf16x8*)(qp + cs*16);
  f32x16 acc[6];
#pragma unroll
  for (int nt = 0; nt < 6; ++nt)
#pragma unroll
    for (int r = 0; r < 16; ++r) acc[nt][r] = 0.f;
  float lsum = 0.f;
  int koff0 = split * 512;
  for (int kb = 0; kb < 16; ++kb) {
    int koff = koff0 + kb*32;
    __syncthreads();   // all waves done reading previous kt/vt
    // stage K tile: 768 x 16B chunks, kp = idx/24, c16 = idx%24
    for (int idx = t; idx < 768; idx += 256) {
      int kp = idx / 24, c16 = idx % 24;
      bf16x8 gv = *(const bf16x8*)&k[(size_t)(b*NFIX + koff + kp)*1152 + h*192 + c16*8];
      bf16x4 lo = __builtin_shufflevector(gv, gv, 0, 1, 2, 3);
      bf16x4 hi = __builtin_shufflevector(gv, gv, 4, 5, 6, 7);
      ushort_t* dst = &kt[kp*196 + c16*8];
      *(bf16x4*)dst = lo;
      *(bf16x4*)(dst + 4) = hi;
    }
    // stage V tile: 768 x 16B chunks, ch = idx/4, c4 = idx%4
    for (int idx = t; idx < 768; idx += 256) {
      int ch = idx >> 2, c4 = idx & 3;
      bf16x8 gv = *(const bf16x8*)&vT[((size_t)bh*192 + ch)*2048 + koff + c4*8];
      bf16x4 lo = __builtin_shufflevector(gv, gv, 0, 1, 2, 3);
      bf16x4 hi = __builtin_shufflevector(gv, gv, 4, 5, 6, 7);
      ushort_t* dst = &vt[ch*36 + c4*8];
      *(bf16x4*)dst = lo;
      *(bf16x4*)(dst + 4) = hi;
    }
    __syncthreads();
    // QK: S^T[kp][q] for this wave's 32 q
    f32x16 sc;
#pragma unroll
    for (int r = 0; r < 16; ++r) sc[r] = 0.f;
#pragma unroll
    for (int cs = 0; cs < 12; ++cs) {
      const ushort_t* kr = &kt[ql*196 + cs*16 + hl*8];
      bf16x4 alo = *(const bf16x4*)kr;
      bf16x4 ahi = *(const bf16x4*)(kr + 4);
      bf16x8 af = __builtin_shufflevector(alo, ahi, 0, 1, 2, 3, 4, 5, 6, 7);
      sc = __builtin_amdgcn_mfma_f32_32x32x16_bf16(af, qf[cs], sc, 0, 0, 0);
    }
    // exp2 + pack + P write (kp = rr + 8*g2 + 4*hl)
#pragma unroll
    for (int g2 = 0; g2 < 4; ++g2) {
      bf16x4 pw;
#pragma unroll
      for (int rr = 0; rr < 4; ++rr) {
        float p = __builtin_amdgcn_exp2f(sc[g2*4 + rr]);
        lsum += p;
        pw[rr] = (short)f2bf(p);
      }
      *(bf16x4*)&plds[w][ql*36 + g2*8 + hl*4] = pw;
    }
    asm volatile("s_waitcnt lgkmcnt(0)" ::: "memory");
    // PV: O += P*V
#pragma unroll
    for (int s = 0; s < 2; ++s) {
      const ushort_t* pr = &plds[w][ql*36 + s*16 + hl*8];
      bf16x4 plo = *(const bf16x4*)pr;
      bf16x4 phi = *(const bf16x4*)(pr + 4);
      bf16x8 pa = __builtin_shufflevector(plo, phi, 0, 1, 2, 3, 4, 5, 6, 7);
#pragma unroll
      for (int nt = 0; nt < 6; ++nt) {
        const ushort_t* vr = &vt[(nt*32 + ql)*36 + s*16 + hl*8];
        bf16x4 vlo = *(const bf16x4*)vr;
        bf16x4 vhi = *(const bf16x4*)(vr + 4);
        bf16x8 vf = __builtin_shufflevector(vlo, vhi, 0, 1, 2, 3, 4, 5, 6, 7);
        acc[nt] = __builtin_amdgcn_mfma_f32_32x32x16_bf16(pa, vf, acc[nt], 0, 0, 0);
      }
    }
  }
  lsum += __shfl_xor(lsum, 32);
  if (lane < 32) {
    alds[w][ql] = 1.0f / lsum;
    lpart[(size_t)split*24*NFIX + (size_t)bh*NFIX + qrow0 + ql] = lsum;
  }
  asm volatile("s_waitcnt lgkmcnt(0)" ::: "memory");
  float lv[4][4];
#pragma unroll
  for (int g2 = 0; g2 < 4; ++g2) {
    f32x4 tv = *(const f32x4*)&alds[w][8*g2 + 4*hl];
#pragma unroll
    for (int rr = 0; rr < 4; ++rr) lv[g2][rr] = tv[rr];
  }
  ushort_t* op = opart + (size_t)split*(size_t)8192*1152
               + (size_t)(b*NFIX + qrow0)*1152 + h*192 + ql;
#pragma unroll
  for (int nt = 0; nt < 6; ++nt)
#pragma unroll
    for (int r = 0; r < 16; ++r) {
      int qrow = (r&3) + 8*(r>>2) + 4*hl;
      op[(size_t)qrow*1152 + nt*32] = f2bf(acc[nt][r] * lv[r>>2][r&3]);
    }
}

// ---------------- combine 4 split-K bf16 partials -> f32 obuf ----------------
__global__ __launch_bounds__(256) void attn_combine(const ushort_t* __restrict__ opart,
    const float* __restrict__ lpart, float* __restrict__ obuf) {
  size_t i = ((size_t)blockIdx.x * 256 + threadIdx.x) * 8;
  int bn = (int)(i / 1152);
  int ch = (int)(i % 1152);
  int b = bn >> 11, n = bn & 2047;
  int h = ch / 192;
  size_t lidx = (size_t)(b*HH + h)*NFIX + n;
  float l0 = lpart[lidx];
  float l1 = lpart[(size_t)24*NFIX + lidx];
  float l2 = lpart[(size_t)48*NFIX + lidx];
  float l3 = lpart[(size_t)72*NFIX + lidx];
  float rd = 1.f / (l0 + l1 + l2 + l3);
  float ws[4] = { l0*rd, l1*rd, l2*rd, l3*rd };
  float o[8];
#pragma unroll
  for (int j = 0; j < 8; ++j) o[j] = 0.f;
  const size_t stride = (size_t)8192*1152;
#pragma unroll
  for (int s = 0; s < 4; ++s) {
    const ushort_t* pp = opart + s*stride + i;
    uint4 raw = *(const uint4*)pp;
    const ushort_t* us = (const ushort_t*)&raw;
#pragma unroll
    for (int j = 0; j < 8; ++j) o[j] += ws[s] * bf2f(us[j]);
  }
  *(float4*)&obuf[i]     = make_float4(o[0], o[1], o[2], o[3]);
  *(float4*)&obuf[i + 4] = make_float4(o[4], o[5], o[6], o[7]);
}

// ---------------- x_mid = x + M @ o_attn + W2b @ knnmean ----------------
__global__ __launch_bounds__(128) void x1mid_kernel(const float* __restrict__ x,
    const float* __restrict__ oattn, const float* __restrict__ knnm,
    const float* __restrict__ Mt, const float* __restrict__ W2bt,
    float* __restrict__ out) {
  __shared__ float os[8*1156];
  __shared__ float ksm[8*388];
  int bnb = blockIdx.x * 8;
  int t = threadIdx.x;
  for (int idx = t; idx < 8*288; idx += 128) {
    int pt = idx / 288, j4 = (idx % 288) * 4;
    *(float4*)&os[pt*1156 + j4] = *(const float4*)&oattn[((size_t)bnb + pt)*1152 + j4];
  }
  for (int idx = t; idx < 8*96; idx += 128) {
    int pt = idx / 96, j4 = (idx % 96) * 4;
    *(float4*)&ksm[pt*388 + j4] = *(const float4*)&knnm[((size_t)bnb + pt)*384 + j4];
  }
  __syncthreads();
  int tc = t & 31;
  int tp = t >> 5;
  float acc[4][2][3];
#pragma unroll
  for (int u = 0; u < 4; ++u)
#pragma unroll
    for (int pp = 0; pp < 2; ++pp)
#pragma unroll
      for (int d = 0; d < 3; ++d)
        acc[u][pp][d] = x[((size_t)bnb + 2*tp + pp)*384 + (tc + 32*u)*3 + d];
  for (int oi = 0; oi < 96; ++oi) {
    float w[4][4];
#pragma unroll
    for (int oo = 0; oo < 4; ++oo)
#pragma unroll
      for (int u = 0; u < 4; ++u)
        w[oo][u] = Mt[(size_t)(4*oi+oo)*128 + tc + 32*u];
#pragma unroll
    for (int pp = 0; pp < 2; ++pp) {
      float vals[12];
      LOAD12(vals, &os[(2*tp+pp)*1156 + 12*oi]);
#pragma unroll
      for (int oo = 0; oo < 4; ++oo)
#pragma unroll
        for (int u = 0; u < 4; ++u)
#pragma unroll
          for (int d = 0; d < 3; ++d)
            acc[u][pp][d] += w[oo][u] * vals[oo*3+d];
    }
  }
  for (int ci = 0; ci < 32; ++ci) {
    float w[4][4];
#pragma unroll
    for (int cc = 0; cc < 4; ++cc)
#pragma unroll
      for (int u = 0; u < 4; ++u)
        w[cc][u] = W2bt[(size_t)(4*ci+cc)*128 + tc + 32*u];
#pragma unroll
    for (int pp = 0; pp < 2; ++pp) {
      float vals[12];
      LOAD12(vals, &ksm[(2*tp+pp)*388 + 12*ci]);
#pragma unroll
      for (int cc = 0; cc < 4; ++cc)
#pragma unroll
        for (int u = 0; u < 4; ++u)
#pragma unroll
          for (int d = 0; d < 3; ++d)
            acc[u][pp][d] += w[cc][u] * vals[cc*3+d];
    }
  }
#pragma unroll
  for (int u = 0; u < 4; ++u)
#pragma unroll
    for (int pp = 0; pp < 2; ++pp)
#pragma unroll
      for (int d = 0; d < 3; ++d)
        out[((size_t)bnb + 2*tp + pp)*384 + (tc + 32*u)*3 + d] = acc[u][pp][d];
}

// ---------------- conv3: VNLinearLeakyReLU 128 -> 256 ----------------
__global__ __launch_bounds__(256) void conv3_kernel(const float* __restrict__ in,
    const float* __restrict__ W3t, const float* __restrict__ U3t,
    float* __restrict__ h3) {
  __shared__ float ins[4*384];
  int bnb = blockIdx.x * 4;
  int t = threadIdx.x;
  for (int idx = t; idx < 4*96; idx += 256)
    *(float4*)&ins[idx*4] = *(const float4*)&in[(size_t)bnb*384 + idx*4];
  __syncthreads();
  float p[4][3], dd[4][3];
#pragma unroll
  for (int pt = 0; pt < 4; ++pt)
#pragma unroll
    for (int d = 0; d < 3; ++d) { p[pt][d] = 0.f; dd[pt][d] = 0.f; }
  for (int ci = 0; ci < 32; ++ci) {
    float w3[4], u3[4];
#pragma unroll
    for (int cc = 0; cc < 4; ++cc) {
      int c = 4*ci + cc;
      w3[cc] = W3t[c*256 + t];
      u3[cc] = U3t[c*256 + t];
    }
#pragma unroll
    for (int pt = 0; pt < 4; ++pt) {
      float vals[12];
      LOAD12(vals, &ins[pt*384 + 12*ci]);
#pragma unroll
      for (int cc = 0; cc < 4; ++cc)
#pragma unroll
        for (int d = 0; d < 3; ++d) {
          float xv = vals[cc*3+d];
          p[pt][d]  += w3[cc]*xv;
          dd[pt][d] += u3[cc]*xv;
        }
    }
  }
#pragma unroll
  for (int pt = 0; pt < 4; ++pt) {
    float res[3];
    vnleaky3(p[pt], dd[pt], res);
    size_t ob = ((size_t)bnb + pt)*768 + t*3;
    h3[ob+0] = res[0]; h3[ob+1] = res[1]; h3[ob+2] = res[2];
  }
}

// ---------------- conv4: VNLinearLeakyReLU 256 -> 128, + residual ----------------
__global__ __launch_bounds__(128) void conv4_kernel(const float* __restrict__ h3,
    const float* __restrict__ W4t, const float* __restrict__ U4t,
    float* __restrict__ out) {
  __shared__ float ins[4*768];
  int bnb = blockIdx.x * 4;
  int t = threadIdx.x;
  for (int idx = t; idx < 4*192; idx += 128)
    *(float4*)&ins[idx*4] = *(const float4*)&h3[(size_t)bnb*768 + idx*4];
  __syncthreads();
  float p[4][3], dd[4][3];
#pragma unroll
  for (int pt = 0; pt < 4; ++pt)
#pragma unroll
    for (int d = 0; d < 3; ++d) { p[pt][d] = 0.f; dd[pt][d] = 0.f; }
  for (int ci = 0; ci < 64; ++ci) {
    float w4[4], u4[4];
#pragma unroll
    for (int cc = 0; cc < 4; ++cc) {
      int c2 = 4*ci + cc;
      w4[cc] = W4t[c2*128 + t];
      u4[cc] = U4t[c2*128 + t];
    }
#pragma unroll
    for (int pt = 0; pt < 4; ++pt) {
      float vals[12];
      LOAD12(vals, &ins[pt*768 + 12*ci]);
#pragma unroll
      for (int cc = 0; cc < 4; ++cc)
#pragma unroll
        for (int d = 0; d < 3; ++d) {
          float xv = vals[cc*3+d];
          p[pt][d]  += w4[cc]*xv;
          dd[pt][d] += u4[cc]*xv;
        }
    }
  }
#pragma unroll
  for (int pt = 0; pt < 4; ++pt) {
    float res[3];
    vnleaky3(p[pt], dd[pt], res);
    float* orow = out + ((size_t)bnb + pt)*384 + t*3;
    orow[0] += res[0]; orow[1] += res[1]; orow[2] += res[2];
  }
}

extern "C" void kernel_launch(void* const* d_in, const int* in_sizes, int n_in,
                              void* d_out, int out_size, void* d_ws, size_t ws_size,
                              hipStream_t stream) {
  const float* x   = (const float*)d_in[0];
  const int* knn   = (const int*)d_in[1];
  const float* g1  = (const float*)d_in[2];
  const float* b1  = (const float*)d_in[3];
  const float* g2  = (const float*)d_in[4];
  const float* b2  = (const float*)d_in[5];
  const float* Wq  = (const float*)d_in[6];
  const float* Wk  = (const float*)d_in[7];
  const float* Wv  = (const float*)d_in[8];
  const float* Wo  = (const float*)d_in[9];
  const float* W1  = (const float*)d_in[10];
  const float* U1  = (const float*)d_in[11];
  const float* W2  = (const float*)d_in[12];
  const float* W3  = (const float*)d_in[13];
  const float* U3  = (const float*)d_in[14];
  const float* W4  = (const float*)d_in[15];
  const float* U4  = (const float*)d_in[16];
  float* out = (float*)d_out;
  (void)n_in; (void)out_size; (void)ws_size;

  const size_t BN = (size_t)in_sizes[0] / 384;   // 8192

  float* ws    = (float*)d_ws;
  float* normx = ws;                          // BN*384 f32
  float* obuf  = normx + BN*384;              // BN*1152 f32 (combined attention out)
  float* knnm  = obuf + BN*1152;              // BN*384 f32
  ushort_t* qb = (ushort_t*)(knnm + BN*384);  // BN*1152 bf16
  ushort_t* kb = qb + BN*1152;
  ushort_t* vb = kb + BN*1152;
  ushort_t* vT = vb + BN*1152;
  float* wsp   = (float*)(vT + BN*1152);
  float* Wqt  = wsp;
  float* Wkt  = Wqt + 49152;
  float* Wvt  = Wkt + 49152;
  float* CWt  = Wvt + 49152;
  float* W3t  = CWt + 65536;
  float* U3t  = W3t + 32768;
  float* W4t  = U3t + 32768;
  float* U4t  = W4t + 32768;
  float* W2bt = U4t + 32768;
  float* Mt   = W2bt + 16384;
  ushort_t* opart = (ushort_t*)(Mt + 49152);  // 4 * BN*1152 bf16 split partials
  float* lpart = (float*)(opart + 4*BN*1152); // 4*24*2048 f32
  // YZ/NB (BN*768 f32 each) alias the q/k/v bf16 region: conv1 runs BEFORE qkv.
  float* YZ = (float*)qb;
  float* NB = YZ + BN*768;
  float* nx2 = (float*)qb;   // q dead after attention
  float* h3  = (float*)kb;   // k/v dead after attention

  prep_weights<<<1600, 256, 0, stream>>>(Wq, Wk, Wv, Wo, W1, U1, W2, W3, U3, W4, U4,
                                         Wqt, Wkt, Wvt, CWt, W3t, U3t, W4t, U4t,
                                         W2bt, Mt);
  ln_kernel<<<(int)BN, 128, 0, stream>>>(x, normx, g1, b1);
  conv1_gemm<<<(int)(BN/16), 256, 0, stream>>>(normx, CWt, YZ, NB);
  conv1_post<<<(int)BN, 128, 0, stream>>>(YZ, NB, knn, knnm);
  qkv_kernel<<<(int)(BN/16), 256, 0, stream>>>(normx, Wqt, Wkt, Wvt, qb, kb, vb);
  vtrans_kernel<<<(int)(BN*1152/8/256), 256, 0, stream>>>(vb, vT);
  attn_kernel<<<16*24*4, 256, 0, stream>>>(qb, kb, vT, opart, lpart);
  attn_combine<<<(int)(BN*1152/8/256), 256, 0, stream>>>(opart, lpart, obuf);
  x1mid_kernel<<<(int)(BN/8), 128, 0, stream>>>(x, obuf, knnm, Mt, W2bt, out);
  ln_kernel<<<(int)BN, 128, 0, stream>>>(out, nx2, g2, b2);
  conv3_kernel<<<(int)(BN/4), 256, 0, stream>>>(nx2, W3t, U3t, h3);
  conv4_kernel<<<(int)(BN/4), 128, 0, stream>>>(h3, W4t, U4t, out);
}

// Round 7
// 632.074 us; speedup vs baseline: 4.8197x; 1.2710x over previous
//
#include <hip/hip_runtime.h>
#include <math.h>

// Problem constants (fixed by setup_inputs): B=4, N=2048, C=128, H=6, K=8
#define NFIX 2048
#define HH 6
#define KNN 8
#define NSLOPE 0.2f
#define EPSF 1e-6f
#define LNEPSF 1e-5f
// 0.125 (softmax scale) * log2(e), folded into Wq rows so S-MFMA output is exp2-ready
#define QSCALE 0.18033688011112042f

typedef unsigned short ushort_t;
typedef unsigned int uint_t;
typedef __attribute__((ext_vector_type(8))) short bf16x8;
typedef __attribute__((ext_vector_type(4))) short bf16x4;
typedef __attribute__((ext_vector_type(16))) float f32x16;
typedef __attribute__((ext_vector_type(4))) float f32x4;

__device__ __forceinline__ ushort_t f2bf(float f) {
  union { float f; unsigned u; } v; v.f = f;
  unsigned r = v.u + 0x7fff + ((v.u >> 16) & 1);   // RNE
  return (ushort_t)(r >> 16);
}
__device__ __forceinline__ float bf2f(ushort_t u) {
  union { uint_t u; float f; } v; v.u = ((uint_t)u) << 16; return v.f;
}
__device__ __forceinline__ uint_t pack2(float a, float b) {
  return (uint_t)f2bf(a) | ((uint_t)f2bf(b) << 16);
}

#define LOAD12(dst, ptr) { \
  float4 _r0 = *(const float4*)((ptr));   \
  float4 _r1 = *(const float4*)((ptr)+4); \
  float4 _r2 = *(const float4*)((ptr)+8); \
  dst[0]=_r0.x; dst[1]=_r0.y; dst[2]=_r0.z; dst[3]=_r0.w; \
  dst[4]=_r1.x; dst[5]=_r1.y; dst[6]=_r1.z; dst[7]=_r1.w; \
  dst[8]=_r2.x; dst[9]=_r2.y; dst[10]=_r2.z; dst[11]=_r2.w; }

__device__ __forceinline__ void vnleaky3(const float* p, const float* dv, float* out) {
  float dot = p[0]*dv[0] + p[1]*dv[1] + p[2]*dv[2];
  float dsq = dv[0]*dv[0] + dv[1]*dv[1] + dv[2]*dv[2] + EPSF;
  float f = dot / dsq;
#pragma unroll
  for (int d = 0; d < 3; ++d) {
    float neg = p[d] - f * dv[d];
    out[d] = NSLOPE * p[d] + (1.f - NSLOPE) * ((dot >= 0.f) ? p[d] : neg);
  }
}

// ---------------- weight prep ----------------
// Wall bf16 [1664][128]: rows 0..383 Wq*QSCALE | 384..767 Wk | 768..1151 Wv |
//   1152..1663 conv1 CW (W1a | U1a | W1b-W1a | U1b-U1a).
// Then fp32: Mt 49152 | W2bt 16384 | W3t 32768 | U3t 32768 | W4t 32768 | U4t 32768.
__global__ void prep_weights(const float* __restrict__ Wq, const float* __restrict__ Wk,
                             const float* __restrict__ Wv, const float* __restrict__ Wo,
                             const float* __restrict__ W1, const float* __restrict__ U1,
                             const float* __restrict__ W2, const float* __restrict__ W3,
                             const float* __restrict__ U3, const float* __restrict__ W4,
                             const float* __restrict__ U4,
                             ushort_t* __restrict__ Wall,
                             float* __restrict__ Mt, float* __restrict__ W2bt,
                             float* __restrict__ W3t, float* __restrict__ U3t,
                             float* __restrict__ W4t, float* __restrict__ U4t) {
  int idx = blockIdx.x * 256 + threadIdx.x;
  if (idx < 212992) {
    int m = idx >> 7, c = idx & 127;
    float val;
    if (m < 384)       val = Wq[m*128 + c] * QSCALE;
    else if (m < 768)  val = Wk[(m-384)*128 + c];
    else if (m < 1152) val = Wv[(m-768)*128 + c];
    else {
      int j = m - 1152;
      if (j < 128)      val = W1[j*256 + c];
      else if (j < 256) val = U1[(j-128)*256 + c];
      else if (j < 384) { int o = j-256; val = W1[o*256 + 128 + c] - W1[o*256 + c]; }
      else              { int o = j-384; val = U1[o*256 + 128 + c] - U1[o*256 + c]; }
    }
    Wall[idx] = f2bf(val); return;
  }
  idx -= 212992;
  if (idx < 49152) {
    int o = idx / 128, c = idx % 128;
    float s = 0.f;
    for (int cp = 0; cp < 128; ++cp) s += W2[c*256 + cp] * Wo[cp*384 + o];
    Mt[idx] = s; return;
  }
  idx -= 49152;
  if (idx < 16384) { int c2 = idx / 128, c = idx % 128; W2bt[idx] = W2[c*256 + 128 + c2]; return; }
  idx -= 16384;
  if (idx < 32768) { int c = idx / 256, o = idx % 256; W3t[idx] = W3[o*128 + c]; return; }
  idx -= 32768;
  if (idx < 32768) { int c = idx / 256, o = idx % 256; U3t[idx] = U3[o*128 + c]; return; }
  idx -= 32768;
  if (idx < 32768) { int c = idx / 128, o = idx % 128; W4t[idx] = W4[o*256 + c]; return; }
  idx -= 32768;
  if (idx < 32768) { int c = idx / 128, o = idx % 128; U4t[idx] = U4[o*256 + c]; return; }
}

// ---------------- VN LayerNorm: xbp!=null -> bf16 de-interleaved out; else fp32 out ----------------
__global__ __launch_bounds__(128) void ln_kernel(const float* __restrict__ in,
                                                 float* __restrict__ out,
                                                 ushort_t* __restrict__ xbp,
                                                 const float* __restrict__ g,
                                                 const float* __restrict__ b) {
  int bn = blockIdx.x;
  int c = threadIdx.x;
  const float* row = in + (size_t)bn * 384;
  float x0 = row[c*3+0], x1 = row[c*3+1], x2 = row[c*3+2];
  float nv = sqrtf(x0*x0 + x1*x1 + x2*x2 + EPSF);
  float s1 = nv, s2 = nv*nv;
#pragma unroll
  for (int off = 32; off >= 1; off >>= 1) {
    s1 += __shfl_down(s1, off);
    s2 += __shfl_down(s2, off);
  }
  __shared__ float red[4];
  int lane = threadIdx.x & 63, w = threadIdx.x >> 6;
  if (lane == 0) { red[w*2] = s1; red[w*2+1] = s2; }
  __syncthreads();
  float tot1 = red[0] + red[2], tot2 = red[1] + red[3];
  float mu  = tot1 * (1.f/128.f);
  float var = tot2 * (1.f/128.f) - mu*mu;
  float rsig = rsqrtf(var + LNEPSF);
  float nnew = g[c] * ((nv - mu) * rsig) + b[c];
  float sc = nnew / nv;
  if (xbp) {
    size_t rb = (size_t)bn * 384;   // 3 rows of 128
    xbp[rb + c]       = f2bf(x0*sc);
    xbp[rb + 128 + c] = f2bf(x1*sc);
    xbp[rb + 256 + c] = f2bf(x2*sc);
  } else {
    float* orow = out + (size_t)bn * 384;
    orow[c*3+0] = x0*sc; orow[c*3+1] = x1*sc; orow[c*3+2] = x2*sc;
  }
}

// ---------------- fused QKV + conv1 MFMA GEMM ----------------
// C[m][n] = sum_c Wall[m][c] * xb[n][c], n = pt*3+d (24576), M = 1664.
// grid = 192 n-tiles(128) x 4 m-quarters(416). Block 256 thr (4 waves, each 32 n).
// Epilogue: per-wave LDS transpose -> contiguous stores. q/k/v bf16 [pt][d*384+m];
// conv1 quarter (mq==3) stored FP32: YZf/NBf [pt][d*256 + sub*128 + o] (precision:
// bf16 storage of conv1 partials caused absmax 0.148 > 0.118 in r6).
#define XT_PITCH 132
#define WT_PITCH 132
#define TR_PITCH 36
__global__ __launch_bounds__(256, 2) void qkv_conv1_mfma(
    const ushort_t* __restrict__ xb, const ushort_t* __restrict__ Wall,
    ushort_t* __restrict__ q, ushort_t* __restrict__ k, ushort_t* __restrict__ v,
    float* __restrict__ YZf, float* __restrict__ NBf) {
  __shared__ ushort_t xs[128*XT_PITCH];
  __shared__ ushort_t wt[32*WT_PITCH];
  __shared__ float tr[4][32*TR_PITCH];
  int nb = blockIdx.x % 192;
  int mq = blockIdx.x / 192;
  int n0 = nb * 128;
  int t = threadIdx.x;
  int w = t >> 6, lane = t & 63, ql = lane & 31, hl = lane >> 5;
  // stage X tile (128 x 256B), pitch-padded
  for (int idx = t; idx < 2048; idx += 256) {
    int n = idx >> 4, c16 = idx & 15;
    bf16x8 gv = *(const bf16x8*)&xb[(size_t)(n0 + n)*128 + c16*8];
    ushort_t* dst = &xs[n*XT_PITCH + c16*8];
    *(bf16x4*)dst = __builtin_shufflevector(gv, gv, 0, 1, 2, 3);
    *(bf16x4*)(dst+4) = __builtin_shufflevector(gv, gv, 4, 5, 6, 7);
  }
  __syncthreads();
  // X fragments (B-operand) to regs: this wave's n = n0 + w*32 + ql
  bf16x8 xf[8];
  {
    const ushort_t* xr = &xs[(w*32 + ql)*XT_PITCH + hl*8];
#pragma unroll
    for (int cs = 0; cs < 8; ++cs) {
      bf16x4 lo = *(const bf16x4*)(xr + cs*16);
      bf16x4 hi = *(const bf16x4*)(xr + cs*16 + 4);
      xf[cs] = __builtin_shufflevector(lo, hi, 0, 1, 2, 3, 4, 5, 6, 7);
    }
  }
  int ng = n0 + w*32 + ql;
  int pt = ng / 3;
  int d  = ng - 3*pt;
  float* trw = tr[w];
  for (int mt = 0; mt < 13; ++mt) {
    int m0 = mq*416 + mt*32;
    __syncthreads();
    // stage W tile (32 x 256B)
    for (int idx = t; idx < 512; idx += 256) {
      int mm = idx >> 4, c16 = idx & 15;
      bf16x8 gv = *(const bf16x8*)&Wall[(size_t)(m0 + mm)*128 + c16*8];
      ushort_t* dst = &wt[mm*WT_PITCH + c16*8];
      *(bf16x4*)dst = __builtin_shufflevector(gv, gv, 0, 1, 2, 3);
      *(bf16x4*)(dst+4) = __builtin_shufflevector(gv, gv, 4, 5, 6, 7);
    }
    __syncthreads();
    f32x16 acc;
#pragma unroll
    for (int r = 0; r < 16; ++r) acc[r] = 0.f;
    const ushort_t* wr = &wt[ql*WT_PITCH + hl*8];
#pragma unroll
    for (int cs = 0; cs < 8; ++cs) {
      bf16x4 lo = *(const bf16x4*)(wr + cs*16);
      bf16x4 hi = *(const bf16x4*)(wr + cs*16 + 4);
      bf16x8 af = __builtin_shufflevector(lo, hi, 0, 1, 2, 3, 4, 5, 6, 7);
      acc = __builtin_amdgcn_mfma_f32_32x32x16_bf16(af, xf[cs], acc, 0, 0, 0);
    }
    // per-wave LDS transpose: tr[n-local][m-local]
#pragma unroll
    for (int r = 0; r < 16; ++r) {
      int mrow = (r&3) + 8*(r>>2) + 4*hl;
      trw[ql*TR_PITCH + mrow] = acc[r];
    }
    asm volatile("s_waitcnt lgkmcnt(0)" ::: "memory");
    float4 c0 = *(float4*)&trw[ql*TR_PITCH + hl*16 + 0];
    float4 c1 = *(float4*)&trw[ql*TR_PITCH + hl*16 + 4];
    float4 c2 = *(float4*)&trw[ql*TR_PITCH + hl*16 + 8];
    float4 c3 = *(float4*)&trw[ql*TR_PITCH + hl*16 + 12];
    asm volatile("s_waitcnt lgkmcnt(0)" ::: "memory");   // reads done before next-tile writes
    int mg = m0 + hl*16;
    if (m0 < 1152) {
      uint4 s0, s1;
      s0.x = pack2(c0.x, c0.y); s0.y = pack2(c0.z, c0.w);
      s0.z = pack2(c1.x, c1.y); s0.w = pack2(c1.z, c1.w);
      s1.x = pack2(c2.x, c2.y); s1.y = pack2(c2.z, c2.w);
      s1.z = pack2(c3.x, c3.y); s1.w = pack2(c3.z, c3.w);
      ushort_t* dst;
      if (m0 < 384)       dst = q + (size_t)pt*1152 + d*384 + mg;
      else if (m0 < 768)  dst = k + (size_t)pt*1152 + d*384 + (mg - 384);
      else                dst = v + (size_t)pt*1152 + d*384 + (mg - 768);
      *(uint4*)dst = s0;
      *(uint4*)(dst + 8) = s1;
    } else {
      int mat = mg - 1152;
      int sub = mat >> 7, o = mat & 127;
      float* base = (sub < 2) ? YZf : NBf;
      float* dst = base + (size_t)pt*768 + d*256 + (sub & 1)*128 + o;
      *(float4*)dst = c0;
      *(float4*)(dst + 4) = c1;
      *(float4*)(dst + 8) = c2;
      *(float4*)(dst + 12) = c3;
    }
  }
}

// ---------------- conv1 post: gather + add + vnleaky + mean over K (fp32 in) ----------------
__global__ __launch_bounds__(128) void conv1_post(const float* __restrict__ YZf,
    const float* __restrict__ NBf, const int* __restrict__ knn_index,
    float* __restrict__ knnm) {
  int bn = blockIdx.x;
  int b = bn / NFIX, n = bn % NFIX;
  int t = threadIdx.x;
  __shared__ int sidx[KNN];
  if (t < KNN) sidx[t] = knn_index[(b*KNN + t)*NFIX + n];
  __syncthreads();
  float yb[3], zb[3];
#pragma unroll
  for (int d = 0; d < 3; ++d) {
    yb[d] = NBf[(size_t)bn*768 + d*256 + t];
    zb[d] = NBf[(size_t)bn*768 + d*256 + 128 + t];
  }
  float om[3] = {0.f, 0.f, 0.f};
#pragma unroll
  for (int kk = 0; kk < KNN; ++kk) {
    const float* r = YZf + (size_t)sidx[kk]*768;
    float p[3], dd[3];
#pragma unroll
    for (int d = 0; d < 3; ++d) {
      p[d]  = r[d*256 + t] + yb[d];
      dd[d] = r[d*256 + 128 + t] + zb[d];
    }
    float res[3];
    vnleaky3(p, dd, res);
    om[0] += res[0]; om[1] += res[1]; om[2] += res[2];
  }
  size_t ob = (size_t)bn*384 + t*3;
  knnm[ob+0] = om[0] * (1.f/KNN);
  knnm[ob+1] = om[1] * (1.f/KNN);
  knnm[ob+2] = om[2] * (1.f/KNN);
}

// ---------------- V transpose: v'[pt][d*384+h*64+o] -> vT[(bh*192 + o*3+d)][pt] ----------------
__global__ __launch_bounds__(256) void vtrans_kernel(const ushort_t* __restrict__ v,
                                                     ushort_t* __restrict__ vT) {
  int T = blockIdx.x * 256 + threadIdx.x;
  int pt0 = (T & 255) * 8;
  int row = T >> 8;
  int bh = row / 192, ch = row % 192;
  int b = bh / HH, h = bh % HH;
  int ol = ch / 3, dd = ch - 3*ol;
  size_t src = (size_t)dd*384 + h*64 + ol;
  ushort_t tmp[8];
#pragma unroll
  for (int i = 0; i < 8; ++i)
    tmp[i] = v[(size_t)(b*NFIX + pt0 + i)*1152 + src];
  uint4 o;
  o.x = (uint_t)tmp[0] | ((uint_t)tmp[1] << 16);
  o.y = (uint_t)tmp[2] | ((uint_t)tmp[3] << 16);
  o.z = (uint_t)tmp[4] | ((uint_t)tmp[5] << 16);
  o.w = (uint_t)tmp[6] | ((uint_t)tmp[7] << 16);
  *(uint4*)&vT[(size_t)row*2048 + pt0] = o;
}

// ---------------- attention: LDS-staged MFMA flash, 4 waves / block, split-K=4 ----------------
// Q/K channel (reduction) order: red = d*64 + m_local; addr = pt*1152 + d*384 + h*64 + m.
__global__ __launch_bounds__(256, 2) void attn_kernel(const ushort_t* __restrict__ q,
    const ushort_t* __restrict__ k, const ushort_t* __restrict__ vT,
    ushort_t* __restrict__ opart, float* __restrict__ lpart) {
  __shared__ ushort_t kt[32*196];
  __shared__ ushort_t vt[192*36];
  __shared__ ushort_t plds[4][32*36];
  __shared__ float alds[4][32];
  int blk = blockIdx.x;
  int qt = blk % 16;
  int bh = (blk / 16) % 24;
  int split = blk / (16*24);
  int b = bh / HH, h = bh % HH;
  int t = threadIdx.x;
  int w = t >> 6, lane = t & 63, ql = lane & 31, hl = lane >> 5;
  int qrow0 = qt*128 + w*32;
  const ushort_t* qpb = q + (size_t)(b*NFIX + qrow0 + ql)*1152 + h*64;
  bf16x8 qf[12];
#pragma unroll
  for (int cs = 0; cs < 12; ++cs) {
    int red0 = cs*16 + hl*8;
    int dq = red0 >> 6, ml = red0 & 63;
    qf[cs] = *(const bf16x8*)(qpb + dq*384 + ml);
  }
  f32x16 acc[6];
#pragma unroll
  for (int nt = 0; nt < 6; ++nt)
#pragma unroll
    for (int r = 0; r < 16; ++r) acc[nt][r] = 0.f;
  float lsum = 0.f;
  int koff0 = split * 512;
  for (int kb = 0; kb < 16; ++kb) {
    int koff = koff0 + kb*32;
    __syncthreads();
    for (int idx = t; idx < 768; idx += 256) {
      int kp = idx / 24, c16 = idx % 24;
      int red0 = c16*8;
      int dk = red0 >> 6, ml = red0 & 63;
      bf16x8 gv = *(const bf16x8*)&k[(size_t)(b*NFIX + koff + kp)*1152 + dk*384 + h*64 + ml];
      bf16x4 lo = __builtin_shufflevector(gv, gv, 0, 1, 2, 3);
      bf16x4 hi = __builtin_shufflevector(gv, gv, 4, 5, 6, 7);
      ushort_t* dst = &kt[kp*196 + c16*8];
      *(bf16x4*)dst = lo;
      *(bf16x4*)(dst + 4) = hi;
    }
    for (int idx = t; idx < 768; idx += 256) {
      int ch = idx >> 2, c4 = idx & 3;
      bf16x8 gv = *(const bf16x8*)&vT[((size_t)bh*192 + ch)*2048 + koff + c4*8];
      bf16x4 lo = __builtin_shufflevector(gv, gv, 0, 1, 2, 3);
      bf16x4 hi = __builtin_shufflevector(gv, gv, 4, 5, 6, 7);
      ushort_t* dst = &vt[ch*36 + c4*8];
      *(bf16x4*)dst = lo;
      *(bf16x4*)(dst + 4) = hi;
    }
    __syncthreads();
    f32x16 sc;
#pragma unroll
    for (int r = 0; r < 16; ++r) sc[r] = 0.f;
#pragma unroll
    for (int cs = 0; cs < 12; ++cs) {
      const ushort_t* kr = &kt[ql*196 + cs*16 + hl*8];
      bf16x4 alo = *(const bf16x4*)kr;
      bf16x4 ahi = *(const bf16x4*)(kr + 4);
      bf16x8 af = __builtin_shufflevector(alo, ahi, 0, 1, 2, 3, 4, 5, 6, 7);
      sc = __builtin_amdgcn_mfma_f32_32x32x16_bf16(af, qf[cs], sc, 0, 0, 0);
    }
#pragma unroll
    for (int g2 = 0; g2 < 4; ++g2) {
      bf16x4 pw;
#pragma unroll
      for (int rr = 0; rr < 4; ++rr) {
        float p = __builtin_amdgcn_exp2f(sc[g2*4 + rr]);
        lsum += p;
        pw[rr] = (short)f2bf(p);
      }
      *(bf16x4*)&plds[w][ql*36 + g2*8 + hl*4] = pw;
    }
    asm volatile("s_waitcnt lgkmcnt(0)" ::: "memory");
#pragma unroll
    for (int s = 0; s < 2; ++s) {
      const ushort_t* pr = &plds[w][ql*36 + s*16 + hl*8];
      bf16x4 plo = *(const bf16x4*)pr;
      bf16x4 phi = *(const bf16x4*)(pr + 4);
      bf16x8 pa = __builtin_shufflevector(plo, phi, 0, 1, 2, 3, 4, 5, 6, 7);
#pragma unroll
      for (int nt = 0; nt < 6; ++nt) {
        const ushort_t* vr = &vt[(nt*32 + ql)*36 + s*16 + hl*8];
        bf16x4 vlo = *(const bf16x4*)vr;
        bf16x4 vhi = *(const bf16x4*)(vr + 4);
        bf16x8 vf = __builtin_shufflevector(vlo, vhi, 0, 1, 2, 3, 4, 5, 6, 7);
        acc[nt] = __builtin_amdgcn_mfma_f32_32x32x16_bf16(pa, vf, acc[nt], 0, 0, 0);
      }
    }
  }
  lsum += __shfl_xor(lsum, 32);
  if (lane < 32) {
    alds[w][ql] = 1.0f / lsum;
    lpart[(size_t)split*24*NFIX + (size_t)bh*NFIX + qrow0 + ql] = lsum;
  }
  asm volatile("s_waitcnt lgkmcnt(0)" ::: "memory");
  float lv[4][4];
#pragma unroll
  for (int g2 = 0; g2 < 4; ++g2) {
    f32x4 tv = *(const f32x4*)&alds[w][8*g2 + 4*hl];
#pragma unroll
    for (int rr = 0; rr < 4; ++rr) lv[g2][rr] = tv[rr];
  }
  ushort_t* op = opart + (size_t)split*(size_t)8192*1152
               + (size_t)(b*NFIX + qrow0)*1152 + h*192 + ql;
#pragma unroll
  for (int nt = 0; nt < 6; ++nt)
#pragma unroll
    for (int r = 0; r < 16; ++r) {
      int qrow = (r&3) + 8*(r>>2) + 4*hl;
      op[(size_t)qrow*1152 + nt*32] = f2bf(acc[nt][r] * lv[r>>2][r&3]);
    }
}

// ---------------- combine 4 split-K bf16 partials -> f32 obuf ----------------
__global__ __launch_bounds__(256) void attn_combine(const ushort_t* __restrict__ opart,
    const float* __restrict__ lpart, float* __restrict__ obuf) {
  size_t i = ((size_t)blockIdx.x * 256 + threadIdx.x) * 8;
  int bn = (int)(i / 1152);
  int ch = (int)(i % 1152);
  int b = bn >> 11, n = bn & 2047;
  int h = ch / 192;
  size_t lidx = (size_t)(b*HH + h)*NFIX + n;
  float l0 = lpart[lidx];
  float l1 = lpart[(size_t)24*NFIX + lidx];
  float l2 = lpart[(size_t)48*NFIX + lidx];
  float l3 = lpart[(size_t)72*NFIX + lidx];
  float rd = 1.f / (l0 + l1 + l2 + l3);
  float wsc[4] = { l0*rd, l1*rd, l2*rd, l3*rd };
  float o[8];
#pragma unroll
  for (int j = 0; j < 8; ++j) o[j] = 0.f;
  const size_t stride = (size_t)8192*1152;
#pragma unroll
  for (int s = 0; s < 4; ++s) {
    const ushort_t* pp = opart + s*stride + i;
    uint4 raw = *(const uint4*)pp;
    const ushort_t* us = (const ushort_t*)&raw;
#pragma unroll
    for (int j = 0; j < 8; ++j) o[j] += wsc[s] * bf2f(us[j]);
  }
  *(float4*)&obuf[i]     = make_float4(o[0], o[1], o[2], o[3]);
  *(float4*)&obuf[i + 4] = make_float4(o[4], o[5], o[6], o[7]);
}

// ---------------- x_mid = x + M @ o_attn + W2b @ knnmean ----------------
__global__ __launch_bounds__(128) void x1mid_kernel(const float* __restrict__ x,
    const float* __restrict__ oattn, const float* __restrict__ knnm,
    const float* __restrict__ Mt, const float* __restrict__ W2bt,
    float* __restrict__ out) {
  __shared__ float os[8*1156];
  __shared__ float ksm[8*388];
  int bnb = blockIdx.x * 8;
  int t = threadIdx.x;
  for (int idx = t; idx < 8*288; idx += 128) {
    int pt = idx / 288, j4 = (idx % 288) * 4;
    *(float4*)&os[pt*1156 + j4] = *(const float4*)&oattn[((size_t)bnb + pt)*1152 + j4];
  }
  for (int idx = t; idx < 8*96; idx += 128) {
    int pt = idx / 96, j4 = (idx % 96) * 4;
    *(float4*)&ksm[pt*388 + j4] = *(const float4*)&knnm[((size_t)bnb + pt)*384 + j4];
  }
  __syncthreads();
  int tc = t & 31;
  int tp = t >> 5;
  float acc[4][2][3];
#pragma unroll
  for (int u = 0; u < 4; ++u)
#pragma unroll
    for (int pp = 0; pp < 2; ++pp)
#pragma unroll
      for (int d = 0; d < 3; ++d)
        acc[u][pp][d] = x[((size_t)bnb + 2*tp + pp)*384 + (tc + 32*u)*3 + d];
  for (int oi = 0; oi < 96; ++oi) {
    float w[4][4];
#pragma unroll
    for (int oo = 0; oo < 4; ++oo)
#pragma unroll
      for (int u = 0; u < 4; ++u)
        w[oo][u] = Mt[(size_t)(4*oi+oo)*128 + tc + 32*u];
#pragma unroll
    for (int pp = 0; pp < 2; ++pp) {
      float vals[12];
      LOAD12(vals, &os[(2*tp+pp)*1156 + 12*oi]);
#pragma unroll
      for (int oo = 0; oo < 4; ++oo)
#pragma unroll
        for (int u = 0; u < 4; ++u)
#pragma unroll
          for (int d = 0; d < 3; ++d)
            acc[u][pp][d] += w[oo][u] * vals[oo*3+d];
    }
  }
  for (int ci = 0; ci < 32; ++ci) {
    float w[4][4];
#pragma unroll
    for (int cc = 0; cc < 4; ++cc)
#pragma unroll
      for (int u = 0; u < 4; ++u)
        w[cc][u] = W2bt[(size_t)(4*ci+cc)*128 + tc + 32*u];
#pragma unroll
    for (int pp = 0; pp < 2; ++pp) {
      float vals[12];
      LOAD12(vals, &ksm[(2*tp+pp)*388 + 12*ci]);
#pragma unroll
      for (int cc = 0; cc < 4; ++cc)
#pragma unroll
        for (int u = 0; u < 4; ++u)
#pragma unroll
          for (int d = 0; d < 3; ++d)
            acc[u][pp][d] += w[cc][u] * vals[cc*3+d];
    }
  }
#pragma unroll
  for (int u = 0; u < 4; ++u)
#pragma unroll
    for (int pp = 0; pp < 2; ++pp)
#pragma unroll
      for (int d = 0; d < 3; ++d)
        out[((size_t)bnb + 2*tp + pp)*384 + (tc + 32*u)*3 + d] = acc[u][pp][d];
}

// ---------------- conv3: VNLinearLeakyReLU 128 -> 256 ----------------
__global__ __launch_bounds__(256) void conv3_kernel(const float* __restrict__ in,
    const float* __restrict__ W3t, const float* __restrict__ U3t,
    float* __restrict__ h3) {
  __shared__ float ins[4*384];
  int bnb = blockIdx.x * 4;
  int t = threadIdx.x;
  for (int idx = t; idx < 4*96; idx += 256)
    *(float4*)&ins[idx*4] = *(const float4*)&in[(size_t)bnb*384 + idx*4];
  __syncthreads();
  float p[4][3], dd[4][3];
#pragma unroll
  for (int pt = 0; pt < 4; ++pt)
#pragma unroll
    for (int d = 0; d < 3; ++d) { p[pt][d] = 0.f; dd[pt][d] = 0.f; }
  for (int ci = 0; ci < 32; ++ci) {
    float w3[4], u3[4];
#pragma unroll
    for (int cc = 0; cc < 4; ++cc) {
      int c = 4*ci + cc;
      w3[cc] = W3t[c*256 + t];
      u3[cc] = U3t[c*256 + t];
    }
#pragma unroll
    for (int pt = 0; pt < 4; ++pt) {
      float vals[12];
      LOAD12(vals, &ins[pt*384 + 12*ci]);
#pragma unroll
      for (int cc = 0; cc < 4; ++cc)
#pragma unroll
        for (int d = 0; d < 3; ++d) {
          float xv = vals[cc*3+d];
          p[pt][d]  += w3[cc]*xv;
          dd[pt][d] += u3[cc]*xv;
        }
    }
  }
#pragma unroll
  for (int pt = 0; pt < 4; ++pt) {
    float res[3];
    vnleaky3(p[pt], dd[pt], res);
    size_t ob = ((size_t)bnb + pt)*768 + t*3;
    h3[ob+0] = res[0]; h3[ob+1] = res[1]; h3[ob+2] = res[2];
  }
}

// ---------------- conv4: VNLinearLeakyReLU 256 -> 128, + residual ----------------
__global__ __launch_bounds__(128) void conv4_kernel(const float* __restrict__ h3,
    const float* __restrict__ W4t, const float* __restrict__ U4t,
    float* __restrict__ out) {
  __shared__ float ins[4*768];
  int bnb = blockIdx.x * 4;
  int t = threadIdx.x;
  for (int idx = t; idx < 4*192; idx += 128)
    *(float4*)&ins[idx*4] = *(const float4*)&h3[(size_t)bnb*768 + idx*4];
  __syncthreads();
  float p[4][3], dd[4][3];
#pragma unroll
  for (int pt = 0; pt < 4; ++pt)
#pragma unroll
    for (int d = 0; d < 3; ++d) { p[pt][d] = 0.f; dd[pt][d] = 0.f; }
  for (int ci = 0; ci < 64; ++ci) {
    float w4[4], u4[4];
#pragma unroll
    for (int cc = 0; cc < 4; ++cc) {
      int c2 = 4*ci + cc;
      w4[cc] = W4t[c2*128 + t];
      u4[cc] = U4t[c2*128 + t];
    }
#pragma unroll
    for (int pt = 0; pt < 4; ++pt) {
      float vals[12];
      LOAD12(vals, &ins[pt*768 + 12*ci]);
#pragma unroll
      for (int cc = 0; cc < 4; ++cc)
#pragma unroll
        for (int d = 0; d < 3; ++d) {
          float xv = vals[cc*3+d];
          p[pt][d]  += w4[cc]*xv;
          dd[pt][d] += u4[cc]*xv;
        }
    }
  }
#pragma unroll
  for (int pt = 0; pt < 4; ++pt) {
    float res[3];
    vnleaky3(p[pt], dd[pt], res);
    float* orow = out + ((size_t)bnb + pt)*384 + t*3;
    orow[0] += res[0]; orow[1] += res[1]; orow[2] += res[2];
  }
}

extern "C" void kernel_launch(void* const* d_in, const int* in_sizes, int n_in,
                              void* d_out, int out_size, void* d_ws, size_t ws_size,
                              hipStream_t stream) {
  const float* x   = (const float*)d_in[0];
  const int* knn   = (const int*)d_in[1];
  const float* g1  = (const float*)d_in[2];
  const float* b1  = (const float*)d_in[3];
  const float* g2  = (const float*)d_in[4];
  const float* b2  = (const float*)d_in[5];
  const float* Wq  = (const float*)d_in[6];
  const float* Wk  = (const float*)d_in[7];
  const float* Wv  = (const float*)d_in[8];
  const float* Wo  = (const float*)d_in[9];
  const float* W1  = (const float*)d_in[10];
  const float* U1  = (const float*)d_in[11];
  const float* W2  = (const float*)d_in[12];
  const float* W3  = (const float*)d_in[13];
  const float* U3  = (const float*)d_in[14];
  const float* W4  = (const float*)d_in[15];
  const float* U4  = (const float*)d_in[16];
  float* out = (float*)d_out;
  (void)n_in; (void)out_size; (void)ws_size;

  const size_t BN = (size_t)in_sizes[0] / 384;   // 8192

  float* ws    = (float*)d_ws;
  float* obuf  = ws;                          // BN*1152 f32 (combined attention out)
  float* knnm  = obuf + BN*1152;              // BN*384 f32
  ushort_t* xbp = (ushort_t*)(knnm + BN*384); // BN*384 bf16 (LN1 out, de-interleaved)
  ushort_t* qb = xbp + BN*384;                // BN*1152 bf16
  ushort_t* kb = qb + BN*1152;
  ushort_t* vb = kb + BN*1152;
  ushort_t* vT = vb + BN*1152;
  ushort_t* Wall = vT + BN*1152;              // 212992 bf16
  float* Mt   = (float*)(Wall + 212992);      // 49152
  float* W2bt = Mt + 49152;
  float* W3t  = W2bt + 16384;
  float* U3t  = W3t + 32768;
  float* W4t  = U3t + 32768;
  float* U4t  = W4t + 32768;
  ushort_t* opart = (ushort_t*)(U4t + 32768); // 4 * BN*1152 bf16
  float* lpart = (float*)(opart + 4*BN*1152); // 4*24*2048 f32
  // YZf/NBf (BN*768 f32 each = 50 MB) alias opart (75.5 MB): conv1_post runs before attn.
  float* YZf = (float*)opart;
  float* NBf = YZf + BN*768;
  float* nx2 = (float*)qb;   // q dead after attention
  float* h3  = (float*)kb;   // k+v dead after attention (BN*768 f32 fits in kb+vb)

  prep_weights<<<1600, 256, 0, stream>>>(Wq, Wk, Wv, Wo, W1, U1, W2, W3, U3, W4, U4,
                                         Wall, Mt, W2bt, W3t, U3t, W4t, U4t);
  ln_kernel<<<(int)BN, 128, 0, stream>>>(x, nullptr, xbp, g1, b1);
  qkv_conv1_mfma<<<192*4, 256, 0, stream>>>(xbp, Wall, qb, kb, vb, YZf, NBf);
  conv1_post<<<(int)BN, 128, 0, stream>>>(YZf, NBf, knn, knnm);
  vtrans_kernel<<<(int)(BN*1152/8/256), 256, 0, stream>>>(vb, vT);
  attn_kernel<<<16*24*4, 256, 0, stream>>>(qb, kb, vT, opart, lpart);
  attn_combine<<<(int)(BN*1152/8/256), 256, 0, stream>>>(opart, lpart, obuf);
  x1mid_kernel<<<(int)(BN/8), 128, 0, stream>>>(x, obuf, knnm, Mt, W2bt, out);
  ln_kernel<<<(int)BN, 128, 0, stream>>>(out, nx2, nullptr, g2, b2);
  conv3_kernel<<<(int)(BN/4), 256, 0, stream>>>(nx2, W3t, U3t, h3);
  conv4_kernel<<<(int)(BN/4), 128, 0, stream>>>(h3, W4t, U4t, out);
}

// Round 8
// 568.818 us; speedup vs baseline: 5.3557x; 1.1112x over previous
//
#include <hip/hip_runtime.h>
#include <math.h>

// Problem constants (fixed by setup_inputs): B=4, N=2048, C=128, H=6, K=8
#define NFIX 2048
#define HH 6
#define KNN 8
#define NSLOPE 0.2f
#define EPSF 1e-6f
#define LNEPSF 1e-5f
// 0.125 (softmax scale) * log2(e), folded into Wq rows so S-MFMA output is exp2-ready
#define QSCALE 0.18033688011112042f

typedef unsigned short ushort_t;
typedef unsigned int uint_t;
typedef __attribute__((ext_vector_type(8))) short bf16x8;
typedef __attribute__((ext_vector_type(4))) short bf16x4;
typedef __attribute__((ext_vector_type(16))) float f32x16;
typedef __attribute__((ext_vector_type(4))) float f32x4;

__device__ __forceinline__ ushort_t f2bf(float f) {
  union { float f; unsigned u; } v; v.f = f;
  unsigned r = v.u + 0x7fff + ((v.u >> 16) & 1);   // RNE
  return (ushort_t)(r >> 16);
}
__device__ __forceinline__ float bf2f(ushort_t u) {
  union { uint_t u; float f; } v; v.u = ((uint_t)u) << 16; return v.f;
}
__device__ __forceinline__ uint_t pack2(float a, float b) {
  return (uint_t)f2bf(a) | ((uint_t)f2bf(b) << 16);
}

#define LOAD12(dst, ptr) { \
  float4 _r0 = *(const float4*)((ptr));   \
  float4 _r1 = *(const float4*)((ptr)+4); \
  float4 _r2 = *(const float4*)((ptr)+8); \
  dst[0]=_r0.x; dst[1]=_r0.y; dst[2]=_r0.z; dst[3]=_r0.w; \
  dst[4]=_r1.x; dst[5]=_r1.y; dst[6]=_r1.z; dst[7]=_r1.w; \
  dst[8]=_r2.x; dst[9]=_r2.y; dst[10]=_r2.z; dst[11]=_r2.w; }

__device__ __forceinline__ void vnleaky3(const float* p, const float* dv, float* out) {
  float dot = p[0]*dv[0] + p[1]*dv[1] + p[2]*dv[2];
  float dsq = dv[0]*dv[0] + dv[1]*dv[1] + dv[2]*dv[2] + EPSF;
  float f = dot / dsq;
#pragma unroll
  for (int d = 0; d < 3; ++d) {
    float neg = p[d] - f * dv[d];
    out[d] = NSLOPE * p[d] + (1.f - NSLOPE) * ((dot >= 0.f) ? p[d] : neg);
  }
}

// ---------------- weight prep ----------------
// Wall bf16 [1664][128]: rows 0..383 Wq*QSCALE | 384..767 Wk | 768..1151 Wv |
//   1152..1663 conv1 CW (W1a | U1a | W1b-W1a | U1b-U1a).
// Then fp32: Mt 49152 | W2bt 16384 | W3t 32768 | U3t 32768 | W4t 32768 | U4t 32768.
__global__ void prep_weights(const float* __restrict__ Wq, const float* __restrict__ Wk,
                             const float* __restrict__ Wv, const float* __restrict__ Wo,
                             const float* __restrict__ W1, const float* __restrict__ U1,
                             const float* __restrict__ W2, const float* __restrict__ W3,
                             const float* __restrict__ U3, const float* __restrict__ W4,
                             const float* __restrict__ U4,
                             ushort_t* __restrict__ Wall,
                             float* __restrict__ Mt, float* __restrict__ W2bt,
                             float* __restrict__ W3t, float* __restrict__ U3t,
                             float* __restrict__ W4t, float* __restrict__ U4t) {
  int idx = blockIdx.x * 256 + threadIdx.x;
  if (idx < 212992) {
    int m = idx >> 7, c = idx & 127;
    float val;
    if (m < 384)       val = Wq[m*128 + c] * QSCALE;
    else if (m < 768)  val = Wk[(m-384)*128 + c];
    else if (m < 1152) val = Wv[(m-768)*128 + c];
    else {
      int j = m - 1152;
      if (j < 128)      val = W1[j*256 + c];
      else if (j < 256) val = U1[(j-128)*256 + c];
      else if (j < 384) { int o = j-256; val = W1[o*256 + 128 + c] - W1[o*256 + c]; }
      else              { int o = j-384; val = U1[o*256 + 128 + c] - U1[o*256 + c]; }
    }
    Wall[idx] = f2bf(val); return;
  }
  idx -= 212992;
  if (idx < 49152) {
    int o = idx / 128, c = idx % 128;
    float s = 0.f;
    for (int cp = 0; cp < 128; ++cp) s += W2[c*256 + cp] * Wo[cp*384 + o];
    Mt[idx] = s; return;
  }
  idx -= 49152;
  if (idx < 16384) { int c2 = idx / 128, c = idx % 128; W2bt[idx] = W2[c*256 + 128 + c2]; return; }
  idx -= 16384;
  if (idx < 32768) { int c = idx / 256, o = idx % 256; W3t[idx] = W3[o*128 + c]; return; }
  idx -= 32768;
  if (idx < 32768) { int c = idx / 256, o = idx % 256; U3t[idx] = U3[o*128 + c]; return; }
  idx -= 32768;
  if (idx < 32768) { int c = idx / 128, o = idx % 128; W4t[idx] = W4[o*256 + c]; return; }
  idx -= 32768;
  if (idx < 32768) { int c = idx / 128, o = idx % 128; U4t[idx] = U4[o*256 + c]; return; }
}

// ---------------- VN LayerNorm: xbp!=null -> bf16 de-interleaved out; else fp32 out ----------------
__global__ __launch_bounds__(128) void ln_kernel(const float* __restrict__ in,
                                                 float* __restrict__ out,
                                                 ushort_t* __restrict__ xbp,
                                                 const float* __restrict__ g,
                                                 const float* __restrict__ b) {
  int bn = blockIdx.x;
  int c = threadIdx.x;
  const float* row = in + (size_t)bn * 384;
  float x0 = row[c*3+0], x1 = row[c*3+1], x2 = row[c*3+2];
  float nv = sqrtf(x0*x0 + x1*x1 + x2*x2 + EPSF);
  float s1 = nv, s2 = nv*nv;
#pragma unroll
  for (int off = 32; off >= 1; off >>= 1) {
    s1 += __shfl_down(s1, off);
    s2 += __shfl_down(s2, off);
  }
  __shared__ float red[4];
  int lane = threadIdx.x & 63, w = threadIdx.x >> 6;
  if (lane == 0) { red[w*2] = s1; red[w*2+1] = s2; }
  __syncthreads();
  float tot1 = red[0] + red[2], tot2 = red[1] + red[3];
  float mu  = tot1 * (1.f/128.f);
  float var = tot2 * (1.f/128.f) - mu*mu;
  float rsig = rsqrtf(var + LNEPSF);
  float nnew = g[c] * ((nv - mu) * rsig) + b[c];
  float sc = nnew / nv;
  if (xbp) {
    size_t rb = (size_t)bn * 384;   // 3 rows of 128
    xbp[rb + c]       = f2bf(x0*sc);
    xbp[rb + 128 + c] = f2bf(x1*sc);
    xbp[rb + 256 + c] = f2bf(x2*sc);
  } else {
    float* orow = out + (size_t)bn * 384;
    orow[c*3+0] = x0*sc; orow[c*3+1] = x1*sc; orow[c*3+2] = x2*sc;
  }
}

// ---------------- fused QKV + conv1 MFMA GEMM ----------------
// C[m][n] = sum_c Wall[m][c] * xb[n][c], n = pt*3+d (24576), M = 1664.
// grid = 192 n-tiles(128) x 4 m-quarters(416). conv1 quarter stored FP32 (precision).
#define XT_PITCH 132
#define WT_PITCH 132
#define TR_PITCH 36
__global__ __launch_bounds__(256, 2) void qkv_conv1_mfma(
    const ushort_t* __restrict__ xb, const ushort_t* __restrict__ Wall,
    ushort_t* __restrict__ q, ushort_t* __restrict__ k, ushort_t* __restrict__ v,
    float* __restrict__ YZf, float* __restrict__ NBf) {
  __shared__ ushort_t xs[128*XT_PITCH];
  __shared__ ushort_t wt[32*WT_PITCH];
  __shared__ float tr[4][32*TR_PITCH];
  int nb = blockIdx.x % 192;
  int mq = blockIdx.x / 192;
  int n0 = nb * 128;
  int t = threadIdx.x;
  int w = t >> 6, lane = t & 63, ql = lane & 31, hl = lane >> 5;
  for (int idx = t; idx < 2048; idx += 256) {
    int n = idx >> 4, c16 = idx & 15;
    bf16x8 gv = *(const bf16x8*)&xb[(size_t)(n0 + n)*128 + c16*8];
    ushort_t* dst = &xs[n*XT_PITCH + c16*8];
    *(bf16x4*)dst = __builtin_shufflevector(gv, gv, 0, 1, 2, 3);
    *(bf16x4*)(dst+4) = __builtin_shufflevector(gv, gv, 4, 5, 6, 7);
  }
  __syncthreads();
  bf16x8 xf[8];
  {
    const ushort_t* xr = &xs[(w*32 + ql)*XT_PITCH + hl*8];
#pragma unroll
    for (int cs = 0; cs < 8; ++cs) {
      bf16x4 lo = *(const bf16x4*)(xr + cs*16);
      bf16x4 hi = *(const bf16x4*)(xr + cs*16 + 4);
      xf[cs] = __builtin_shufflevector(lo, hi, 0, 1, 2, 3, 4, 5, 6, 7);
    }
  }
  int ng = n0 + w*32 + ql;
  int pt = ng / 3;
  int d  = ng - 3*pt;
  float* trw = tr[w];
  for (int mt = 0; mt < 13; ++mt) {
    int m0 = mq*416 + mt*32;
    __syncthreads();
    for (int idx = t; idx < 512; idx += 256) {
      int mm = idx >> 4, c16 = idx & 15;
      bf16x8 gv = *(const bf16x8*)&Wall[(size_t)(m0 + mm)*128 + c16*8];
      ushort_t* dst = &wt[mm*WT_PITCH + c16*8];
      *(bf16x4*)dst = __builtin_shufflevector(gv, gv, 0, 1, 2, 3);
      *(bf16x4*)(dst+4) = __builtin_shufflevector(gv, gv, 4, 5, 6, 7);
    }
    __syncthreads();
    f32x16 acc;
#pragma unroll
    for (int r = 0; r < 16; ++r) acc[r] = 0.f;
    const ushort_t* wr = &wt[ql*WT_PITCH + hl*8];
#pragma unroll
    for (int cs = 0; cs < 8; ++cs) {
      bf16x4 lo = *(const bf16x4*)(wr + cs*16);
      bf16x4 hi = *(const bf16x4*)(wr + cs*16 + 4);
      bf16x8 af = __builtin_shufflevector(lo, hi, 0, 1, 2, 3, 4, 5, 6, 7);
      acc = __builtin_amdgcn_mfma_f32_32x32x16_bf16(af, xf[cs], acc, 0, 0, 0);
    }
#pragma unroll
    for (int r = 0; r < 16; ++r) {
      int mrow = (r&3) + 8*(r>>2) + 4*hl;
      trw[ql*TR_PITCH + mrow] = acc[r];
    }
    asm volatile("s_waitcnt lgkmcnt(0)" ::: "memory");
    float4 c0 = *(float4*)&trw[ql*TR_PITCH + hl*16 + 0];
    float4 c1 = *(float4*)&trw[ql*TR_PITCH + hl*16 + 4];
    float4 c2 = *(float4*)&trw[ql*TR_PITCH + hl*16 + 8];
    float4 c3 = *(float4*)&trw[ql*TR_PITCH + hl*16 + 12];
    asm volatile("s_waitcnt lgkmcnt(0)" ::: "memory");
    int mg = m0 + hl*16;
    if (m0 < 1152) {
      uint4 s0, s1;
      s0.x = pack2(c0.x, c0.y); s0.y = pack2(c0.z, c0.w);
      s0.z = pack2(c1.x, c1.y); s0.w = pack2(c1.z, c1.w);
      s1.x = pack2(c2.x, c2.y); s1.y = pack2(c2.z, c2.w);
      s1.z = pack2(c3.x, c3.y); s1.w = pack2(c3.z, c3.w);
      ushort_t* dst;
      if (m0 < 384)       dst = q + (size_t)pt*1152 + d*384 + mg;
      else if (m0 < 768)  dst = k + (size_t)pt*1152 + d*384 + (mg - 384);
      else                dst = v + (size_t)pt*1152 + d*384 + (mg - 768);
      *(uint4*)dst = s0;
      *(uint4*)(dst + 8) = s1;
    } else {
      int mat = mg - 1152;
      int sub = mat >> 7, o = mat & 127;
      float* base = (sub < 2) ? YZf : NBf;
      float* dst = base + (size_t)pt*768 + d*256 + (sub & 1)*128 + o;
      *(float4*)dst = c0;
      *(float4*)(dst + 4) = c1;
      *(float4*)(dst + 8) = c2;
      *(float4*)(dst + 12) = c3;
    }
  }
}

// ---------------- conv1 post: gather + add + vnleaky + mean over K (fp32 in) ----------------
__global__ __launch_bounds__(128) void conv1_post(const float* __restrict__ YZf,
    const float* __restrict__ NBf, const int* __restrict__ knn_index,
    float* __restrict__ knnm) {
  int bn = blockIdx.x;
  int b = bn / NFIX, n = bn % NFIX;
  int t = threadIdx.x;
  __shared__ int sidx[KNN];
  if (t < KNN) sidx[t] = knn_index[(b*KNN + t)*NFIX + n];
  __syncthreads();
  float yb[3], zb[3];
#pragma unroll
  for (int d = 0; d < 3; ++d) {
    yb[d] = NBf[(size_t)bn*768 + d*256 + t];
    zb[d] = NBf[(size_t)bn*768 + d*256 + 128 + t];
  }
  float om[3] = {0.f, 0.f, 0.f};
#pragma unroll
  for (int kk = 0; kk < KNN; ++kk) {
    const float* r = YZf + (size_t)sidx[kk]*768;
    float p[3], dd[3];
#pragma unroll
    for (int d = 0; d < 3; ++d) {
      p[d]  = r[d*256 + t] + yb[d];
      dd[d] = r[d*256 + 128 + t] + zb[d];
    }
    float res[3];
    vnleaky3(p, dd, res);
    om[0] += res[0]; om[1] += res[1]; om[2] += res[2];
  }
  size_t ob = (size_t)bn*384 + t*3;
  knnm[ob+0] = om[0] * (1.f/KNN);
  knnm[ob+1] = om[1] * (1.f/KNN);
  knnm[ob+2] = om[2] * (1.f/KNN);
}

// ---------------- V transpose: v'[pt][d*384+h*64+o] -> vT[(bh*192 + o*3+d)][pt] ----------------
__global__ __launch_bounds__(256) void vtrans_kernel(const ushort_t* __restrict__ v,
                                                     ushort_t* __restrict__ vT) {
  int T = blockIdx.x * 256 + threadIdx.x;
  int pt0 = (T & 255) * 8;
  int row = T >> 8;
  int bh = row / 192, ch = row % 192;
  int b = bh / HH, h = bh % HH;
  int ol = ch / 3, dd = ch - 3*ol;
  size_t src = (size_t)dd*384 + h*64 + ol;
  ushort_t tmp[8];
#pragma unroll
  for (int i = 0; i < 8; ++i)
    tmp[i] = v[(size_t)(b*NFIX + pt0 + i)*1152 + src];
  uint4 o;
  o.x = (uint_t)tmp[0] | ((uint_t)tmp[1] << 16);
  o.y = (uint_t)tmp[2] | ((uint_t)tmp[3] << 16);
  o.z = (uint_t)tmp[4] | ((uint_t)tmp[5] << 16);
  o.w = (uint_t)tmp[6] | ((uint_t)tmp[7] << 16);
  *(uint4*)&vT[(size_t)row*2048 + pt0] = o;
}

// ---------------- attention v3: dbuf LDS staging, shfl-P transpose, 1 barrier/iter ----------------
// 4 waves/block (128 q), split-K=4, k-tile 32. LDS 53 KB -> ~3 blocks/CU.
__global__ __launch_bounds__(256, 2) void attn_kernel(const ushort_t* __restrict__ q,
    const ushort_t* __restrict__ k, const ushort_t* __restrict__ vT,
    ushort_t* __restrict__ opart, float* __restrict__ lpart) {
  __shared__ ushort_t kt[2][32*196];
  __shared__ ushort_t vt[2][192*36];
  __shared__ float alds[4][32];
  int blk = blockIdx.x;
  int qt = blk % 16;
  int bh = (blk / 16) % 24;
  int split = blk / (16*24);
  int b = bh / HH, h = bh % HH;
  int t = threadIdx.x;
  int w = t >> 6, lane = t & 63, ql = lane & 31, hl = lane >> 5;
  int qrow0 = qt*128 + w*32;
  // Q fragments (B-operand)
  const ushort_t* qpb = q + (size_t)(b*NFIX + qrow0 + ql)*1152 + h*64;
  bf16x8 qf[12];
#pragma unroll
  for (int cs = 0; cs < 12; ++cs) {
    int red0 = cs*16 + hl*8;
    int dq = red0 >> 6, ml = red0 & 63;
    qf[cs] = *(const bf16x8*)(qpb + dq*384 + ml);
  }
  // staging descriptors (3 K chunks + 3 V chunks per thread)
  const ushort_t* ksrc[3]; int kdsto[3];
  const ushort_t* vsrc[3]; int vdsto[3];
#pragma unroll
  for (int j = 0; j < 3; ++j) {
    int idx = t + j*256;
    int kp = idx / 24, c16 = idx % 24;
    int red0 = c16*8;
    int dk = red0 >> 6, ml = red0 & 63;
    ksrc[j] = k + (size_t)(b*NFIX + kp)*1152 + dk*384 + h*64 + ml;
    kdsto[j] = kp*196 + c16*8;
    int ch = idx >> 2, c4 = idx & 3;
    vsrc[j] = vT + ((size_t)bh*192 + ch)*2048 + c4*8;
    vdsto[j] = ch*36 + c4*8;
  }
  f32x16 acc[6];
#pragma unroll
  for (int nt = 0; nt < 6; ++nt)
#pragma unroll
    for (int r = 0; r < 16; ++r) acc[nt][r] = 0.f;
  float lsum = 0.f;
  int koff0 = split * 512;
  // prefetch tile 0 and write buf 0
  bf16x8 kpre[3], vpre[3];
#pragma unroll
  for (int j = 0; j < 3; ++j) {
    kpre[j] = *(const bf16x8*)(ksrc[j] + (size_t)koff0*1152);
    vpre[j] = *(const bf16x8*)(vsrc[j] + koff0);
  }
#pragma unroll
  for (int j = 0; j < 3; ++j) {
    ushort_t* kd = &kt[0][kdsto[j]];
    *(bf16x4*)kd = __builtin_shufflevector(kpre[j], kpre[j], 0, 1, 2, 3);
    *(bf16x4*)(kd+4) = __builtin_shufflevector(kpre[j], kpre[j], 4, 5, 6, 7);
    ushort_t* vd = &vt[0][vdsto[j]];
    *(bf16x4*)vd = __builtin_shufflevector(vpre[j], vpre[j], 0, 1, 2, 3);
    *(bf16x4*)(vd+4) = __builtin_shufflevector(vpre[j], vpre[j], 4, 5, 6, 7);
  }
  __syncthreads();
  for (int kb = 0; kb < 16; ++kb) {
    int cur = kb & 1;
    if (kb < 15) {
      int koff = koff0 + (kb+1)*32;
#pragma unroll
      for (int j = 0; j < 3; ++j) {
        kpre[j] = *(const bf16x8*)(ksrc[j] + (size_t)koff*1152);
        vpre[j] = *(const bf16x8*)(vsrc[j] + koff);
      }
    }
    // QK: S^T[kp][q]
    f32x16 sc;
#pragma unroll
    for (int r = 0; r < 16; ++r) sc[r] = 0.f;
    const ushort_t* ktc = kt[cur];
#pragma unroll
    for (int cs = 0; cs < 12; ++cs) {
      const ushort_t* kr = &ktc[ql*196 + cs*16 + hl*8];
      bf16x4 alo = *(const bf16x4*)kr;
      bf16x4 ahi = *(const bf16x4*)(kr + 4);
      bf16x8 af = __builtin_shufflevector(alo, ahi, 0, 1, 2, 3, 4, 5, 6, 7);
      sc = __builtin_amdgcn_mfma_f32_32x32x16_bf16(af, qf[cs], sc, 0, 0, 0);
    }
    // softmax (no-max) + pack + shfl_xor(32) transpose into A-operand layout
    uint_t u[8], pex[8];
#pragma unroll
    for (int g2 = 0; g2 < 4; ++g2) {
      float p0 = __builtin_amdgcn_exp2f(sc[g2*4 + 0]);
      float p1 = __builtin_amdgcn_exp2f(sc[g2*4 + 1]);
      float p2 = __builtin_amdgcn_exp2f(sc[g2*4 + 2]);
      float p3 = __builtin_amdgcn_exp2f(sc[g2*4 + 3]);
      lsum += (p0 + p1) + (p2 + p3);
      u[2*g2]   = pack2(p0, p1);
      u[2*g2+1] = pack2(p2, p3);
    }
#pragma unroll
    for (int j = 0; j < 8; ++j) pex[j] = (uint_t)__shfl_xor((int)u[j], 32);
    const ushort_t* vtc = vt[cur];
#pragma unroll
    for (int s = 0; s < 2; ++s) {
      uint4 au;
      au.x = hl ? pex[4*s+2] : u[4*s+0];
      au.y = hl ? pex[4*s+3] : u[4*s+1];
      au.z = hl ? u[4*s+2]   : pex[4*s+0];
      au.w = hl ? u[4*s+3]   : pex[4*s+1];
      union { uint4 ui; bf16x8 bv; } cvt; cvt.ui = au;
      bf16x8 pa = cvt.bv;
#pragma unroll
      for (int nt = 0; nt < 6; ++nt) {
        const ushort_t* vr = &vtc[(nt*32 + ql)*36 + s*16 + hl*8];
        bf16x4 vlo = *(const bf16x4*)vr;
        bf16x4 vhi = *(const bf16x4*)(vr + 4);
        bf16x8 vf = __builtin_shufflevector(vlo, vhi, 0, 1, 2, 3, 4, 5, 6, 7);
        acc[nt] = __builtin_amdgcn_mfma_f32_32x32x16_bf16(pa, vf, acc[nt], 0, 0, 0);
      }
    }
    if (kb < 15) {
      int nxt = cur ^ 1;
#pragma unroll
      for (int j = 0; j < 3; ++j) {
        ushort_t* kd = &kt[nxt][kdsto[j]];
        *(bf16x4*)kd = __builtin_shufflevector(kpre[j], kpre[j], 0, 1, 2, 3);
        *(bf16x4*)(kd+4) = __builtin_shufflevector(kpre[j], kpre[j], 4, 5, 6, 7);
        ushort_t* vd = &vt[nxt][vdsto[j]];
        *(bf16x4*)vd = __builtin_shufflevector(vpre[j], vpre[j], 0, 1, 2, 3);
        *(bf16x4*)(vd+4) = __builtin_shufflevector(vpre[j], vpre[j], 4, 5, 6, 7);
      }
    }
    __syncthreads();
  }
  lsum += __shfl_xor(lsum, 32);
  if (lane < 32) {
    alds[w][ql] = 1.0f / lsum;
    lpart[(size_t)split*24*NFIX + (size_t)bh*NFIX + qrow0 + ql] = lsum;
  }
  asm volatile("s_waitcnt lgkmcnt(0)" ::: "memory");
  float lv[4][4];
#pragma unroll
  for (int g2 = 0; g2 < 4; ++g2) {
    f32x4 tv = *(const f32x4*)&alds[w][8*g2 + 4*hl];
#pragma unroll
    for (int rr = 0; rr < 4; ++rr) lv[g2][rr] = tv[rr];
  }
  ushort_t* op = opart + (size_t)split*(size_t)8192*1152
               + (size_t)(b*NFIX + qrow0)*1152 + h*192 + ql;
#pragma unroll
  for (int nt = 0; nt < 6; ++nt)
#pragma unroll
    for (int r = 0; r < 16; ++r) {
      int qrow = (r&3) + 8*(r>>2) + 4*hl;
      op[(size_t)qrow*1152 + nt*32] = f2bf(acc[nt][r] * lv[r>>2][r&3]);
    }
}

// ---------------- x_mid = x + M @ o_attn + W2b @ knnmean (combine fused into staging) ----------------
__global__ __launch_bounds__(128) void x1mid_kernel(const float* __restrict__ x,
    const ushort_t* __restrict__ opart, const float* __restrict__ lpart,
    const float* __restrict__ knnm,
    const float* __restrict__ Mt, const float* __restrict__ W2bt,
    float* __restrict__ out) {
  __shared__ float os[8*1156];
  __shared__ float ksm[8*388];
  __shared__ float wls[8][6][4];
  int bnb = blockIdx.x * 8;
  int t = threadIdx.x;
  if (t < 48) {
    int pt = t / 6, h = t % 6;
    int bn = bnb + pt;
    int b = bn >> 11, n = bn & 2047;
    size_t lidx = (size_t)(b*HH + h)*NFIX + n;
    float l0 = lpart[lidx];
    float l1 = lpart[(size_t)24*NFIX + lidx];
    float l2 = lpart[(size_t)48*NFIX + lidx];
    float l3 = lpart[(size_t)72*NFIX + lidx];
    float rd = 1.f / (l0 + l1 + l2 + l3);
    wls[pt][h][0] = l0*rd; wls[pt][h][1] = l1*rd;
    wls[pt][h][2] = l2*rd; wls[pt][h][3] = l3*rd;
  }
  __syncthreads();
  const size_t stride = (size_t)8192*1152;
  for (int idx = t; idx < 8*288; idx += 128) {
    int pt = idx / 288, j4 = (idx % 288) * 4;
    int h = j4 / 192;
    size_t base = ((size_t)bnb + pt)*1152 + j4;
    float o0 = 0.f, o1 = 0.f, o2 = 0.f, o3 = 0.f;
#pragma unroll
    for (int s = 0; s < 4; ++s) {
      bf16x4 r = *(const bf16x4*)&opart[s*stride + base];
      float wsc = wls[pt][h][s];
      o0 += wsc * bf2f((ushort_t)r[0]);
      o1 += wsc * bf2f((ushort_t)r[1]);
      o2 += wsc * bf2f((ushort_t)r[2]);
      o3 += wsc * bf2f((ushort_t)r[3]);
    }
    *(float4*)&os[pt*1156 + j4] = make_float4(o0, o1, o2, o3);
  }
  for (int idx = t; idx < 8*96; idx += 128) {
    int pt = idx / 96, j4 = (idx % 96) * 4;
    *(float4*)&ksm[pt*388 + j4] = *(const float4*)&knnm[((size_t)bnb + pt)*384 + j4];
  }
  __syncthreads();
  int tc = t & 31;
  int tp = t >> 5;
  float acc[4][2][3];
#pragma unroll
  for (int u = 0; u < 4; ++u)
#pragma unroll
    for (int pp = 0; pp < 2; ++pp)
#pragma unroll
      for (int d = 0; d < 3; ++d)
        acc[u][pp][d] = x[((size_t)bnb + 2*tp + pp)*384 + (tc + 32*u)*3 + d];
  for (int oi = 0; oi < 96; ++oi) {
    float w[4][4];
#pragma unroll
    for (int oo = 0; oo < 4; ++oo)
#pragma unroll
      for (int u = 0; u < 4; ++u)
        w[oo][u] = Mt[(size_t)(4*oi+oo)*128 + tc + 32*u];
#pragma unroll
    for (int pp = 0; pp < 2; ++pp) {
      float vals[12];
      LOAD12(vals, &os[(2*tp+pp)*1156 + 12*oi]);
#pragma unroll
      for (int oo = 0; oo < 4; ++oo)
#pragma unroll
        for (int u = 0; u < 4; ++u)
#pragma unroll
          for (int d = 0; d < 3; ++d)
            acc[u][pp][d] += w[oo][u] * vals[oo*3+d];
    }
  }
  for (int ci = 0; ci < 32; ++ci) {
    float w[4][4];
#pragma unroll
    for (int cc = 0; cc < 4; ++cc)
#pragma unroll
      for (int u = 0; u < 4; ++u)
        w[cc][u] = W2bt[(size_t)(4*ci+cc)*128 + tc + 32*u];
#pragma unroll
    for (int pp = 0; pp < 2; ++pp) {
      float vals[12];
      LOAD12(vals, &ksm[(2*tp+pp)*388 + 12*ci]);
#pragma unroll
      for (int cc = 0; cc < 4; ++cc)
#pragma unroll
        for (int u = 0; u < 4; ++u)
#pragma unroll
          for (int d = 0; d < 3; ++d)
            acc[u][pp][d] += w[cc][u] * vals[cc*3+d];
    }
  }
#pragma unroll
  for (int u = 0; u < 4; ++u)
#pragma unroll
    for (int pp = 0; pp < 2; ++pp)
#pragma unroll
      for (int d = 0; d < 3; ++d)
        out[((size_t)bnb + 2*tp + pp)*384 + (tc + 32*u)*3 + d] = acc[u][pp][d];
}

// ---------------- conv3: VNLinearLeakyReLU 128 -> 256 ----------------
__global__ __launch_bounds__(256) void conv3_kernel(const float* __restrict__ in,
    const float* __restrict__ W3t, const float* __restrict__ U3t,
    float* __restrict__ h3) {
  __shared__ float ins[4*384];
  int bnb = blockIdx.x * 4;
  int t = threadIdx.x;
  for (int idx = t; idx < 4*96; idx += 256)
    *(float4*)&ins[idx*4] = *(const float4*)&in[(size_t)bnb*384 + idx*4];
  __syncthreads();
  float p[4][3], dd[4][3];
#pragma unroll
  for (int pt = 0; pt < 4; ++pt)
#pragma unroll
    for (int d = 0; d < 3; ++d) { p[pt][d] = 0.f; dd[pt][d] = 0.f; }
  for (int ci = 0; ci < 32; ++ci) {
    float w3[4], u3[4];
#pragma unroll
    for (int cc = 0; cc < 4; ++cc) {
      int c = 4*ci + cc;
      w3[cc] = W3t[c*256 + t];
      u3[cc] = U3t[c*256 + t];
    }
#pragma unroll
    for (int pt = 0; pt < 4; ++pt) {
      float vals[12];
      LOAD12(vals, &ins[pt*384 + 12*ci]);
#pragma unroll
      for (int cc = 0; cc < 4; ++cc)
#pragma unroll
        for (int d = 0; d < 3; ++d) {
          float xv = vals[cc*3+d];
          p[pt][d]  += w3[cc]*xv;
          dd[pt][d] += u3[cc]*xv;
        }
    }
  }
#pragma unroll
  for (int pt = 0; pt < 4; ++pt) {
    float res[3];
    vnleaky3(p[pt], dd[pt], res);
    size_t ob = ((size_t)bnb + pt)*768 + t*3;
    h3[ob+0] = res[0]; h3[ob+1] = res[1]; h3[ob+2] = res[2];
  }
}

// ---------------- conv4: VNLinearLeakyReLU 256 -> 128, + residual ----------------
__global__ __launch_bounds__(128) void conv4_kernel(const float* __restrict__ h3,
    const float* __restrict__ W4t, const float* __restrict__ U4t,
    float* __restrict__ out) {
  __shared__ float ins[4*768];
  int bnb = blockIdx.x * 4;
  int t = threadIdx.x;
  for (int idx = t; idx < 4*192; idx += 128)
    *(float4*)&ins[idx*4] = *(const float4*)&h3[(size_t)bnb*768 + idx*4];
  __syncthreads();
  float p[4][3], dd[4][3];
#pragma unroll
  for (int pt = 0; pt < 4; ++pt)
#pragma unroll
    for (int d = 0; d < 3; ++d) { p[pt][d] = 0.f; dd[pt][d] = 0.f; }
  for (int ci = 0; ci < 64; ++ci) {
    float w4[4], u4[4];
#pragma unroll
    for (int cc = 0; cc < 4; ++cc) {
      int c2 = 4*ci + cc;
      w4[cc] = W4t[c2*128 + t];
      u4[cc] = U4t[c2*128 + t];
    }
#pragma unroll
    for (int pt = 0; pt < 4; ++pt) {
      float vals[12];
      LOAD12(vals, &ins[pt*768 + 12*ci]);
#pragma unroll
      for (int cc = 0; cc < 4; ++cc)
#pragma unroll
        for (int d = 0; d < 3; ++d) {
          float xv = vals[cc*3+d];
          p[pt][d]  += w4[cc]*xv;
          dd[pt][d] += u4[cc]*xv;
        }
    }
  }
#pragma unroll
  for (int pt = 0; pt < 4; ++pt) {
    float res[3];
    vnleaky3(p[pt], dd[pt], res);
    float* orow = out + ((size_t)bnb + pt)*384 + t*3;
    orow[0] += res[0]; orow[1] += res[1]; orow[2] += res[2];
  }
}

extern "C" void kernel_launch(void* const* d_in, const int* in_sizes, int n_in,
                              void* d_out, int out_size, void* d_ws, size_t ws_size,
                              hipStream_t stream) {
  const float* x   = (const float*)d_in[0];
  const int* knn   = (const int*)d_in[1];
  const float* g1  = (const float*)d_in[2];
  const float* b1  = (const float*)d_in[3];
  const float* g2  = (const float*)d_in[4];
  const float* b2  = (const float*)d_in[5];
  const float* Wq  = (const float*)d_in[6];
  const float* Wk  = (const float*)d_in[7];
  const float* Wv  = (const float*)d_in[8];
  const float* Wo  = (const float*)d_in[9];
  const float* W1  = (const float*)d_in[10];
  const float* U1  = (const float*)d_in[11];
  const float* W2  = (const float*)d_in[12];
  const float* W3  = (const float*)d_in[13];
  const float* U3  = (const float*)d_in[14];
  const float* W4  = (const float*)d_in[15];
  const float* U4  = (const float*)d_in[16];
  float* out = (float*)d_out;
  (void)n_in; (void)out_size; (void)ws_size;

  const size_t BN = (size_t)in_sizes[0] / 384;   // 8192

  float* ws    = (float*)d_ws;
  float* knnm  = ws;                          // BN*384 f32
  ushort_t* xbp = (ushort_t*)(knnm + BN*384); // BN*384 bf16 (LN1 out, de-interleaved)
  ushort_t* qb = xbp + BN*384;                // BN*1152 bf16
  ushort_t* kb = qb + BN*1152;
  ushort_t* vb = kb + BN*1152;
  ushort_t* vT = vb + BN*1152;
  ushort_t* Wall = vT + BN*1152;              // 212992 bf16
  float* Mt   = (float*)(Wall + 212992);      // 49152
  float* W2bt = Mt + 49152;
  float* W3t  = W2bt + 16384;
  float* U3t  = W3t + 32768;
  float* W4t  = U3t + 32768;
  float* U4t  = W4t + 32768;
  ushort_t* opart = (ushort_t*)(U4t + 32768); // 4 * BN*1152 bf16
  float* lpart = (float*)(opart + 4*BN*1152); // 4*24*2048 f32
  // YZf/NBf (BN*768 f32 each = 50 MB) alias opart (75.5 MB): conv1_post runs before attn.
  float* YZf = (float*)opart;
  float* NBf = YZf + BN*768;
  float* nx2 = (float*)qb;   // q dead after attention
  float* h3  = (float*)kb;   // k+v dead after attention (BN*768 f32 fits in kb+vb)

  prep_weights<<<1600, 256, 0, stream>>>(Wq, Wk, Wv, Wo, W1, U1, W2, W3, U3, W4, U4,
                                         Wall, Mt, W2bt, W3t, U3t, W4t, U4t);
  ln_kernel<<<(int)BN, 128, 0, stream>>>(x, nullptr, xbp, g1, b1);
  qkv_conv1_mfma<<<192*4, 256, 0, stream>>>(xbp, Wall, qb, kb, vb, YZf, NBf);
  conv1_post<<<(int)BN, 128, 0, stream>>>(YZf, NBf, knn, knnm);
  vtrans_kernel<<<(int)(BN*1152/8/256), 256, 0, stream>>>(vb, vT);
  attn_kernel<<<16*24*4, 256, 0, stream>>>(qb, kb, vT, opart, lpart);
  x1mid_kernel<<<(int)(BN/8), 128, 0, stream>>>(x, opart, lpart, knnm, Mt, W2bt, out);
  ln_kernel<<<(int)BN, 128, 0, stream>>>(out, nx2, nullptr, g2, b2);
  conv3_kernel<<<(int)(BN/4), 256, 0, stream>>>(nx2, W3t, U3t, h3);
  conv4_kernel<<<(int)(BN/4), 128, 0, stream>>>(h3, W4t, U4t, out);
}

// Round 9
// 515.962 us; speedup vs baseline: 5.9043x; 1.1024x over previous
//
#include <hip/hip_runtime.h>
#include <math.h>

// Problem constants (fixed by setup_inputs): B=4, N=2048, C=128, H=6, K=8
#define NFIX 2048
#define HH 6
#define KNN 8
#define NSLOPE 0.2f
#define EPSF 1e-6f
#define LNEPSF 1e-5f
// 0.125 (softmax scale) * log2(e), folded into Wq rows so S-MFMA output is exp2-ready
#define QSCALE 0.18033688011112042f

typedef unsigned short ushort_t;
typedef unsigned int uint_t;
typedef __attribute__((ext_vector_type(8))) short bf16x8;
typedef __attribute__((ext_vector_type(4))) short bf16x4;
typedef __attribute__((ext_vector_type(8))) _Float16 f16x8;
typedef __attribute__((ext_vector_type(4))) _Float16 f16x4;
typedef __attribute__((ext_vector_type(16))) float f32x16;
typedef __attribute__((ext_vector_type(4))) float f32x4;

__device__ __forceinline__ ushort_t f2bf(float f) {
  union { float f; unsigned u; } v; v.f = f;
  unsigned r = v.u + 0x7fff + ((v.u >> 16) & 1);   // RNE
  return (ushort_t)(r >> 16);
}
__device__ __forceinline__ float bf2f(ushort_t u) {
  union { uint_t u; float f; } v; v.u = ((uint_t)u) << 16; return v.f;
}
__device__ __forceinline__ uint_t pack2(float a, float b) {
  return (uint_t)f2bf(a) | ((uint_t)f2bf(b) << 16);
}

#define LOAD12(dst, ptr) { \
  float4 _r0 = *(const float4*)((ptr));   \
  float4 _r1 = *(const float4*)((ptr)+4); \
  float4 _r2 = *(const float4*)((ptr)+8); \
  dst[0]=_r0.x; dst[1]=_r0.y; dst[2]=_r0.z; dst[3]=_r0.w; \
  dst[4]=_r1.x; dst[5]=_r1.y; dst[6]=_r1.z; dst[7]=_r1.w; \
  dst[8]=_r2.x; dst[9]=_r2.y; dst[10]=_r2.z; dst[11]=_r2.w; }

__device__ __forceinline__ void vnleaky3(const float* p, const float* dv, float* out) {
  float dot = p[0]*dv[0] + p[1]*dv[1] + p[2]*dv[2];
  float dsq = dv[0]*dv[0] + dv[1]*dv[1] + dv[2]*dv[2] + EPSF;
  float f = dot / dsq;
#pragma unroll
  for (int d = 0; d < 3; ++d) {
    float neg = p[d] - f * dv[d];
    out[d] = NSLOPE * p[d] + (1.f - NSLOPE) * ((dot >= 0.f) ? p[d] : neg);
  }
}

// ---------------- weight prep ----------------
// Wall bf16 [1664][128] (qkv+conv1 GEMM A). Af16 fp16 [128][512] = [M2 | W2b] rows c.
// fp32: W3t | U3t | W4t | U4t. Threads: 212992+49152+16384+131072 = 409600 = 1600*256.
__global__ void prep_weights(const float* __restrict__ Wq, const float* __restrict__ Wk,
                             const float* __restrict__ Wv, const float* __restrict__ Wo,
                             const float* __restrict__ W1, const float* __restrict__ U1,
                             const float* __restrict__ W2, const float* __restrict__ W3,
                             const float* __restrict__ U3, const float* __restrict__ W4,
                             const float* __restrict__ U4,
                             ushort_t* __restrict__ Wall, _Float16* __restrict__ Af16,
                             float* __restrict__ W3t, float* __restrict__ U3t,
                             float* __restrict__ W4t, float* __restrict__ U4t) {
  int idx = blockIdx.x * 256 + threadIdx.x;
  if (idx < 212992) {
    int m = idx >> 7, c = idx & 127;
    float val;
    if (m < 384)       val = Wq[m*128 + c] * QSCALE;
    else if (m < 768)  val = Wk[(m-384)*128 + c];
    else if (m < 1152) val = Wv[(m-768)*128 + c];
    else {
      int j = m - 1152;
      if (j < 128)      val = W1[j*256 + c];
      else if (j < 256) val = U1[(j-128)*256 + c];
      else if (j < 384) { int o = j-256; val = W1[o*256 + 128 + c] - W1[o*256 + c]; }
      else              { int o = j-384; val = U1[o*256 + 128 + c] - U1[o*256 + c]; }
    }
    Wall[idx] = f2bf(val); return;
  }
  idx -= 212992;
  if (idx < 49152) {
    int j = idx / 128, c = idx % 128;   // M2[c][j] = (W2a@Wo)[c][j]
    float s = 0.f;
    for (int cp = 0; cp < 128; ++cp) s += W2[c*256 + cp] * Wo[cp*384 + j];
    Af16[(size_t)c*512 + j] = (_Float16)s; return;
  }
  idx -= 49152;
  if (idx < 16384) {
    int c2 = idx / 128, c = idx % 128;
    Af16[(size_t)c*512 + 384 + c2] = (_Float16)W2[c*256 + 128 + c2]; return;
  }
  idx -= 16384;
  if (idx < 32768) { int c = idx / 256, o = idx % 256; W3t[idx] = W3[o*128 + c]; return; }
  idx -= 32768;
  if (idx < 32768) { int c = idx / 256, o = idx % 256; U3t[idx] = U3[o*128 + c]; return; }
  idx -= 32768;
  if (idx < 32768) { int c = idx / 128, o = idx % 128; W4t[idx] = W4[o*256 + c]; return; }
  idx -= 32768;
  if (idx < 32768) { int c = idx / 128, o = idx % 128; U4t[idx] = U4[o*256 + c]; return; }
}

// ---------------- LN1: raw x -> xbp (bf16 de-interleaved, normalized) + xdi (fp32 raw de-interleaved) ----------------
__global__ __launch_bounds__(128) void ln1_kernel(const float* __restrict__ in,
                                                  ushort_t* __restrict__ xbp,
                                                  float* __restrict__ xdi,
                                                  const float* __restrict__ g,
                                                  const float* __restrict__ b) {
  int bn = blockIdx.x;
  int c = threadIdx.x;
  const float* row = in + (size_t)bn * 384;
  float x0 = row[c*3+0], x1 = row[c*3+1], x2 = row[c*3+2];
  float nv = sqrtf(x0*x0 + x1*x1 + x2*x2 + EPSF);
  float s1 = nv, s2 = nv*nv;
#pragma unroll
  for (int off = 32; off >= 1; off >>= 1) {
    s1 += __shfl_down(s1, off);
    s2 += __shfl_down(s2, off);
  }
  __shared__ float red[4];
  int lane = threadIdx.x & 63, w = threadIdx.x >> 6;
  if (lane == 0) { red[w*2] = s1; red[w*2+1] = s2; }
  __syncthreads();
  float tot1 = red[0] + red[2], tot2 = red[1] + red[3];
  float mu  = tot1 * (1.f/128.f);
  float var = tot2 * (1.f/128.f) - mu*mu;
  float rsig = rsqrtf(var + LNEPSF);
  float nnew = g[c] * ((nv - mu) * rsig) + b[c];
  float sc = nnew / nv;
  size_t rb = (size_t)bn * 384;
  xbp[rb + c]       = f2bf(x0*sc);
  xbp[rb + 128 + c] = f2bf(x1*sc);
  xbp[rb + 256 + c] = f2bf(x2*sc);
  xdi[rb + c]       = x0;
  xdi[rb + 128 + c] = x1;
  xdi[rb + 256 + c] = x2;
}

// ---------------- LN2: de-interleaved fp32 in/out ----------------
__global__ __launch_bounds__(128) void ln2_kernel(const float* __restrict__ in,
                                                  float* __restrict__ out,
                                                  const float* __restrict__ g,
                                                  const float* __restrict__ b) {
  int bn = blockIdx.x;
  int c = threadIdx.x;
  size_t base = (size_t)bn * 384;
  float x0 = in[base + c], x1 = in[base + 128 + c], x2 = in[base + 256 + c];
  float nv = sqrtf(x0*x0 + x1*x1 + x2*x2 + EPSF);
  float s1 = nv, s2 = nv*nv;
#pragma unroll
  for (int off = 32; off >= 1; off >>= 1) {
    s1 += __shfl_down(s1, off);
    s2 += __shfl_down(s2, off);
  }
  __shared__ float red[4];
  int lane = threadIdx.x & 63, w = threadIdx.x >> 6;
  if (lane == 0) { red[w*2] = s1; red[w*2+1] = s2; }
  __syncthreads();
  float tot1 = red[0] + red[2], tot2 = red[1] + red[3];
  float mu  = tot1 * (1.f/128.f);
  float var = tot2 * (1.f/128.f) - mu*mu;
  float rsig = rsqrtf(var + LNEPSF);
  float nnew = g[c] * ((nv - mu) * rsig) + b[c];
  float sc = nnew / nv;
  out[base + c]       = x0*sc;
  out[base + 128 + c] = x1*sc;
  out[base + 256 + c] = x2*sc;
}

// ---------------- fused QKV + conv1 MFMA GEMM (unchanged from r7) ----------------
#define XT_PITCH 132
#define WT_PITCH 132
#define TR_PITCH 36
__global__ __launch_bounds__(256, 2) void qkv_conv1_mfma(
    const ushort_t* __restrict__ xb, const ushort_t* __restrict__ Wall,
    ushort_t* __restrict__ q, ushort_t* __restrict__ k, ushort_t* __restrict__ v,
    float* __restrict__ YZf, float* __restrict__ NBf) {
  __shared__ ushort_t xs[128*XT_PITCH];
  __shared__ ushort_t wt[32*WT_PITCH];
  __shared__ float tr[4][32*TR_PITCH];
  int nb = blockIdx.x % 192;
  int mq = blockIdx.x / 192;
  int n0 = nb * 128;
  int t = threadIdx.x;
  int w = t >> 6, lane = t & 63, ql = lane & 31, hl = lane >> 5;
  for (int idx = t; idx < 2048; idx += 256) {
    int n = idx >> 4, c16 = idx & 15;
    bf16x8 gv = *(const bf16x8*)&xb[(size_t)(n0 + n)*128 + c16*8];
    ushort_t* dst = &xs[n*XT_PITCH + c16*8];
    *(bf16x4*)dst = __builtin_shufflevector(gv, gv, 0, 1, 2, 3);
    *(bf16x4*)(dst+4) = __builtin_shufflevector(gv, gv, 4, 5, 6, 7);
  }
  __syncthreads();
  bf16x8 xf[8];
  {
    const ushort_t* xr = &xs[(w*32 + ql)*XT_PITCH + hl*8];
#pragma unroll
    for (int cs = 0; cs < 8; ++cs) {
      bf16x4 lo = *(const bf16x4*)(xr + cs*16);
      bf16x4 hi = *(const bf16x4*)(xr + cs*16 + 4);
      xf[cs] = __builtin_shufflevector(lo, hi, 0, 1, 2, 3, 4, 5, 6, 7);
    }
  }
  int ng = n0 + w*32 + ql;
  int pt = ng / 3;
  int d  = ng - 3*pt;
  float* trw = tr[w];
  for (int mt = 0; mt < 13; ++mt) {
    int m0 = mq*416 + mt*32;
    __syncthreads();
    for (int idx = t; idx < 512; idx += 256) {
      int mm = idx >> 4, c16 = idx & 15;
      bf16x8 gv = *(const bf16x8*)&Wall[(size_t)(m0 + mm)*128 + c16*8];
      ushort_t* dst = &wt[mm*WT_PITCH + c16*8];
      *(bf16x4*)dst = __builtin_shufflevector(gv, gv, 0, 1, 2, 3);
      *(bf16x4*)(dst+4) = __builtin_shufflevector(gv, gv, 4, 5, 6, 7);
    }
    __syncthreads();
    f32x16 acc;
#pragma unroll
    for (int r = 0; r < 16; ++r) acc[r] = 0.f;
    const ushort_t* wr = &wt[ql*WT_PITCH + hl*8];
#pragma unroll
    for (int cs = 0; cs < 8; ++cs) {
      bf16x4 lo = *(const bf16x4*)(wr + cs*16);
      bf16x4 hi = *(const bf16x4*)(wr + cs*16 + 4);
      bf16x8 af = __builtin_shufflevector(lo, hi, 0, 1, 2, 3, 4, 5, 6, 7);
      acc = __builtin_amdgcn_mfma_f32_32x32x16_bf16(af, xf[cs], acc, 0, 0, 0);
    }
#pragma unroll
    for (int r = 0; r < 16; ++r) {
      int mrow = (r&3) + 8*(r>>2) + 4*hl;
      trw[ql*TR_PITCH + mrow] = acc[r];
    }
    asm volatile("s_waitcnt lgkmcnt(0)" ::: "memory");
    float4 c0 = *(float4*)&trw[ql*TR_PITCH + hl*16 + 0];
    float4 c1 = *(float4*)&trw[ql*TR_PITCH + hl*16 + 4];
    float4 c2 = *(float4*)&trw[ql*TR_PITCH + hl*16 + 8];
    float4 c3 = *(float4*)&trw[ql*TR_PITCH + hl*16 + 12];
    asm volatile("s_waitcnt lgkmcnt(0)" ::: "memory");
    int mg = m0 + hl*16;
    if (m0 < 1152) {
      uint4 s0, s1;
      s0.x = pack2(c0.x, c0.y); s0.y = pack2(c0.z, c0.w);
      s0.z = pack2(c1.x, c1.y); s0.w = pack2(c1.z, c1.w);
      s1.x = pack2(c2.x, c2.y); s1.y = pack2(c2.z, c2.w);
      s1.z = pack2(c3.x, c3.y); s1.w = pack2(c3.z, c3.w);
      ushort_t* dst;
      if (m0 < 384)       dst = q + (size_t)pt*1152 + d*384 + mg;
      else if (m0 < 768)  dst = k + (size_t)pt*1152 + d*384 + (mg - 384);
      else                dst = v + (size_t)pt*1152 + d*384 + (mg - 768);
      *(uint4*)dst = s0;
      *(uint4*)(dst + 8) = s1;
    } else {
      int mat = mg - 1152;
      int sub = mat >> 7, o = mat & 127;
      float* base = (sub < 2) ? YZf : NBf;
      float* dst = base + (size_t)pt*768 + d*256 + (sub & 1)*128 + o;
      *(float4*)dst = c0;
      *(float4*)(dst + 4) = c1;
      *(float4*)(dst + 8) = c2;
      *(float4*)(dst + 12) = c3;
    }
  }
}

// ---------------- conv1 post: gather + vnleaky + mean -> kmf16 [n=(pt*3+d)][o] fp16 ----------------
__global__ __launch_bounds__(128) void conv1_post(const float* __restrict__ YZf,
    const float* __restrict__ NBf, const int* __restrict__ knn_index,
    _Float16* __restrict__ kmf16) {
  int bn = blockIdx.x;
  int b = bn / NFIX, n = bn % NFIX;
  int t = threadIdx.x;
  __shared__ int sidx[KNN];
  if (t < KNN) sidx[t] = knn_index[(b*KNN + t)*NFIX + n];
  __syncthreads();
  float yb[3], zb[3];
#pragma unroll
  for (int d = 0; d < 3; ++d) {
    yb[d] = NBf[(size_t)bn*768 + d*256 + t];
    zb[d] = NBf[(size_t)bn*768 + d*256 + 128 + t];
  }
  float om[3] = {0.f, 0.f, 0.f};
#pragma unroll
  for (int kk = 0; kk < KNN; ++kk) {
    const float* r = YZf + (size_t)sidx[kk]*768;
    float p[3], dd[3];
#pragma unroll
    for (int d = 0; d < 3; ++d) {
      p[d]  = r[d*256 + t] + yb[d];
      dd[d] = r[d*256 + 128 + t] + zb[d];
    }
    float res[3];
    vnleaky3(p, dd, res);
    om[0] += res[0]; om[1] += res[1]; om[2] += res[2];
  }
#pragma unroll
  for (int d = 0; d < 3; ++d)
    kmf16[((size_t)bn*3 + d)*128 + t] = (_Float16)(om[d] * (1.f/KNN));
}

// ---------------- V transpose (unchanged) ----------------
__global__ __launch_bounds__(256) void vtrans_kernel(const ushort_t* __restrict__ v,
                                                     ushort_t* __restrict__ vT) {
  int T = blockIdx.x * 256 + threadIdx.x;
  int pt0 = (T & 255) * 8;
  int row = T >> 8;
  int bh = row / 192, ch = row % 192;
  int b = bh / HH, h = bh % HH;
  int ol = ch / 3, dd = ch - 3*ol;
  size_t src = (size_t)dd*384 + h*64 + ol;
  ushort_t tmp[8];
#pragma unroll
  for (int i = 0; i < 8; ++i)
    tmp[i] = v[(size_t)(b*NFIX + pt0 + i)*1152 + src];
  uint4 o;
  o.x = (uint_t)tmp[0] | ((uint_t)tmp[1] << 16);
  o.y = (uint_t)tmp[2] | ((uint_t)tmp[3] << 16);
  o.z = (uint_t)tmp[4] | ((uint_t)tmp[5] << 16);
  o.w = (uint_t)tmp[6] | ((uint_t)tmp[7] << 16);
  *(uint4*)&vT[(size_t)row*2048 + pt0] = o;
}

// ---------------- attention (r8 structure; epilogue writes opart[n=(pt*3+d)][h*64+ol]) ----------------
__global__ __launch_bounds__(256, 2) void attn_kernel(const ushort_t* __restrict__ q,
    const ushort_t* __restrict__ k, const ushort_t* __restrict__ vT,
    ushort_t* __restrict__ opart, float* __restrict__ lpart) {
  __shared__ ushort_t kt[2][32*196];
  __shared__ ushort_t vt[2][192*36];
  __shared__ float alds[4][32];
  int blk = blockIdx.x;
  int qt = blk % 16;
  int bh = (blk / 16) % 24;
  int split = blk / (16*24);
  int b = bh / HH, h = bh % HH;
  int t = threadIdx.x;
  int w = t >> 6, lane = t & 63, ql = lane & 31, hl = lane >> 5;
  int qrow0 = qt*128 + w*32;
  const ushort_t* qpb = q + (size_t)(b*NFIX + qrow0 + ql)*1152 + h*64;
  bf16x8 qf[12];
#pragma unroll
  for (int cs = 0; cs < 12; ++cs) {
    int red0 = cs*16 + hl*8;
    int dq = red0 >> 6, ml = red0 & 63;
    qf[cs] = *(const bf16x8*)(qpb + dq*384 + ml);
  }
  const ushort_t* ksrc[3]; int kdsto[3];
  const ushort_t* vsrc[3]; int vdsto[3];
#pragma unroll
  for (int j = 0; j < 3; ++j) {
    int idx = t + j*256;
    int kp = idx / 24, c16 = idx % 24;
    int red0 = c16*8;
    int dk = red0 >> 6, ml = red0 & 63;
    ksrc[j] = k + (size_t)(b*NFIX + kp)*1152 + dk*384 + h*64 + ml;
    kdsto[j] = kp*196 + c16*8;
    int ch = idx >> 2, c4 = idx & 3;
    vsrc[j] = vT + ((size_t)bh*192 + ch)*2048 + c4*8;
    vdsto[j] = ch*36 + c4*8;
  }
  f32x16 acc[6];
#pragma unroll
  for (int nt = 0; nt < 6; ++nt)
#pragma unroll
    for (int r = 0; r < 16; ++r) acc[nt][r] = 0.f;
  float lsum = 0.f;
  int koff0 = split * 512;
  bf16x8 kpre[3], vpre[3];
#pragma unroll
  for (int j = 0; j < 3; ++j) {
    kpre[j] = *(const bf16x8*)(ksrc[j] + (size_t)koff0*1152);
    vpre[j] = *(const bf16x8*)(vsrc[j] + koff0);
  }
#pragma unroll
  for (int j = 0; j < 3; ++j) {
    ushort_t* kd = &kt[0][kdsto[j]];
    *(bf16x4*)kd = __builtin_shufflevector(kpre[j], kpre[j], 0, 1, 2, 3);
    *(bf16x4*)(kd+4) = __builtin_shufflevector(kpre[j], kpre[j], 4, 5, 6, 7);
    ushort_t* vd = &vt[0][vdsto[j]];
    *(bf16x4*)vd = __builtin_shufflevector(vpre[j], vpre[j], 0, 1, 2, 3);
    *(bf16x4*)(vd+4) = __builtin_shufflevector(vpre[j], vpre[j], 4, 5, 6, 7);
  }
  __syncthreads();
  for (int kb = 0; kb < 16; ++kb) {
    int cur = kb & 1;
    if (kb < 15) {
      int koff = koff0 + (kb+1)*32;
#pragma unroll
      for (int j = 0; j < 3; ++j) {
        kpre[j] = *(const bf16x8*)(ksrc[j] + (size_t)koff*1152);
        vpre[j] = *(const bf16x8*)(vsrc[j] + koff);
      }
    }
    f32x16 sc;
#pragma unroll
    for (int r = 0; r < 16; ++r) sc[r] = 0.f;
    const ushort_t* ktc = kt[cur];
#pragma unroll
    for (int cs = 0; cs < 12; ++cs) {
      const ushort_t* kr = &ktc[ql*196 + cs*16 + hl*8];
      bf16x4 alo = *(const bf16x4*)kr;
      bf16x4 ahi = *(const bf16x4*)(kr + 4);
      bf16x8 af = __builtin_shufflevector(alo, ahi, 0, 1, 2, 3, 4, 5, 6, 7);
      sc = __builtin_amdgcn_mfma_f32_32x32x16_bf16(af, qf[cs], sc, 0, 0, 0);
    }
    uint_t u[8], pex[8];
#pragma unroll
    for (int g2 = 0; g2 < 4; ++g2) {
      float p0 = __builtin_amdgcn_exp2f(sc[g2*4 + 0]);
      float p1 = __builtin_amdgcn_exp2f(sc[g2*4 + 1]);
      float p2 = __builtin_amdgcn_exp2f(sc[g2*4 + 2]);
      float p3 = __builtin_amdgcn_exp2f(sc[g2*4 + 3]);
      lsum += (p0 + p1) + (p2 + p3);
      u[2*g2]   = pack2(p0, p1);
      u[2*g2+1] = pack2(p2, p3);
    }
#pragma unroll
    for (int j = 0; j < 8; ++j) pex[j] = (uint_t)__shfl_xor((int)u[j], 32);
    const ushort_t* vtc = vt[cur];
#pragma unroll
    for (int s = 0; s < 2; ++s) {
      uint4 au;
      au.x = hl ? pex[4*s+2] : u[4*s+0];
      au.y = hl ? pex[4*s+3] : u[4*s+1];
      au.z = hl ? u[4*s+2]   : pex[4*s+0];
      au.w = hl ? u[4*s+3]   : pex[4*s+1];
      union { uint4 ui; bf16x8 bv; } cvt; cvt.ui = au;
      bf16x8 pa = cvt.bv;
#pragma unroll
      for (int nt = 0; nt < 6; ++nt) {
        const ushort_t* vr = &vtc[(nt*32 + ql)*36 + s*16 + hl*8];
        bf16x4 vlo = *(const bf16x4*)vr;
        bf16x4 vhi = *(const bf16x4*)(vr + 4);
        bf16x8 vf = __builtin_shufflevector(vlo, vhi, 0, 1, 2, 3, 4, 5, 6, 7);
        acc[nt] = __builtin_amdgcn_mfma_f32_32x32x16_bf16(pa, vf, acc[nt], 0, 0, 0);
      }
    }
    if (kb < 15) {
      int nxt = cur ^ 1;
#pragma unroll
      for (int j = 0; j < 3; ++j) {
        ushort_t* kd = &kt[nxt][kdsto[j]];
        *(bf16x4*)kd = __builtin_shufflevector(kpre[j], kpre[j], 0, 1, 2, 3);
        *(bf16x4*)(kd+4) = __builtin_shufflevector(kpre[j], kpre[j], 4, 5, 6, 7);
        ushort_t* vd = &vt[nxt][vdsto[j]];
        *(bf16x4*)vd = __builtin_shufflevector(vpre[j], vpre[j], 0, 1, 2, 3);
        *(bf16x4*)(vd+4) = __builtin_shufflevector(vpre[j], vpre[j], 4, 5, 6, 7);
      }
    }
    __syncthreads();
  }
  lsum += __shfl_xor(lsum, 32);
  if (lane < 32) {
    alds[w][ql] = 1.0f / lsum;
    lpart[(size_t)split*24*NFIX + (size_t)bh*NFIX + qrow0 + ql] = lsum;
  }
  asm volatile("s_waitcnt lgkmcnt(0)" ::: "memory");
  float lv[4][4];
#pragma unroll
  for (int g2 = 0; g2 < 4; ++g2) {
    f32x4 tv = *(const f32x4*)&alds[w][8*g2 + 4*hl];
#pragma unroll
    for (int rr = 0; rr < 4; ++rr) lv[g2][rr] = tv[rr];
  }
  // opart layout: [split][n = pt*3 + dd][h*64 + ol]
  ushort_t* opb = opart + (size_t)split*(size_t)8192*1152;
  size_t nbase = (size_t)(b*NFIX + qrow0) * 3;
#pragma unroll
  for (int nt = 0; nt < 6; ++nt) {
    int ch = nt*32 + ql;
    int ol = ch / 3, dd = ch - 3*ol;
#pragma unroll
    for (int r = 0; r < 16; ++r) {
      int qrow = (r&3) + 8*(r>>2) + 4*hl;
      opb[(nbase + (size_t)qrow*3 + dd)*384 + h*64 + ol] = f2bf(acc[nt][r] * lv[r>>2][r&3]);
    }
  }
}

// ---------------- x1mid fp16 MFMA: xmid[n][c] = xdi + [M|W2b] @ [o_comb|km] ----------------
// grid 256 blocks, 384 thr (6 waves: nsub=w>>1, m-half=w&1). n-tile 96 (32 pts), K=512 in 8 panels of 64.
#define AP 68          // panel row pitch in fp16 (64 + 4 pad -> 2-way bank aliasing, free)
__global__ __launch_bounds__(384) void x1mid_mfma(
    const float* __restrict__ xdi, const ushort_t* __restrict__ opart,
    const float* __restrict__ lpart, const _Float16* __restrict__ kmf16,
    const _Float16* __restrict__ Af16, float* __restrict__ xmid) {
  __shared__ __align__(16) char smem[33536];
  _Float16* As = (_Float16*)smem;                 // 128 x AP = 17408 B
  _Float16* Bt = (_Float16*)(smem + 17408);       //  96 x AP = 13056 B
  float* wlsL  = (float*)(smem + 30464);          //  32 x 6 x 4 = 3072 B
  float* trbase = (float*)smem;                   // epilogue overlay (6*32*34*4 = 26112 B)
  int blk = blockIdx.x;
  int n0 = blk * 96;       // divisible by 3 -> 32 whole points
  int pt0 = blk * 32;
  int t = threadIdx.x;
  int w = t >> 6, lane = t & 63, ql = lane & 31, hl = lane >> 5;
  int nsub = w >> 1, mh = w & 1;
  if (t < 192) {
    int ptl = t / 6, h = t % 6;
    int ptg = pt0 + ptl;
    int b = ptg >> 11, n = ptg & 2047;
    size_t lidx = (size_t)(b*HH + h)*NFIX + n;
    float l0 = lpart[lidx];
    float l1 = lpart[(size_t)24*NFIX + lidx];
    float l2 = lpart[(size_t)48*NFIX + lidx];
    float l3 = lpart[(size_t)72*NFIX + lidx];
    float rd = 1.f / (l0 + l1 + l2 + l3);
    float* wp = &wlsL[(ptl*6 + h)*4];
    wp[0] = l0*rd; wp[1] = l1*rd; wp[2] = l2*rd; wp[3] = l3*rd;
  }
  f32x16 acc[2];
#pragma unroll
  for (int m2 = 0; m2 < 2; ++m2)
#pragma unroll
    for (int r = 0; r < 16; ++r) acc[m2][r] = 0.f;
  const size_t SS = (size_t)8192*1152;
  __syncthreads();   // wlsL ready
  for (int p = 0; p < 8; ++p) {
    // stage A panel: 128 m x 64 k
    for (int u = t; u < 1024; u += 384) {
      int m = u >> 3, kc = u & 7;
      f16x4 a0 = *(const f16x4*)&Af16[(size_t)m*512 + p*64 + kc*8];
      f16x4 a1 = *(const f16x4*)&Af16[(size_t)m*512 + p*64 + kc*8 + 4];
      _Float16* dst = &As[m*AP + kc*8];
      *(f16x4*)dst = a0;
      *(f16x4*)(dst+4) = a1;
    }
    // stage B panel: 96 n x 64 k (combine 4 splits for p<6; raw kmf16 for p>=6)
    {
      int u = t;   // 96*4 = 384 units, one per thread
      if (u < 384) {
        int n_l = u >> 2, jc = u & 3;
        int n_g = n0 + n_l;
        _Float16* dst = &Bt[n_l*AP + jc*16];
        if (p < 6) {
          int pt_l = n_l / 3;
          const float* wp = &wlsL[(pt_l*6 + p)*4];
          float facc[16];
#pragma unroll
          for (int e = 0; e < 16; ++e) facc[e] = 0.f;
#pragma unroll
          for (int s = 0; s < 4; ++s) {
            const ushort_t* src = opart + s*SS + (size_t)n_g*384 + p*64 + jc*16;
            uint4 ra = *(const uint4*)src;
            uint4 rb = *(const uint4*)(src + 8);
            const ushort_t* ua = (const ushort_t*)&ra;
            const ushort_t* ub = (const ushort_t*)&rb;
            float wsc = wp[s];
#pragma unroll
            for (int e = 0; e < 8; ++e) {
              facc[e]     += wsc * bf2f(ua[e]);
              facc[8 + e] += wsc * bf2f(ub[e]);
            }
          }
          _Float16 hv[16];
#pragma unroll
          for (int e = 0; e < 16; ++e) hv[e] = (_Float16)facc[e];
#pragma unroll
          for (int g = 0; g < 4; ++g)
            *(f16x4*)(dst + g*4) = *(f16x4*)&hv[g*4];
        } else {
          const _Float16* src = kmf16 + (size_t)n_g*128 + (p-6)*64 + jc*16;
          f16x4 v0 = *(const f16x4*)src;
          f16x4 v1 = *(const f16x4*)(src + 4);
          f16x4 v2 = *(const f16x4*)(src + 8);
          f16x4 v3 = *(const f16x4*)(src + 12);
          *(f16x4*)dst = v0; *(f16x4*)(dst+4) = v1;
          *(f16x4*)(dst+8) = v2; *(f16x4*)(dst+12) = v3;
        }
      }
    }
    __syncthreads();
#pragma unroll
    for (int cs = 0; cs < 4; ++cs) {
      int kloc = cs*16 + hl*8;
      f16x4 b0 = *(const f16x4*)&Bt[(nsub*32 + ql)*AP + kloc];
      f16x4 b1 = *(const f16x4*)&Bt[(nsub*32 + ql)*AP + kloc + 4];
      f16x8 bf = __builtin_shufflevector(b0, b1, 0, 1, 2, 3, 4, 5, 6, 7);
#pragma unroll
      for (int m2 = 0; m2 < 2; ++m2) {
        int mrow = (mh*2 + m2)*32 + ql;
        f16x4 a0 = *(const f16x4*)&As[mrow*AP + kloc];
        f16x4 a1 = *(const f16x4*)&As[mrow*AP + kloc + 4];
        f16x8 af = __builtin_shufflevector(a0, a1, 0, 1, 2, 3, 4, 5, 6, 7);
        acc[m2] = __builtin_amdgcn_mfma_f32_32x32x16_f16(af, bf, acc[m2], 0, 0, 0);
      }
    }
    __syncthreads();
  }
  // epilogue: per-wave LDS transpose (overlay As/Bt region), add xdi, store xmid
  float* trw = trbase + w*32*34;
#pragma unroll
  for (int m2 = 0; m2 < 2; ++m2) {
#pragma unroll
    for (int r = 0; r < 16; ++r) {
      int mrow = (r&3) + 8*(r>>2) + 4*hl;
      trw[ql*34 + mrow] = acc[m2][r];
    }
    asm volatile("s_waitcnt lgkmcnt(0)" ::: "memory");
    float4 c0 = *(float4*)&trw[ql*34 + hl*16 + 0];
    float4 c1 = *(float4*)&trw[ql*34 + hl*16 + 4];
    float4 c2 = *(float4*)&trw[ql*34 + hl*16 + 8];
    float4 c3 = *(float4*)&trw[ql*34 + hl*16 + 12];
    asm volatile("s_waitcnt lgkmcnt(0)" ::: "memory");
    int n_g = n0 + nsub*32 + ql;
    int c0g = (mh*2 + m2)*32 + hl*16;
    const float* xd = xdi + (size_t)n_g*128 + c0g;
    float4 x0 = *(const float4*)xd;
    float4 x1 = *(const float4*)(xd + 4);
    float4 x2 = *(const float4*)(xd + 8);
    float4 x3 = *(const float4*)(xd + 12);
    c0.x += x0.x; c0.y += x0.y; c0.z += x0.z; c0.w += x0.w;
    c1.x += x1.x; c1.y += x1.y; c1.z += x1.z; c1.w += x1.w;
    c2.x += x2.x; c2.y += x2.y; c2.z += x2.z; c2.w += x2.w;
    c3.x += x3.x; c3.y += x3.y; c3.z += x3.z; c3.w += x3.w;
    float* dst = xmid + (size_t)n_g*128 + c0g;
    *(float4*)dst = c0;
    *(float4*)(dst + 4) = c1;
    *(float4*)(dst + 8) = c2;
    *(float4*)(dst + 12) = c3;
  }
}

// ---------------- conv3: VNLinearLeakyReLU 128 -> 256 (de-interleaved input) ----------------
__global__ __launch_bounds__(256) void conv3_kernel(const float* __restrict__ in,
    const float* __restrict__ W3t, const float* __restrict__ U3t,
    float* __restrict__ h3) {
  __shared__ float ins[4*384];
  int bnb = blockIdx.x * 4;
  int t = threadIdx.x;
  for (int idx = t; idx < 4*96; idx += 256)
    *(float4*)&ins[idx*4] = *(const float4*)&in[(size_t)bnb*384 + idx*4];
  __syncthreads();
  float p[4][3], dd[4][3];
#pragma unroll
  for (int pt = 0; pt < 4; ++pt)
#pragma unroll
    for (int d = 0; d < 3; ++d) { p[pt][d] = 0.f; dd[pt][d] = 0.f; }
  for (int ci = 0; ci < 32; ++ci) {
    float w3[4], u3[4];
#pragma unroll
    for (int cc = 0; cc < 4; ++cc) {
      int c = 4*ci + cc;
      w3[cc] = W3t[c*256 + t];
      u3[cc] = U3t[c*256 + t];
    }
#pragma unroll
    for (int pt = 0; pt < 4; ++pt) {
      const float* ip = &ins[pt*384 + 4*ci];
      float4 v0 = *(const float4*)ip;
      float4 v1 = *(const float4*)(ip + 128);
      float4 v2 = *(const float4*)(ip + 256);
      float vd[3][4] = {{v0.x,v0.y,v0.z,v0.w},{v1.x,v1.y,v1.z,v1.w},{v2.x,v2.y,v2.z,v2.w}};
#pragma unroll
      for (int cc = 0; cc < 4; ++cc)
#pragma unroll
        for (int d = 0; d < 3; ++d) {
          float xv = vd[d][cc];
          p[pt][d]  += w3[cc]*xv;
          dd[pt][d] += u3[cc]*xv;
        }
    }
  }
#pragma unroll
  for (int pt = 0; pt < 4; ++pt) {
    float res[3];
    vnleaky3(p[pt], dd[pt], res);
    size_t ob = ((size_t)bnb + pt)*768 + t*3;
    h3[ob+0] = res[0]; h3[ob+1] = res[1]; h3[ob+2] = res[2];
  }
}

// ---------------- conv4: VNLinearLeakyReLU 256 -> 128, + xmid residual -> standard-layout out ----------------
__global__ __launch_bounds__(128) void conv4_kernel(const float* __restrict__ h3,
    const float* __restrict__ W4t, const float* __restrict__ U4t,
    const float* __restrict__ xmid, float* __restrict__ out) {
  __shared__ float ins[4*768];
  int bnb = blockIdx.x * 4;
  int t = threadIdx.x;
  for (int idx = t; idx < 4*192; idx += 128)
    *(float4*)&ins[idx*4] = *(const float4*)&h3[(size_t)bnb*768 + idx*4];
  __syncthreads();
  float p[4][3], dd[4][3];
#pragma unroll
  for (int pt = 0; pt < 4; ++pt)
#pragma unroll
    for (int d = 0; d < 3; ++d) { p[pt][d] = 0.f; dd[pt][d] = 0.f; }
  for (int ci = 0; ci < 64; ++ci) {
    float w4[4], u4[4];
#pragma unroll
    for (int cc = 0; cc < 4; ++cc) {
      int c2 = 4*ci + cc;
      w4[cc] = W4t[c2*128 + t];
      u4[cc] = U4t[c2*128 + t];
    }
#pragma unroll
    for (int pt = 0; pt < 4; ++pt) {
      float vals[12];
      LOAD12(vals, &ins[pt*768 + 12*ci]);
#pragma unroll
      for (int cc = 0; cc < 4; ++cc)
#pragma unroll
        for (int d = 0; d < 3; ++d) {
          float xv = vals[cc*3+d];
          p[pt][d]  += w4[cc]*xv;
          dd[pt][d] += u4[cc]*xv;
        }
    }
  }
#pragma unroll
  for (int pt = 0; pt < 4; ++pt) {
    float res[3];
    vnleaky3(p[pt], dd[pt], res);
    size_t bn = (size_t)bnb + pt;
    float* orow = out + bn*384 + t*3;
#pragma unroll
    for (int d = 0; d < 3; ++d)
      orow[d] = res[d] + xmid[bn*384 + d*128 + t];
  }
}

extern "C" void kernel_launch(void* const* d_in, const int* in_sizes, int n_in,
                              void* d_out, int out_size, void* d_ws, size_t ws_size,
                              hipStream_t stream) {
  const float* x   = (const float*)d_in[0];
  const int* knn   = (const int*)d_in[1];
  const float* g1  = (const float*)d_in[2];
  const float* b1  = (const float*)d_in[3];
  const float* g2  = (const float*)d_in[4];
  const float* b2  = (const float*)d_in[5];
  const float* Wq  = (const float*)d_in[6];
  const float* Wk  = (const float*)d_in[7];
  const float* Wv  = (const float*)d_in[8];
  const float* Wo  = (const float*)d_in[9];
  const float* W1  = (const float*)d_in[10];
  const float* U1  = (const float*)d_in[11];
  const float* W2  = (const float*)d_in[12];
  const float* W3  = (const float*)d_in[13];
  const float* U3  = (const float*)d_in[14];
  const float* W4  = (const float*)d_in[15];
  const float* U4  = (const float*)d_in[16];
  float* out = (float*)d_out;
  (void)n_in; (void)out_size; (void)ws_size;

  const size_t BN = (size_t)in_sizes[0] / 384;   // 8192

  float* ws    = (float*)d_ws;
  float* xdi   = ws;                          // BN*384 f32 (raw x, de-interleaved [n][c])
  float* xmid  = xdi + BN*384;                // BN*384 f32 (x_mid, de-interleaved)
  _Float16* kmf16 = (_Float16*)(xmid + BN*384);  // BN*384 fp16 [n][128]
  ushort_t* xbp = (ushort_t*)(kmf16 + BN*384);   // BN*384 bf16 (LN1 normalized, de-interleaved)
  ushort_t* qb = xbp + BN*384;                // BN*1152 bf16
  ushort_t* kb = qb + BN*1152;
  ushort_t* vb = kb + BN*1152;
  ushort_t* vT = vb + BN*1152;
  ushort_t* Wall = vT + BN*1152;              // 212992 bf16
  _Float16* Af16 = (_Float16*)(Wall + 212992);   // 65536 fp16
  float* W3t  = (float*)(Af16 + 65536);
  float* U3t  = W3t + 32768;
  float* W4t  = U3t + 32768;
  float* U4t  = W4t + 32768;
  ushort_t* opart = (ushort_t*)(U4t + 32768); // 4 * BN*1152 bf16
  float* lpart = (float*)(opart + 4*BN*1152); // 4*24*2048 f32
  // YZf/NBf (BN*768 f32 each = 50 MB) alias opart (75.5 MB): conv1_post runs before attn.
  float* YZf = (float*)opart;
  float* NBf = YZf + BN*768;
  float* nx2 = (float*)qb;   // q dead after x1mid
  float* h3  = (float*)kb;   // k+v dead after attention

  prep_weights<<<1600, 256, 0, stream>>>(Wq, Wk, Wv, Wo, W1, U1, W2, W3, U3, W4, U4,
                                         Wall, Af16, W3t, U3t, W4t, U4t);
  ln1_kernel<<<(int)BN, 128, 0, stream>>>(x, xbp, xdi, g1, b1);
  qkv_conv1_mfma<<<192*4, 256, 0, stream>>>(xbp, Wall, qb, kb, vb, YZf, NBf);
  conv1_post<<<(int)BN, 128, 0, stream>>>(YZf, NBf, knn, kmf16);
  vtrans_kernel<<<(int)(BN*1152/8/256), 256, 0, stream>>>(vb, vT);
  attn_kernel<<<16*24*4, 256, 0, stream>>>(qb, kb, vT, opart, lpart);
  x1mid_mfma<<<256, 384, 0, stream>>>(xdi, opart, lpart, kmf16, Af16, xmid);
  ln2_kernel<<<(int)BN, 128, 0, stream>>>(xmid, nx2, g2, b2);
  conv3_kernel<<<(int)(BN/4), 256, 0, stream>>>(nx2, W3t, U3t, h3);
  conv4_kernel<<<(int)(BN/4), 128, 0, stream>>>(h3, W4t, U4t, xmid, out);
}